// Round 9
// baseline (696.632 us; speedup 1.0000x reference)
//
#include <hip/hip_runtime.h>

// ============================================================================
// RWKV6 TimeMix forward, MI355X.  B=2 L=4096 D=1024 H=16 DH=64 T_CHUNK=128.
// Tier-1 (~186MB ws): mix einsum as swapped-operand single-K-step split MFMA
//   GEMM (vectorized epilogue); r,k,v + decay via split bf16 MFMA GEMMs;
//   pass1 writes cumsum in-place (d_out), pass3 v2 (no cumsum, 39KB LDS,
//   4 blocks/CU); fused GN+SiLU.
// Tier-2 fallback (~112MB): all-bf16 pipeline.
// ============================================================================

typedef __attribute__((ext_vector_type(8))) short bf16x8;
typedef __attribute__((ext_vector_type(4))) float f32x4;

static __device__ __forceinline__ unsigned short f2bf(float f){
  unsigned int u = __float_as_uint(f);
  u += 0x7FFFu + ((u >> 16) & 1u);
  return (unsigned short)(u >> 16);
}
static __device__ __forceinline__ float bf2f(unsigned short h){
  return __uint_as_float(((unsigned int)h) << 16);
}

// ---------------------------------------------------------------------------
// transpose + optional bf16 convert: src[R][C] f32 -> dst[C][R]
// ---------------------------------------------------------------------------
template<int OUT_BF16>
__global__ void transpose_k(const float* __restrict__ src, void* __restrict__ dst,
                            int R, int C)
{
  __shared__ float tile[32][33];
  const int c0 = blockIdx.x*32, r0 = blockIdx.y*32;
  const int tx = threadIdx.x, ty = threadIdx.y;
  #pragma unroll
  for (int i=0;i<4;i++)
    tile[ty+i*8][tx] = src[(size_t)(r0+ty+i*8)*C + (c0+tx)];
  __syncthreads();
  #pragma unroll
  for (int i=0;i<4;i++){
    float v = tile[tx][ty+i*8];
    size_t o = (size_t)(c0+ty+i*8)*R + (r0+tx);
    if (OUT_BF16) ((unsigned short*)dst)[o] = f2bf(v);
    else          ((float*)dst)[o] = v;
  }
}

// transpose f32 -> bf16 hi + bf16 lo residual
__global__ void transpose_split(const float* __restrict__ src,
                                unsigned short* __restrict__ dh,
                                unsigned short* __restrict__ dl, int R, int C)
{
  __shared__ float tile[32][33];
  const int c0 = blockIdx.x*32, r0 = blockIdx.y*32;
  const int tx = threadIdx.x, ty = threadIdx.y;
  #pragma unroll
  for (int i=0;i<4;i++)
    tile[ty+i*8][tx] = src[(size_t)(r0+ty+i*8)*C + (c0+tx)];
  __syncthreads();
  #pragma unroll
  for (int i=0;i<4;i++){
    float v = tile[tx][ty+i*8];
    size_t o = (size_t)(c0+ty+i*8)*R + (r0+tx);
    unsigned short h = f2bf(v);
    dh[o] = h;
    dl[o] = f2bf(v - bf2f(h));
  }
}

// w2 [5][32][1024] -> w2t [5120][32] hi/lo  (w2t[n*1024+d][f] = w2[n][f][d])
__global__ void build_w2t(const float* __restrict__ w2,
                          unsigned short* __restrict__ th,
                          unsigned short* __restrict__ tl)
{
  const int idx = blockIdx.x*256 + threadIdx.x;   // 163840 total
  const int col = idx >> 5, f = idx & 31;
  const int n = col >> 10, d = col & 1023;
  const float v = w2[(size_t)n*32768 + (size_t)f*1024 + d];
  const unsigned short h = f2bf(v);
  th[idx] = h;
  tl[idx] = f2bf(v - bf2f(h));
}

// ---------------------------------------------------------------------------
// bf16 MFMA GEMM: C[M][N] = A[M][K]*B, A bf16 row-major, Bt = B^T bf16 [N][K].
// ---------------------------------------------------------------------------
__launch_bounds__(256)
__global__ void gemm_bf16(const unsigned short* __restrict__ A,
                          const unsigned short* __restrict__ Bt,
                          void* __restrict__ Cp,
                          int M, int N, int K, int c_bf16)
{
  __shared__ unsigned short As[128*32];
  __shared__ unsigned short Bs[128*32];
  const int tid  = threadIdx.x;
  const int row0 = blockIdx.x*128, n0 = blockIdx.y*128;
  const int wid  = tid >> 6, lane = tid & 63;
  const int wm   = (wid >> 1)*64, wn = (wid & 1)*64;
  const int sr   = tid >> 2;
  const int sk   = (tid & 3)*8;
  const int laneq = (lane >> 4)*8;
  const int lanem = lane & 15;

  f32x4 acc[4][4];
  #pragma unroll
  for (int i=0;i<4;i++)
    #pragma unroll
    for (int j=0;j<4;j++) acc[i][j] = (f32x4){0.f,0.f,0.f,0.f};

  for (int kt = 0; kt < K; kt += 32){
    uint4 a0 = *(const uint4*)(A + (size_t)(row0+sr   )*K + kt + sk);
    uint4 a1 = *(const uint4*)(A + (size_t)(row0+sr+64)*K + kt + sk);
    uint4 z; z.x=0u; z.y=0u; z.z=0u; z.w=0u;
    const int nb0 = n0+sr, nb1 = n0+sr+64;
    uint4 b0 = (nb0 < N) ? *(const uint4*)(Bt + (size_t)nb0*K + kt + sk) : z;
    uint4 b1 = (nb1 < N) ? *(const uint4*)(Bt + (size_t)nb1*K + kt + sk) : z;
    *(uint4*)(As + sr*32 + sk)      = a0;
    *(uint4*)(As + (sr+64)*32 + sk) = a1;
    *(uint4*)(Bs + sr*32 + sk)      = b0;
    *(uint4*)(Bs + (sr+64)*32 + sk) = b1;
    __syncthreads();

    bf16x8 af[4], bfr[4];
    #pragma unroll
    for (int mi=0;mi<4;mi++)
      af[mi] = *(const bf16x8*)(As + (wm + mi*16 + lanem)*32 + laneq);
    #pragma unroll
    for (int ni=0;ni<4;ni++)
      bfr[ni] = *(const bf16x8*)(Bs + (wn + ni*16 + lanem)*32 + laneq);
    #pragma unroll
    for (int mi=0;mi<4;mi++)
      #pragma unroll
      for (int ni=0;ni<4;ni++)
        acc[mi][ni] = __builtin_amdgcn_mfma_f32_16x16x32_bf16(af[mi], bfr[ni], acc[mi][ni], 0,0,0);
    __syncthreads();
  }

  const int rr = (lane >> 4)*4, cc = lane & 15;
  #pragma unroll
  for (int mi=0;mi<4;mi++){
    #pragma unroll
    for (int ni=0;ni<4;ni++){
      const int cg = n0 + wn + ni*16 + cc;
      if (cg < N){
        #pragma unroll
        for (int q=0;q<4;q++){
          const int rg = row0 + wm + mi*16 + rr + q;
          float v = acc[mi][ni][q];
          if (c_bf16) ((unsigned short*)Cp)[(size_t)rg*N + cg] = f2bf(v);
          else        ((float*)Cp)[(size_t)rg*N + cg] = v;
        }
      }
    }
  }
}

// ---------------------------------------------------------------------------
// bf16 GEMM with tanh hi/lo epilogue (for m5).  N guarded.
// ---------------------------------------------------------------------------
__launch_bounds__(256)
__global__ void gemm_tanh_bf16(const unsigned short* __restrict__ A,
                               const unsigned short* __restrict__ Bt,
                               unsigned short* __restrict__ Th,
                               unsigned short* __restrict__ Tl,
                               int M, int N, int K)
{
  __shared__ unsigned short As[128*32];
  __shared__ unsigned short Bs[128*32];
  const int tid  = threadIdx.x;
  const int row0 = blockIdx.x*128, n0 = blockIdx.y*128;
  const int wid  = tid >> 6, lane = tid & 63;
  const int wm   = (wid >> 1)*64, wn = (wid & 1)*64;
  const int sr   = tid >> 2;
  const int sk   = (tid & 3)*8;
  const int laneq = (lane >> 4)*8;
  const int lanem = lane & 15;

  f32x4 acc[4][4];
  #pragma unroll
  for (int i=0;i<4;i++)
    #pragma unroll
    for (int j=0;j<4;j++) acc[i][j] = (f32x4){0.f,0.f,0.f,0.f};

  for (int kt = 0; kt < K; kt += 32){
    uint4 a0 = *(const uint4*)(A + (size_t)(row0+sr   )*K + kt + sk);
    uint4 a1 = *(const uint4*)(A + (size_t)(row0+sr+64)*K + kt + sk);
    uint4 z; z.x=0u; z.y=0u; z.z=0u; z.w=0u;
    const int nb0 = n0+sr, nb1 = n0+sr+64;
    uint4 b0 = (nb0 < N) ? *(const uint4*)(Bt + (size_t)nb0*K + kt + sk) : z;
    uint4 b1 = (nb1 < N) ? *(const uint4*)(Bt + (size_t)nb1*K + kt + sk) : z;
    *(uint4*)(As + sr*32 + sk)      = a0;
    *(uint4*)(As + (sr+64)*32 + sk) = a1;
    *(uint4*)(Bs + sr*32 + sk)      = b0;
    *(uint4*)(Bs + (sr+64)*32 + sk) = b1;
    __syncthreads();

    bf16x8 af[4], bfr[4];
    #pragma unroll
    for (int mi=0;mi<4;mi++)
      af[mi] = *(const bf16x8*)(As + (wm + mi*16 + lanem)*32 + laneq);
    #pragma unroll
    for (int ni=0;ni<4;ni++)
      bfr[ni] = *(const bf16x8*)(Bs + (wn + ni*16 + lanem)*32 + laneq);
    #pragma unroll
    for (int mi=0;mi<4;mi++)
      #pragma unroll
      for (int ni=0;ni<4;ni++)
        acc[mi][ni] = __builtin_amdgcn_mfma_f32_16x16x32_bf16(af[mi], bfr[ni], acc[mi][ni], 0,0,0);
    __syncthreads();
  }

  const int rr = (lane >> 4)*4, cc = lane & 15;
  #pragma unroll
  for (int mi=0;mi<4;mi++){
    #pragma unroll
    for (int ni=0;ni<4;ni++){
      const int cg = n0 + wn + ni*16 + cc;
      if (cg < N){
        #pragma unroll
        for (int q=0;q<4;q++){
          const int rg = row0 + wm + mi*16 + rr + q;
          const float t = tanhf(acc[mi][ni][q]);
          const unsigned short h = f2bf(t);
          Th[(size_t)rg*N + cg] = h;
          Tl[(size_t)rg*N + cg] = f2bf(t - bf2f(h));
        }
      }
    }
  }
}

// ---------------------------------------------------------------------------
// gemm_mix (swapped operands): Z[d][tok] = w2t-tile @ m5^T  (single K=32 step)
//   + lerp epilogue: out[tok][d] = x + xx*(maa_n - maa_x + Z), hi/lo stores.
// A = w2t [5120][32] hi/lo (rows = d), Bt = m5 [8192][160] hi/lo (rows = tok,
// K-window n*32).  grid (40, 64).  Lane owns 4 consecutive d per token ->
// float4 x loads, ushort4 stores.
// ---------------------------------------------------------------------------
__launch_bounds__(256)
__global__ void gemm_mix(const unsigned short* __restrict__ w2th,
                         const unsigned short* __restrict__ w2tl,
                         const unsigned short* __restrict__ m5h,
                         const unsigned short* __restrict__ m5l,
                         const float* __restrict__ x,
                         const float* __restrict__ maa_x,
                         const float* __restrict__ maa_w,
                         const float* __restrict__ maa_k,
                         const float* __restrict__ maa_v,
                         const float* __restrict__ maa_r,
                         const float* __restrict__ maa_g,
                         unsigned short* __restrict__ xwh, unsigned short* __restrict__ xwl,
                         unsigned short* __restrict__ xkh, unsigned short* __restrict__ xkl,
                         unsigned short* __restrict__ xvh, unsigned short* __restrict__ xvl,
                         unsigned short* __restrict__ xrh, unsigned short* __restrict__ xrl,
                         unsigned short* __restrict__ xg)
{
  __shared__ unsigned short AhS[128*32], AlS[128*32];
  __shared__ unsigned short BhS[128*32], BlS[128*32];
  const int tid  = threadIdx.x;
  const int row0 = blockIdx.x*128;          // d dimension (0..5120)
  const int col0 = blockIdx.y*128;          // token dimension
  const int n    = row0 >> 10;              // uniform per block
  const int wid  = tid >> 6, lane = tid & 63;
  const int wm   = (wid >> 1)*64, wn = (wid & 1)*64;
  const int sr   = tid >> 2;
  const int sk   = (tid & 3)*8;
  const int laneq = (lane >> 4)*8;
  const int lanem = lane & 15;

  { // stage A (w2t rows) and B (m5 rows, K-window n*32)
    const size_t a0 = (size_t)(row0+sr)*32 + sk;
    const size_t a1 = (size_t)(row0+sr+64)*32 + sk;
    *(uint4*)(AhS + sr*32 + sk)      = *(const uint4*)(w2th + a0);
    *(uint4*)(AhS + (sr+64)*32 + sk) = *(const uint4*)(w2th + a1);
    *(uint4*)(AlS + sr*32 + sk)      = *(const uint4*)(w2tl + a0);
    *(uint4*)(AlS + (sr+64)*32 + sk) = *(const uint4*)(w2tl + a1);
    const size_t b0 = (size_t)(col0+sr)*160 + n*32 + sk;
    const size_t b1 = (size_t)(col0+sr+64)*160 + n*32 + sk;
    *(uint4*)(BhS + sr*32 + sk)      = *(const uint4*)(m5h + b0);
    *(uint4*)(BhS + (sr+64)*32 + sk) = *(const uint4*)(m5h + b1);
    *(uint4*)(BlS + sr*32 + sk)      = *(const uint4*)(m5l + b0);
    *(uint4*)(BlS + (sr+64)*32 + sk) = *(const uint4*)(m5l + b1);
  }
  __syncthreads();

  f32x4 acc[4][4];
  #pragma unroll
  for (int i=0;i<4;i++)
    #pragma unroll
    for (int j=0;j<4;j++) acc[i][j] = (f32x4){0.f,0.f,0.f,0.f};

  {
    bf16x8 ahf[4], alf[4], bhf[4], blf[4];
    #pragma unroll
    for (int mi=0;mi<4;mi++){
      ahf[mi] = *(const bf16x8*)(AhS + (wm + mi*16 + lanem)*32 + laneq);
      alf[mi] = *(const bf16x8*)(AlS + (wm + mi*16 + lanem)*32 + laneq);
    }
    #pragma unroll
    for (int ni=0;ni<4;ni++){
      bhf[ni] = *(const bf16x8*)(BhS + (wn + ni*16 + lanem)*32 + laneq);
      blf[ni] = *(const bf16x8*)(BlS + (wn + ni*16 + lanem)*32 + laneq);
    }
    #pragma unroll
    for (int mi=0;mi<4;mi++)
      #pragma unroll
      for (int ni=0;ni<4;ni++){
        acc[mi][ni] = __builtin_amdgcn_mfma_f32_16x16x32_bf16(ahf[mi], bhf[ni], acc[mi][ni], 0,0,0);
        acc[mi][ni] = __builtin_amdgcn_mfma_f32_16x16x32_bf16(ahf[mi], blf[ni], acc[mi][ni], 0,0,0);
        acc[mi][ni] = __builtin_amdgcn_mfma_f32_16x16x32_bf16(alf[mi], bhf[ni], acc[mi][ni], 0,0,0);
      }
  }

  const int rr = (lane >> 4)*4, cc = lane & 15;
  const float* cnp = (n==0)?maa_w:(n==1)?maa_k:(n==2)?maa_v:(n==3)?maa_r:maa_g;
  unsigned short* hp = (n==0)?xwh:(n==1)?xkh:(n==2)?xvh:(n==3)?xrh:xg;
  unsigned short* lp = (n==0)?xwl:(n==1)?xkl:(n==2)?xvl:(n==3)?xrl:nullptr;
  #pragma unroll
  for (int mi=0;mi<4;mi++){
    #pragma unroll
    for (int ni=0;ni<4;ni++){
      const int tok = col0 + wn + ni*16 + cc;
      const int dg  = row0 + wm + mi*16 + rr;
      const int dd  = dg & 1023;
      float4 mx4 = *(const float4*)(maa_x + dd);
      float4 cn4 = *(const float4*)(cnp + dd);
      const size_t px = (size_t)tok*1024 + dd;
      float4 xc4 = *(const float4*)(x + px);
      float4 xp4;
      if ((tok & 4095) == 0) xp4 = make_float4(0.f,0.f,0.f,0.f);
      else                   xp4 = *(const float4*)(x + px - 1024);
      const float xca[4] = {xc4.x,xc4.y,xc4.z,xc4.w};
      const float xpa[4] = {xp4.x,xp4.y,xp4.z,xp4.w};
      const float mxa[4] = {mx4.x,mx4.y,mx4.z,mx4.w};
      const float cna[4] = {cn4.x,cn4.y,cn4.z,cn4.w};
      ushort4 hv, lv;
      unsigned short* hq = (unsigned short*)&hv;
      unsigned short* lq = (unsigned short*)&lv;
      #pragma unroll
      for (int j=0;j<4;j++){
        const float xx = xpa[j] - xca[j];
        const float v  = xca[j] + xx*mxa[j] + xx*((cna[j]-mxa[j]) + acc[mi][ni][j]);
        const unsigned short h = f2bf(v);
        hq[j] = h;
        lq[j] = f2bf(v - bf2f(h));
      }
      *(ushort4*)(hp + px) = hv;
      if (n != 4) *(ushort4*)(lp + px) = lv;
    }
  }
}

// ---------------------------------------------------------------------------
// split GEMM (pre-decomposed hi/lo): C = AhBh + AhBl + AlBh.  Register staging.
// EPI 0: f32 store.  EPI 2: wlog = -min(exp(bias[col]+acc), 5.2983174) f32.
// ---------------------------------------------------------------------------
template<int EPI>
__launch_bounds__(256)
__global__ void gemm_split2(const unsigned short* __restrict__ Ah,
                            const unsigned short* __restrict__ Al,
                            const unsigned short* __restrict__ Bh,
                            const unsigned short* __restrict__ Bl,
                            float* __restrict__ C, const float* __restrict__ bias,
                            int M, int N, int K)
{
  __shared__ unsigned short AhS[128*32], AlS[128*32];
  __shared__ unsigned short BhS[128*32], BlS[128*32];
  const int tid  = threadIdx.x;
  const int row0 = blockIdx.x*128, n0 = blockIdx.y*128;
  const int wid  = tid >> 6, lane = tid & 63;
  const int wm   = (wid >> 1)*64, wn = (wid & 1)*64;
  const int sr   = tid >> 2;
  const int sk   = (tid & 3)*8;
  const int laneq = (lane >> 4)*8;
  const int lanem = lane & 15;

  f32x4 acc[4][4];
  #pragma unroll
  for (int i=0;i<4;i++)
    #pragma unroll
    for (int j=0;j<4;j++) acc[i][j] = (f32x4){0.f,0.f,0.f,0.f};

  for (int kt = 0; kt < K; kt += 32){
    const size_t ra0 = (size_t)(row0+sr)*K + kt + sk;
    const size_t ra1 = (size_t)(row0+sr+64)*K + kt + sk;
    const size_t rb0 = (size_t)(n0 +sr)*K + kt + sk;
    const size_t rb1 = (size_t)(n0 +sr+64)*K + kt + sk;
    uint4 ah0 = *(const uint4*)(Ah + ra0);
    uint4 ah1 = *(const uint4*)(Ah + ra1);
    uint4 al0 = *(const uint4*)(Al + ra0);
    uint4 al1 = *(const uint4*)(Al + ra1);
    uint4 bh0 = *(const uint4*)(Bh + rb0);
    uint4 bh1 = *(const uint4*)(Bh + rb1);
    uint4 bl0 = *(const uint4*)(Bl + rb0);
    uint4 bl1 = *(const uint4*)(Bl + rb1);
    *(uint4*)(AhS + sr*32 + sk)      = ah0;
    *(uint4*)(AhS + (sr+64)*32 + sk) = ah1;
    *(uint4*)(AlS + sr*32 + sk)      = al0;
    *(uint4*)(AlS + (sr+64)*32 + sk) = al1;
    *(uint4*)(BhS + sr*32 + sk)      = bh0;
    *(uint4*)(BhS + (sr+64)*32 + sk) = bh1;
    *(uint4*)(BlS + sr*32 + sk)      = bl0;
    *(uint4*)(BlS + (sr+64)*32 + sk) = bl1;
    __syncthreads();

    bf16x8 ahf[4], alf[4], bhf[4], blf[4];
    #pragma unroll
    for (int mi=0;mi<4;mi++){
      ahf[mi] = *(const bf16x8*)(AhS + (wm + mi*16 + lanem)*32 + laneq);
      alf[mi] = *(const bf16x8*)(AlS + (wm + mi*16 + lanem)*32 + laneq);
    }
    #pragma unroll
    for (int ni=0;ni<4;ni++){
      bhf[ni] = *(const bf16x8*)(BhS + (wn + ni*16 + lanem)*32 + laneq);
      blf[ni] = *(const bf16x8*)(BlS + (wn + ni*16 + lanem)*32 + laneq);
    }
    #pragma unroll
    for (int mi=0;mi<4;mi++)
      #pragma unroll
      for (int ni=0;ni<4;ni++){
        acc[mi][ni] = __builtin_amdgcn_mfma_f32_16x16x32_bf16(ahf[mi], bhf[ni], acc[mi][ni], 0,0,0);
        acc[mi][ni] = __builtin_amdgcn_mfma_f32_16x16x32_bf16(ahf[mi], blf[ni], acc[mi][ni], 0,0,0);
        acc[mi][ni] = __builtin_amdgcn_mfma_f32_16x16x32_bf16(alf[mi], bhf[ni], acc[mi][ni], 0,0,0);
      }
    __syncthreads();
  }

  const int rr = (lane >> 4)*4, cc = lane & 15;
  #pragma unroll
  for (int mi=0;mi<4;mi++)
    #pragma unroll
    for (int ni=0;ni<4;ni++){
      const int cg = n0 + wn + ni*16 + cc;
      const float bv = (EPI==2) ? bias[cg] : 0.f;
      #pragma unroll
      for (int q=0;q<4;q++){
        float v = acc[mi][ni][q];
        if (EPI==2) v = -fminf(expf(bv + v), 5.2983174f);
        C[(size_t)(row0 + wm + mi*16 + rr + q)*N + cg] = v;
      }
    }
}

// ---------------------------------------------------------------------------
// split GEMM, N=64 guarded, tanh epilogue -> hi/lo bf16 outputs.
// ---------------------------------------------------------------------------
__launch_bounds__(256)
__global__ void gemm_tanh64(const unsigned short* __restrict__ Ah,
                            const unsigned short* __restrict__ Al,
                            const unsigned short* __restrict__ Bh,
                            const unsigned short* __restrict__ Bl,
                            unsigned short* __restrict__ Th,
                            unsigned short* __restrict__ Tl,
                            int M, int N, int K)
{
  __shared__ unsigned short AhS[128*32], AlS[128*32];
  __shared__ unsigned short BhS[128*32], BlS[128*32];
  const int tid  = threadIdx.x;
  const int row0 = blockIdx.x*128, n0 = 0;
  const int wid  = tid >> 6, lane = tid & 63;
  const int wm   = (wid >> 1)*64, wn = (wid & 1)*64;
  const int sr   = tid >> 2;
  const int sk   = (tid & 3)*8;
  const int laneq = (lane >> 4)*8;
  const int lanem = lane & 15;

  f32x4 acc[4][4];
  #pragma unroll
  for (int i=0;i<4;i++)
    #pragma unroll
    for (int j=0;j<4;j++) acc[i][j] = (f32x4){0.f,0.f,0.f,0.f};

  for (int kt = 0; kt < K; kt += 32){
    const size_t ra0 = (size_t)(row0+sr)*K + kt + sk;
    const size_t ra1 = (size_t)(row0+sr+64)*K + kt + sk;
    uint4 ah0 = *(const uint4*)(Ah + ra0);
    uint4 ah1 = *(const uint4*)(Ah + ra1);
    uint4 al0 = *(const uint4*)(Al + ra0);
    uint4 al1 = *(const uint4*)(Al + ra1);
    uint4 z; z.x=0u; z.y=0u; z.z=0u; z.w=0u;
    uint4 bh0 = (sr < N) ? *(const uint4*)(Bh + (size_t)sr*K + kt + sk) : z;
    uint4 bl0 = (sr < N) ? *(const uint4*)(Bl + (size_t)sr*K + kt + sk) : z;
    *(uint4*)(AhS + sr*32 + sk)      = ah0;
    *(uint4*)(AhS + (sr+64)*32 + sk) = ah1;
    *(uint4*)(AlS + sr*32 + sk)      = al0;
    *(uint4*)(AlS + (sr+64)*32 + sk) = al1;
    *(uint4*)(BhS + sr*32 + sk)      = bh0;
    *(uint4*)(BhS + (sr+64)*32 + sk) = z;
    *(uint4*)(BlS + sr*32 + sk)      = bl0;
    *(uint4*)(BlS + (sr+64)*32 + sk) = z;
    __syncthreads();

    bf16x8 ahf[4], alf[4], bhf[4], blf[4];
    #pragma unroll
    for (int mi=0;mi<4;mi++){
      ahf[mi] = *(const bf16x8*)(AhS + (wm + mi*16 + lanem)*32 + laneq);
      alf[mi] = *(const bf16x8*)(AlS + (wm + mi*16 + lanem)*32 + laneq);
    }
    #pragma unroll
    for (int ni=0;ni<4;ni++){
      bhf[ni] = *(const bf16x8*)(BhS + (wn + ni*16 + lanem)*32 + laneq);
      blf[ni] = *(const bf16x8*)(BlS + (wn + ni*16 + lanem)*32 + laneq);
    }
    #pragma unroll
    for (int mi=0;mi<4;mi++)
      #pragma unroll
      for (int ni=0;ni<4;ni++){
        acc[mi][ni] = __builtin_amdgcn_mfma_f32_16x16x32_bf16(ahf[mi], bhf[ni], acc[mi][ni], 0,0,0);
        acc[mi][ni] = __builtin_amdgcn_mfma_f32_16x16x32_bf16(ahf[mi], blf[ni], acc[mi][ni], 0,0,0);
        acc[mi][ni] = __builtin_amdgcn_mfma_f32_16x16x32_bf16(alf[mi], bhf[ni], acc[mi][ni], 0,0,0);
      }
    __syncthreads();
  }

  const int rr = (lane >> 4)*4, cc = lane & 15;
  #pragma unroll
  for (int mi=0;mi<4;mi++)
    #pragma unroll
    for (int ni=0;ni<4;ni++){
      const int cg = n0 + wn + ni*16 + cc;
      if (cg < N){
        #pragma unroll
        for (int q=0;q<4;q++){
          const int rg = row0 + wm + mi*16 + rr + q;
          const float t = tanhf(acc[mi][ni][q]);
          const unsigned short h = f2bf(t);
          Th[(size_t)rg*N + cg] = h;
          Tl[(size_t)rg*N + cg] = f2bf(t - bf2f(h));
        }
      }
    }
}

// ---------------------------------------------------------------------------
// prep: xxx = x + (shift(x)-x)*maa_x (bf16).  grid 8192 x 256.
// ---------------------------------------------------------------------------
__global__ void prep_k(const float* __restrict__ x, const float* __restrict__ maa_x,
                       unsigned short* __restrict__ xxxg)
{
  const size_t e = ((size_t)blockIdx.x*256 + threadIdx.x)*4;
  const int d = (int)(e & 1023);
  const int t = (int)((e >> 10) & 4095);
  float4 xv = *(const float4*)(x + e);
  float4 xp;
  if (t == 0) xp = make_float4(0.f,0.f,0.f,0.f);
  else        xp = *(const float4*)(x + e - 1024);
  float4 mx = *(const float4*)(maa_x + d);
  ushort4 o;
  o.x = f2bf(xv.x + (xp.x-xv.x)*mx.x);
  o.y = f2bf(xv.y + (xp.y-xv.y)*mx.y);
  o.z = f2bf(xv.z + (xp.z-xv.z)*mx.z);
  o.w = f2bf(xv.w + (xp.w-xv.w)*mx.w);
  *(ushort4*)(xxxg + e) = o;
}

// ---------------------------------------------------------------------------
// mix fallback (tier-2): bf16 outputs + in-kernel decay GEMV + wlog.
// ---------------------------------------------------------------------------
__launch_bounds__(256)
__global__ void mix_fb(const float* __restrict__ x, const float* __restrict__ mraw,
                       const float* __restrict__ maa_x, const float* __restrict__ maa_w,
                       const float* __restrict__ maa_k, const float* __restrict__ maa_v,
                       const float* __restrict__ maa_r, const float* __restrict__ maa_g,
                       const float* __restrict__ w2,   const float* __restrict__ dw1,
                       const float* __restrict__ dw2,  const float* __restrict__ tdec,
                       unsigned short* __restrict__ xr, unsigned short* __restrict__ xk,
                       unsigned short* __restrict__ xv, unsigned short* __restrict__ xg,
                       float* __restrict__ wlog)
{
  __shared__ float m5L[8*160];
  __shared__ float xwL[8*1024];
  __shared__ float t64L[8*64];
  const int tid = threadIdx.x;
  const size_t g0 = (size_t)blockIdx.x*8;

  for (int idx = tid; idx < 1280; idx += 256){
    const int tok = idx/160, f = idx%160;
    m5L[tok*160+f] = tanhf(mraw[(g0+tok)*160 + f]);
  }
  float xxv[8][4], xsv[8][4];
  #pragma unroll
  for (int i=0;i<4;i++){
    const int d = i*256 + tid;
    const float mx = maa_x[d];
    #pragma unroll
    for (int tok=0;tok<8;tok++){
      const size_t tglob = g0 + tok;
      const size_t p = tglob*1024 + d;
      const float xc = x[p];
      const float xprev = ((tglob & 4095) == 0) ? 0.f : x[p - 1024];
      const float xxq = xprev - xc;
      xxv[tok][i] = xxq;
      xsv[tok][i] = xc + xxq*mx;
    }
  }
  __syncthreads();

  for (int n=0;n<5;n++){
    float acc[8][4];
    #pragma unroll
    for (int tok=0;tok<8;tok++)
      #pragma unroll
      for (int i=0;i<4;i++) acc[tok][i] = 0.f;
    for (int jj=0;jj<32;jj++){
      const int f = n*32+jj;
      float mv[8];
      #pragma unroll
      for (int tok=0;tok<8;tok++) mv[tok] = m5L[tok*160+f];
      #pragma unroll
      for (int i=0;i<4;i++){
        const float wv = w2[(size_t)f*1024 + i*256 + tid];
        #pragma unroll
        for (int tok=0;tok<8;tok++) acc[tok][i] += mv[tok]*wv;
      }
    }
    const float* cnp = (n==0)?maa_w:(n==1)?maa_k:(n==2)?maa_v:(n==3)?maa_r:maa_g;
    unsigned short* outp = (n==1)?xk:(n==2)?xv:(n==3)?xr:xg;
    #pragma unroll
    for (int i=0;i<4;i++){
      const int d = i*256 + tid;
      const float cdelta = cnp[d] - maa_x[d];
      #pragma unroll
      for (int tok=0;tok<8;tok++){
        const float val = xsv[tok][i] + xxv[tok][i]*(cdelta + acc[tok][i]);
        const size_t op = (g0+tok)*1024 + d;
        if (n == 0) xwL[tok*1024 + d] = val;
        else        outp[op] = f2bf(val);
      }
    }
  }
  __syncthreads();

  {
    const int jj = tid & 63, grp = tid >> 6;
    float a0 = 0.f, a1 = 0.f;
    const float* xr0 = &xwL[grp*1024];
    const float* xr1 = &xwL[(grp+4)*1024];
    for (int k=0;k<1024;k+=8){
      #pragma unroll
      for (int q=0;q<8;q++){
        const float dv = dw1[(size_t)(k+q)*64 + jj];
        a0 += xr0[k+q]*dv;
        a1 += xr1[k+q]*dv;
      }
    }
    t64L[grp*64 + jj]     = tanhf(a0);
    t64L[(grp+4)*64 + jj] = tanhf(a1);
  }
  __syncthreads();

  {
    float acc[8][4];
    #pragma unroll
    for (int tok=0;tok<8;tok++)
      #pragma unroll
      for (int i=0;i<4;i++) acc[tok][i] = 0.f;
    for (int f=0;f<64;f++){
      float tv[8];
      #pragma unroll
      for (int tok=0;tok<8;tok++) tv[tok] = t64L[tok*64+f];
      #pragma unroll
      for (int i=0;i<4;i++){
        const float wv = dw2[(size_t)f*1024 + i*256 + tid];
        #pragma unroll
        for (int tok=0;tok<8;tok++) acc[tok][i] += tv[tok]*wv;
      }
    }
    #pragma unroll
    for (int i=0;i<4;i++){
      const int d = i*256 + tid;
      const float td = tdec[d];
      #pragma unroll
      for (int tok=0;tok<8;tok++){
        const float wl = -fminf(expf(td + acc[tok][i]), 5.2983174f);
        wlog[(g0+tok)*1024 + d] = wl;
      }
    }
  }
}

// ---------------------------------------------------------------------------
// wkv pass1.  Reads wlog, computes cumsum, WRITES CUM BACK IN PLACE (over
// wlog), computes per-chunk wkv + wse.  F32KV selects f32 vs bf16 k/v.
// vL halved (64 rows) for occupancy: LDS ~49KB -> 3 blocks/CU.
// ---------------------------------------------------------------------------
template<int F32KV>
__launch_bounds__(256, 3)
__global__ void wkv_pass1(float* __restrict__ wlog, const void* __restrict__ kg,
                          const void* __restrict__ vg,
                          float* __restrict__ wkv, float* __restrict__ wse)
{
  __shared__ float cumL[128*64];   // cum -> khat in place
  __shared__ float vL[64*64];
  __shared__ float wsL[64];
  __shared__ float segsum[4*64];
  const int tid = threadIdx.x;
  const int hc = blockIdx.x;
  const int n = hc & 31, h = (hc >> 5) & 15, b = hc >> 9;
  const size_t tokbase = (size_t)b*4096 + (size_t)n*128;
  const size_t colbase = (size_t)h*64;

  #pragma unroll
  for (int i=0;i<8;i++){
    const int q = tid + 256*i;          // 2048 float4
    const int t = q >> 4, k4 = (q & 15)*4;
    *(float4*)&cumL[t*64 + k4] =
      *(const float4*)&wlog[(tokbase + t)*1024 + colbase + k4];
  }
  __syncthreads();
  { // segmented cumsum along t
    const int k2 = tid & 63, seg = tid >> 6;
    const int base = seg*32*64 + k2;
    float run = 0.f;
    for (int i=0;i<32;i++){ run += cumL[base + i*64]; cumL[base + i*64] = run; }
    segsum[seg*64 + k2] = run;
    __syncthreads();
    float offv = 0.f;
    for (int s2=0;s2<seg;s2++) offv += segsum[s2*64 + k2];
    if (seg > 0)
      for (int i=0;i<32;i++) cumL[base + i*64] += offv;
    __syncthreads();
  }
  if (tid < 64){
    const float wsv = cumL[127*64 + tid];
    wsL[tid] = wsv;
    wse[(size_t)hc*64 + tid] = expf(wsv);
  }
  __syncthreads();
  // write cum back to global (in place) + overwrite cumL with khat
  for (int idx = tid; idx < 8192; idx += 256){
    const int t = idx >> 6, k2 = idx & 63;
    const float c = cumL[idx];
    const size_t p = (tokbase + t)*1024 + colbase + k2;
    wlog[p] = c;
    const float kv = F32KV ? ((const float*)kg)[p] : bf2f(((const unsigned short*)kg)[p]);
    cumL[idx] = kv * expf(wsL[k2] - c);
  }
  __syncthreads();

  const int kk0 = (tid >> 4)*4, vv0 = (tid & 15)*4;
  float a[4][4];
  #pragma unroll
  for (int i=0;i<4;i++){ a[i][0]=0.f; a[i][1]=0.f; a[i][2]=0.f; a[i][3]=0.f; }
  for (int half=0; half<2; half++){
    #pragma unroll
    for (int i=0;i<4;i++){
      const int q = tid + 256*i;        // 1024 float4
      const int tr = q >> 4, k4 = (q & 15)*4;
      const size_t p = (tokbase + half*64 + tr)*1024 + colbase + k4;
      float4 vv;
      if (F32KV) vv = *(const float4*)((const float*)vg + p);
      else {
        ushort4 vu = *(const ushort4*)((const unsigned short*)vg + p);
        vv = make_float4(bf2f(vu.x), bf2f(vu.y), bf2f(vu.z), bf2f(vu.w));
      }
      *(float4*)&vL[tr*64 + k4] = vv;
    }
    __syncthreads();
    for (int t64=0; t64<64; t64++){
      float4 kf = *(const float4*)&cumL[(half*64 + t64)*64 + kk0];
      float4 vf = *(const float4*)&vL[t64*64 + vv0];
      const float kr[4] = {kf.x, kf.y, kf.z, kf.w};
      const float vr[4] = {vf.x, vf.y, vf.z, vf.w};
      #pragma unroll
      for (int i=0;i<4;i++)
        #pragma unroll
        for (int j=0;j<4;j++) a[i][j] += kr[i]*vr[j];
    }
    __syncthreads();
  }
  const size_t obase = (size_t)hc*4096;
  #pragma unroll
  for (int i=0;i<4;i++)
    *(float4*)(wkv + obase + (size_t)(kk0+i)*64 + vv0) = make_float4(a[i][0],a[i][1],a[i][2],a[i][3]);
}

// ---------------------------------------------------------------------------
// wkv pass2: scan over 32 chunks.
// ---------------------------------------------------------------------------
__global__ void wkv_scan(const float* __restrict__ wkv, const float* __restrict__ wse,
                         float* __restrict__ states)
{
  const int idx = blockIdx.x*256 + threadIdx.x;
  const int vv = idx & 63, kq = (idx >> 6) & 63, bh = idx >> 12;
  float st = 0.f;
  for (int n=0;n<32;n++){
    const size_t hc = (size_t)bh*32 + n;
    states[hc*4096 + (size_t)kq*64 + vv] = st;
    st = st * wse[hc*64 + kq] + wkv[hc*4096 + (size_t)kq*64 + vv];
  }
}

// ---------------------------------------------------------------------------
// wkv pass3 v2: reads PRECOMPUTED cum (from pass1, in d_out).  No cumsum.
// Double-buffered 16-row cumS; hoisted-exp rhat/khat; diag via 16-lane
// shuffle reduce; khB folded as khat*decL.  LDS ~39KB -> 4 blocks/CU.
// F32 selects f32 r/k/v.  FUSED=1: groupnorm+silu(g) -> act bf16.
// ---------------------------------------------------------------------------
template<int F32, int FUSED>
__launch_bounds__(256, 4)
__global__ void wkv_pass3(const float* __restrict__ cum, const void* __restrict__ rg,
                          const void* __restrict__ kg, const void* __restrict__ vg,
                          const float* __restrict__ states, const float* __restrict__ faaaa,
                          const unsigned short* __restrict__ gg,
                          const float* __restrict__ lnw, const float* __restrict__ lnb,
                          unsigned short* __restrict__ outp)
{
  __shared__ float cumS[2][16*68];
  __shared__ float P[64*64];
  __shared__ __attribute__((aligned(16))) float rhat[16*68];
  __shared__ __attribute__((aligned(16))) float khat[16*68];
  __shared__ float vB[16*64];
  __shared__ float decL[64];
  __shared__ float aL[16*16];
  __shared__ float uL[64];
  __shared__ float lnwL[64], lnbL[64];
  const int tid = threadIdx.x;
  const int hc = blockIdx.x;
  const int n = hc & 31, h = (hc >> 5) & 15, b = hc >> 9;
  const size_t tokbase = (size_t)b*4096 + (size_t)n*128;
  const size_t colbase = (size_t)h*64;

  if (tid < 64){
    uL[tid] = faaaa[colbase + tid];
    cumS[1][15*68 + tid] = 0.f;          // "prev" row-15 for c=0
    if (FUSED){
      lnwL[tid] = lnw[colbase + tid];
      lnbL[tid] = lnb[colbase + tid];
    }
  }
  for (int idx = tid; idx < 4096; idx += 256)
    P[idx] = states[(size_t)hc*4096 + idx];
  __syncthreads();

  for (int c=0;c<8;c++){
    const int t0 = c*16;
    float* cur = cumS[c & 1];
    float* prv = cumS[(c & 1) ^ 1];
    { // phase A: load cum rows t0..t0+15 (one float4/thread)
      const int row = tid >> 4, k4 = (tid & 15)*4;
      *(float4*)&cur[row*68 + k4] =
        *(const float4*)&cum[(tokbase + t0 + row)*1024 + colbase + k4];
    }
    __syncthreads();

    { // phase B: staging — rhat/khat/vB/diag/decL (one float4/thread)
      const int tl = tid >> 4, k4 = (tid & 15)*4;
      const size_t p4 = (tokbase + t0 + tl)*1024 + colbase + k4;
      float rv[4], kv[4], vv[4];
      if (F32){
        float4 r4 = *(const float4*)((const float*)rg + p4);
        float4 kq4 = *(const float4*)((const float*)kg + p4);
        float4 v4 = *(const float4*)((const float*)vg + p4);
        rv[0]=r4.x; rv[1]=r4.y; rv[2]=r4.z; rv[3]=r4.w;
        kv[0]=kq4.x; kv[1]=kq4.y; kv[2]=kq4.z; kv[3]=kq4.w;
        vv[0]=v4.x; vv[1]=v4.y; vv[2]=v4.z; vv[3]=v4.w;
      } else {
        ushort4 r4 = *(const ushort4*)((const unsigned short*)rg + p4);
        ushort4 kq4 = *(const ushort4*)((const unsigned short*)kg + p4);
        ushort4 v4 = *(const ushort4*)((const unsigned short*)vg + p4);
        rv[0]=bf2f(r4.x); rv[1]=bf2f(r4.y); rv[2]=bf2f(r4.z); rv[3]=bf2f(r4.w);
        kv[0]=bf2f(kq4.x); kv[1]=bf2f(kq4.y); kv[2]=bf2f(kq4.z); kv[3]=bf2f(kq4.w);
        vv[0]=bf2f(v4.x); vv[1]=bf2f(v4.y); vv[2]=bf2f(v4.z); vv[3]=bf2f(v4.w);
      }
      float4 off4 = *(const float4*)&prv[15*68 + k4];
      float4 cs4  = *(const float4*)&cur[tl*68 + k4];
      float4 cp4  = (tl == 0) ? off4 : *(const float4*)&cur[(tl-1)*68 + k4];
      float4 u4   = *(const float4*)&uL[k4];
      const float offa[4] = {off4.x,off4.y,off4.z,off4.w};
      const float csa[4]  = {cs4.x,cs4.y,cs4.z,cs4.w};
      const float cpa[4]  = {cp4.x,cp4.y,cp4.z,cp4.w};
      const float ua[4]   = {u4.x,u4.y,u4.z,u4.w};
      float rh[4], kh[4];
      float diagp = 0.f;
      #pragma unroll
      for (int j=0;j<4;j++){
        rh[j] = rv[j]*expf(cpa[j] - offa[j]);
        kh[j] = kv[j]*expf(offa[j] - csa[j]);
        diagp += rv[j]*ua[j]*kv[j];
      }
      *(float4*)&rhat[tl*68 + k4] = make_float4(rh[0],rh[1],rh[2],rh[3]);
      *(float4*)&khat[tl*68 + k4] = make_float4(kh[0],kh[1],kh[2],kh[3]);
      *(float4*)&vB[tl*64 + k4]   = make_float4(vv[0],vv[1],vv[2],vv[3]);
      diagp += __shfl_xor(diagp, 1);
      diagp += __shfl_xor(diagp, 2);
      diagp += __shfl_xor(diagp, 4);
      diagp += __shfl_xor(diagp, 8);
      if ((tid & 15) == 0) aL[tl*16 + tl] = diagp;
      if (tl == 15){
        decL[k4+0] = expf(csa[0] - offa[0]);
        decL[k4+1] = expf(csa[1] - offa[1]);
        decL[k4+2] = expf(csa[2] - offa[2]);
        decL[k4+3] = expf(csa[3] - offa[3]);
      }
    }
    __syncthreads();

    { // phase C: strict-lower a[t,s] = rhat[t].khat[s]
      const int tl = tid >> 4, sl = tid & 15;
      if (sl < tl){
        const float4* rp = (const float4*)&rhat[tl*68];
        const float4* kp = (const float4*)&khat[sl*68];
        float a0=0.f,a1=0.f,a2=0.f,a3=0.f;
        #pragma unroll
        for (int q=0;q<16;q++){
          float4 rv4 = rp[q], kv4 = kp[q];
          a0 += rv4.x*kv4.x; a1 += rv4.y*kv4.y;
          a2 += rv4.z*kv4.z; a3 += rv4.w*kv4.w;
        }
        aL[tl*16 + sl] = (a0+a1)+(a2+a3);
      }
    }
    __syncthreads();

    { // phase D: out = tril(a)@v + rhat@P (+ fused GN/SiLU)
      const int tl = tid >> 4, vq = (tid & 15)*4;
      float o0=0.f,o1=0.f,o2=0.f,o3=0.f;
      for (int sl=0; sl<=tl; sl++){
        const float av = aL[tl*16 + sl];
        float4 vf = *(const float4*)&vB[sl*64 + vq];
        o0 += av*vf.x; o1 += av*vf.y; o2 += av*vf.z; o3 += av*vf.w;
      }
      for (int k2=0;k2<64;k2++){
        const float rv = rhat[tl*68 + k2];
        float4 pf = *(const float4*)&P[k2*64 + vq];
        o0 += rv*pf.x; o1 += rv*pf.y; o2 += rv*pf.z; o3 += rv*pf.w;
      }
      const size_t yp = (tokbase + t0 + tl)*1024 + colbase + vq;
      if (FUSED){
        float s  = o0+o1+o2+o3;
        float s2 = o0*o0+o1*o1+o2*o2+o3*o3;
        #pragma unroll
        for (int m=1; m<16; m<<=1){
          s  += __shfl_xor(s,  m);
          s2 += __shfl_xor(s2, m);
        }
        const float mean = s*(1.f/64.f);
        const float var  = s2*(1.f/64.f) - mean*mean;
        const float rstd = rsqrtf(var + 6.4e-4f);
        ushort4 gv4 = *(const ushort4*)(gg + yp);
        const float gvs[4] = {bf2f(gv4.x), bf2f(gv4.y), bf2f(gv4.z), bf2f(gv4.w)};
        const float os[4] = {o0,o1,o2,o3};
        ushort4 ov;
        unsigned short* ovp = (unsigned short*)&ov;
        #pragma unroll
        for (int j=0;j<4;j++){
          const float yn = (os[j] - mean)*rstd*lnwL[vq+j] + lnbL[vq+j];
          const float gv = gvs[j];
          const float sg = gv/(1.f + expf(-gv));
          ovp[j] = f2bf(yn*sg);
        }
        *(ushort4*)(outp + yp) = ov;
      } else {
        ushort4 ov; ov.x = f2bf(o0); ov.y = f2bf(o1); ov.z = f2bf(o2); ov.w = f2bf(o3);
        *(ushort4*)(outp + yp) = ov;
      }
    }
    __syncthreads();

    { // phase E: P = P*dec + (khat*dec)^T @ v
      const int vq = (tid & 15)*4;
      const int kq0 = tid >> 4;
      float dec_ii[4];
      #pragma unroll
      for (int ii=0;ii<4;ii++) dec_ii[ii] = decL[kq0 + ii*16];
      float pv[4][4];
      #pragma unroll
      for (int ii=0;ii<4;ii++){
        const int kq = kq0 + ii*16;
        const float dec = dec_ii[ii];
        float4 pf = *(const float4*)&P[kq*64 + vq];
        pv[ii][0] = pf.x*dec; pv[ii][1] = pf.y*dec; pv[ii][2] = pf.z*dec; pv[ii][3] = pf.w*dec;
      }
      for (int tl=0;tl<16;tl++){
        float4 vf = *(const float4*)&vB[tl*64 + vq];
        const float vr[4] = {vf.x, vf.y, vf.z, vf.w};
        #pragma unroll
        for (int ii=0;ii<4;ii++){
          const float khv = khat[tl*68 + kq0 + ii*16]*dec_ii[ii];
          #pragma unroll
          for (int j=0;j<4;j++) pv[ii][j] += khv*vr[j];
        }
      }
      #pragma unroll
      for (int ii=0;ii<4;ii++)
        *(float4*)&P[(kq0+ii*16)*64 + vq] = make_float4(pv[ii][0],pv[ii][1],pv[ii][2],pv[ii][3]);
    }
    __syncthreads();
  }
}

// ---------------------------------------------------------------------------
// act (tier-2 only): groupnorm * silu(g) -> bf16.
// ---------------------------------------------------------------------------
__global__ void act_k(const unsigned short* __restrict__ y, const unsigned short* __restrict__ g,
                      const float* __restrict__ lnw, const float* __restrict__ lnb,
                      unsigned short* __restrict__ act)
{
  const size_t tau = blockIdx.x;
  const int lane = threadIdx.x & 63;
  const int wave = threadIdx.x >> 6;
  #pragma unroll
  for (int hh=0; hh<4; hh++){
    const int h = wave*4 + hh;
    const size_t p = tau*1024 + (size_t)h*64 + lane;
    const float val = bf2f(y[p]);
    float s = val, s2 = val*val;
    #pragma unroll
    for (int m=32; m>=1; m>>=1){
      s  += __shfl_xor(s, m);
      s2 += __shfl_xor(s2, m);
    }
    const float mean = s*(1.f/64.f);
    const float var  = s2*(1.f/64.f) - mean*mean;
    const int dd = h*64 + lane;
    float yn = (val - mean)*rsqrtf(var + 6.4e-4f);
    yn = yn*lnw[dd] + lnb[dd];
    const float gv = bf2f(g[p]);
    const float sg = gv/(1.f + expf(-gv));
    act[p] = f2bf(yn*sg);
  }
}

// ===========================================================================
extern "C" void kernel_launch(void* const* d_in, const int* in_sizes, int n_in,
                              void* d_out, int out_size, void* d_ws, size_t ws_size,
                              hipStream_t stream)
{
  (void)in_sizes; (void)n_in; (void)out_size;
  const float* x     = (const float*)d_in[0];
  const float* maa_x = (const float*)d_in[1];
  const float* maa_r = (const float*)d_in[2];
  const float* maa_w = (const float*)d_in[3];
  const float* maa_k = (const float*)d_in[4];
  const float* maa_v = (const float*)d_in[5];
  const float* maa_g = (const float*)d_in[6];
  const float* w1    = (const float*)d_in[7];
  const float* w2    = (const float*)d_in[8];
  const float* dw1   = (const float*)d_in[9];
  const float* dw2   = (const float*)d_in[10];
  const float* tdec  = (const float*)d_in[11];
  const float* faaaa = (const float*)d_in[12];
  const float* Wr    = (const float*)d_in[13];
  const float* Wk    = (const float*)d_in[14];
  const float* Wv    = (const float*)d_in[15];
  const float* Wg    = (const float*)d_in[16];
  const float* Wo    = (const float*)d_in[17];
  const float* lnw   = (const float*)d_in[18];
  const float* lnb   = (const float*)d_in[19];

  char* ws = (char*)d_ws;
  const dim3 tb32(32, 8);
  const size_t MB16 = (size_t)8192*1024*2;   // 16MB (one bf16 token-matrix)

  // ---------- tier-1 (~186MB) ----------
  {
    size_t o = 0;
    auto take = [&o](size_t nb){ size_t r = o; o += (nb + 255) & ~(size_t)255; return r; };
    unsigned short* WtG = (unsigned short*)(ws + take((size_t)1024*1024*2));
    unsigned short* WtO = (unsigned short*)(ws + take((size_t)1024*1024*2));
    unsigned short* W1t = (unsigned short*)(ws + take((size_t)160*1024*2));
    unsigned short* WrH = (unsigned short*)(ws + take((size_t)1024*1024*2));
    unsigned short* WrL = (unsigned short*)(ws + take((size_t)1024*1024*2));
    unsigned short* WkH = (unsigned short*)(ws + take((size_t)1024*1024*2));
    unsigned short* WkL = (unsigned short*)(ws + take((size_t)1024*1024*2));
    unsigned short* WvH = (unsigned short*)(ws + take((size_t)1024*1024*2));
    unsigned short* WvL = (unsigned short*)(ws + take((size_t)1024*1024*2));
    unsigned short* D1H = (unsigned short*)(ws + take((size_t)64*1024*2));
    unsigned short* D1L = (unsigned short*)(ws + take((size_t)64*1024*2));
    unsigned short* D2H = (unsigned short*)(ws + take((size_t)1024*64*2));
    unsigned short* D2L = (unsigned short*)(ws + take((size_t)1024*64*2));
    unsigned short* W2tH= (unsigned short*)(ws + take((size_t)5120*32*2));
    unsigned short* W2tL= (unsigned short*)(ws + take((size_t)5120*32*2));
    unsigned short* Th  = (unsigned short*)(ws + take((size_t)8192*64*2));
    unsigned short* Tl  = (unsigned short*)(ws + take((size_t)8192*64*2));
    unsigned short* M5h = (unsigned short*)(ws + take((size_t)8192*160*2));  // -> wse f32
    unsigned short* M5l = (unsigned short*)(ws + take((size_t)8192*160*2));
    char*  Sxxx  = ws + take(MB16);            // xxx bf16 -> g bf16
    char*  slotRA = ws + take(2*MB16);         // xrh+xrl -> k32 f32
    char*  slotKB = ws + take(2*MB16);         // xkh+xkl -> v32 f32
    char*  slotVC = ws + take(2*MB16);         // xvh+xvl -> wkv f32 + st f32
    char*  slotOA = ws + take(2*MB16);         // xwh+xwl -> r32 f32
    char*  Sxg   = ws + take(MB16);            // xg bf16 -> act bf16

    if (o <= ws_size){
      unsigned short* xxxb = (unsigned short*)Sxxx;
      unsigned short* gb   = (unsigned short*)Sxxx;
      float* wse = (float*)M5h;                 // m5 dead after gemm_mix
      unsigned short* xrh = (unsigned short*)slotRA;
      unsigned short* xrl = (unsigned short*)(slotRA + MB16);
      float* k32 = (float*)slotRA;
      unsigned short* xkh = (unsigned short*)slotKB;
      unsigned short* xkl = (unsigned short*)(slotKB + MB16);
      float* v32 = (float*)slotKB;
      unsigned short* xvh = (unsigned short*)slotVC;
      unsigned short* xvl = (unsigned short*)(slotVC + MB16);
      float* wkvb = (float*)slotVC;
      float* st   = (float*)(slotVC + MB16);
      unsigned short* xwh = (unsigned short*)slotOA;
      unsigned short* xwl = (unsigned short*)(slotOA + MB16);
      float* r32  = (float*)slotOA;
      unsigned short* xgb  = (unsigned short*)Sxg;
      unsigned short* actb = (unsigned short*)Sxg;
      float* wlogb = (float*)d_out;             // wlog -> cum (in place)

      transpose_k<1><<<dim3(32,32), tb32, 0, stream>>>(Wg, WtG, 1024, 1024);
      transpose_k<1><<<dim3(32,32), tb32, 0, stream>>>(Wo, WtO, 1024, 1024);
      transpose_k<1><<<dim3(5,32),  tb32, 0, stream>>>(w1, W1t, 1024, 160);
      transpose_split<<<dim3(32,32), tb32, 0, stream>>>(Wr, WrH, WrL, 1024, 1024);
      transpose_split<<<dim3(32,32), tb32, 0, stream>>>(Wk, WkH, WkL, 1024, 1024);
      transpose_split<<<dim3(32,32), tb32, 0, stream>>>(Wv, WvH, WvL, 1024, 1024);
      transpose_split<<<dim3(2,32),  tb32, 0, stream>>>(dw1, D1H, D1L, 1024, 64);
      transpose_split<<<dim3(32,2),  tb32, 0, stream>>>(dw2, D2H, D2L, 64, 1024);
      build_w2t<<<640, 256, 0, stream>>>(w2, W2tH, W2tL);

      prep_k<<<8192, 256, 0, stream>>>(x, maa_x, xxxb);
      gemm_tanh_bf16<<<dim3(64,2), 256, 0, stream>>>(xxxb, W1t, M5h, M5l, 8192, 160, 1024);
      gemm_mix<<<dim3(40,64), 256, 0, stream>>>(W2tH, W2tL, M5h, M5l, x, maa_x,
                                                maa_w, maa_k, maa_v, maa_r, maa_g,
                                                xwh, xwl, xkh, xkl, xvh, xvl,
                                                xrh, xrl, xgb);

      // decay path: t = tanh(xw@dw1) -> wlog = -min(exp(tdec + t@dw2), 5.298)
      gemm_tanh64<<<dim3(64,1), 256, 0, stream>>>(xwh, xwl, D1H, D1L, Th, Tl, 8192, 64, 1024);
      gemm_split2<2><<<dim3(64,8), 256, 0, stream>>>(Th, Tl, D2H, D2L, wlogb, tdec, 8192, 1024, 64);

      gemm_bf16<<<dim3(64,8), 256, 0, stream>>>(xgb, WtG, gb, 8192, 1024, 1024, 1);
      gemm_split2<0><<<dim3(64,8), 256, 0, stream>>>(xrh, xrl, WrH, WrL, r32, nullptr, 8192, 1024, 1024);
      gemm_split2<0><<<dim3(64,8), 256, 0, stream>>>(xkh, xkl, WkH, WkL, k32, nullptr, 8192, 1024, 1024);
      gemm_split2<0><<<dim3(64,8), 256, 0, stream>>>(xvh, xvl, WvH, WvL, v32, nullptr, 8192, 1024, 1024);

      wkv_pass1<1><<<1024, 256, 0, stream>>>(wlogb, k32, v32, wkvb, wse);
      wkv_scan    <<<512,  256, 0, stream>>>(wkvb, wse, st);
      wkv_pass3<1,1><<<1024, 256, 0, stream>>>(wlogb, r32, k32, v32, st, faaaa,
                                               gb, lnw, lnb, actb);

      gemm_bf16<<<dim3(64,8), 256, 0, stream>>>(actb, WtO, d_out, 8192, 1024, 1024, 0);
      return;
    }
  }

  // ---------- tier-2 fallback (~112MB, all-bf16) ----------
  {
    size_t o = 0;
    auto take = [&o](size_t nb){ size_t r = o; o += (nb + 255) & ~(size_t)255; return r; };
    unsigned short* WtR  = (unsigned short*)(ws + take((size_t)1024*1024*2));
    unsigned short* WtK  = (unsigned short*)(ws + take((size_t)1024*1024*2));
    unsigned short* WtV  = (unsigned short*)(ws + take((size_t)1024*1024*2));
    unsigned short* WtG  = (unsigned short*)(ws + take((size_t)1024*1024*2));
    unsigned short* WtO  = (unsigned short*)(ws + take((size_t)1024*1024*2));
    unsigned short* W1t  = (unsigned short*)(ws + take((size_t)160*1024*2));
    unsigned short* xxxb = (unsigned short*)(ws + take(MB16));
    float*          mraw = (float*)         (ws + take((size_t)8192*160*4));
    unsigned short* xrb  = (unsigned short*)(ws + take(MB16));
    unsigned short* xkb  = (unsigned short*)(ws + take(MB16));
    unsigned short* xvb  = (unsigned short*)(ws + take(MB16));
    unsigned short* xgb  = (unsigned short*)(ws + take(MB16));
    unsigned short* kb   = (unsigned short*)(ws + take(MB16));
    float*          wseb = (float*)         (ws + take((size_t)1024*64*4));
    if (o > ws_size) return;

    float*          wlogb = (float*)d_out;
    unsigned short* rb    = xxxb;
    unsigned short* vb    = xrb;
    unsigned short* gb    = xkb;
    float*          wkvb  = (float*)xvb;
    float*          stb   = (float*)xgb;
    unsigned short* yb    = xvb;
    unsigned short* actb  = kb;

    transpose_k<1><<<dim3(32,32), tb32, 0, stream>>>(Wr, WtR, 1024, 1024);
    transpose_k<1><<<dim3(32,32), tb32, 0, stream>>>(Wk, WtK, 1024, 1024);
    transpose_k<1><<<dim3(32,32), tb32, 0, stream>>>(Wv, WtV, 1024, 1024);
    transpose_k<1><<<dim3(32,32), tb32, 0, stream>>>(Wg, WtG, 1024, 1024);
    transpose_k<1><<<dim3(32,32), tb32, 0, stream>>>(Wo, WtO, 1024, 1024);
    transpose_k<1><<<dim3(5,32),  tb32, 0, stream>>>(w1, W1t, 1024, 160);

    prep_k<<<8192, 256, 0, stream>>>(x, maa_x, xxxb);
    gemm_bf16<<<dim3(64,2), 256, 0, stream>>>(xxxb, W1t, mraw, 8192, 160, 1024, 0);
    mix_fb<<<1024, 256, 0, stream>>>(x, mraw, maa_x, maa_w, maa_k, maa_v, maa_r, maa_g,
                                     w2, dw1, dw2, tdec,
                                     xrb, xkb, xvb, xgb, wlogb);

    gemm_bf16<<<dim3(64,8), 256, 0, stream>>>(xrb, WtR, rb, 8192, 1024, 1024, 1);
    gemm_bf16<<<dim3(64,8), 256, 0, stream>>>(xkb, WtK, kb, 8192, 1024, 1024, 1);
    gemm_bf16<<<dim3(64,8), 256, 0, stream>>>(xvb, WtV, vb, 8192, 1024, 1024, 1);
    gemm_bf16<<<dim3(64,8), 256, 0, stream>>>(xgb, WtG, gb, 8192, 1024, 1024, 1);

    wkv_pass1<0><<<1024, 256, 0, stream>>>(wlogb, kb, vb, wkvb, wseb);
    wkv_scan    <<<512,  256, 0, stream>>>(wkvb, wseb, stb);
    wkv_pass3<0,0><<<1024, 256, 0, stream>>>(wlogb, rb, kb, vb, stb, faaaa,
                                             nullptr, nullptr, nullptr, yb);

    act_k<<<8192, 256, 0, stream>>>(yb, gb, lnw, lnb, actb);
    gemm_bf16<<<dim3(64,8), 256, 0, stream>>>(actb, WtO, d_out, 8192, 1024, 1024, 0);
  }
}

// Round 10
// 694.192 us; speedup vs baseline: 1.0035x; 1.0035x over previous
//
#include <hip/hip_runtime.h>

// ============================================================================
// RWKV6 TimeMix forward, MI355X.  B=2 L=4096 D=1024 H=16 DH=64 T_CHUNK=128.
// Tier-1 (~186MB ws): mix einsum as swapped-operand single-K-step split MFMA
//   GEMM with LDS-bounced coalesced epilogue; r,k,v + decay via split bf16
//   MFMA GEMMs; pass1 writes cumsum in-place (d_out); pass3 v3 (no cumsum,
//   shfl-broadcast rhat, 4 blocks/CU); fused GN+SiLU.
// Tier-2 fallback (~112MB): all-bf16 pipeline.
// ============================================================================

typedef __attribute__((ext_vector_type(8))) short bf16x8;
typedef __attribute__((ext_vector_type(4))) float f32x4;

static __device__ __forceinline__ unsigned short f2bf(float f){
  unsigned int u = __float_as_uint(f);
  u += 0x7FFFu + ((u >> 16) & 1u);
  return (unsigned short)(u >> 16);
}
static __device__ __forceinline__ float bf2f(unsigned short h){
  return __uint_as_float(((unsigned int)h) << 16);
}

// ---------------------------------------------------------------------------
// transpose + optional bf16 convert: src[R][C] f32 -> dst[C][R]
// ---------------------------------------------------------------------------
template<int OUT_BF16>
__global__ void transpose_k(const float* __restrict__ src, void* __restrict__ dst,
                            int R, int C)
{
  __shared__ float tile[32][33];
  const int c0 = blockIdx.x*32, r0 = blockIdx.y*32;
  const int tx = threadIdx.x, ty = threadIdx.y;
  #pragma unroll
  for (int i=0;i<4;i++)
    tile[ty+i*8][tx] = src[(size_t)(r0+ty+i*8)*C + (c0+tx)];
  __syncthreads();
  #pragma unroll
  for (int i=0;i<4;i++){
    float v = tile[tx][ty+i*8];
    size_t o = (size_t)(c0+ty+i*8)*R + (r0+tx);
    if (OUT_BF16) ((unsigned short*)dst)[o] = f2bf(v);
    else          ((float*)dst)[o] = v;
  }
}

// transpose f32 -> bf16 hi + bf16 lo residual
__global__ void transpose_split(const float* __restrict__ src,
                                unsigned short* __restrict__ dh,
                                unsigned short* __restrict__ dl, int R, int C)
{
  __shared__ float tile[32][33];
  const int c0 = blockIdx.x*32, r0 = blockIdx.y*32;
  const int tx = threadIdx.x, ty = threadIdx.y;
  #pragma unroll
  for (int i=0;i<4;i++)
    tile[ty+i*8][tx] = src[(size_t)(r0+ty+i*8)*C + (c0+tx)];
  __syncthreads();
  #pragma unroll
  for (int i=0;i<4;i++){
    float v = tile[tx][ty+i*8];
    size_t o = (size_t)(c0+ty+i*8)*R + (r0+tx);
    unsigned short h = f2bf(v);
    dh[o] = h;
    dl[o] = f2bf(v - bf2f(h));
  }
}

// w2 [5][32][1024] -> w2t [5120][32] hi/lo  (w2t[n*1024+d][f] = w2[n][f][d])
__global__ void build_w2t(const float* __restrict__ w2,
                          unsigned short* __restrict__ th,
                          unsigned short* __restrict__ tl)
{
  const int idx = blockIdx.x*256 + threadIdx.x;   // 163840 total
  const int col = idx >> 5, f = idx & 31;
  const int n = col >> 10, d = col & 1023;
  const float v = w2[(size_t)n*32768 + (size_t)f*1024 + d];
  const unsigned short h = f2bf(v);
  th[idx] = h;
  tl[idx] = f2bf(v - bf2f(h));
}

// ---------------------------------------------------------------------------
// bf16 MFMA GEMM: C[M][N] = A[M][K]*B, A bf16 row-major, Bt = B^T bf16 [N][K].
// ---------------------------------------------------------------------------
__launch_bounds__(256)
__global__ void gemm_bf16(const unsigned short* __restrict__ A,
                          const unsigned short* __restrict__ Bt,
                          void* __restrict__ Cp,
                          int M, int N, int K, int c_bf16)
{
  __shared__ unsigned short As[128*32];
  __shared__ unsigned short Bs[128*32];
  const int tid  = threadIdx.x;
  const int row0 = blockIdx.x*128, n0 = blockIdx.y*128;
  const int wid  = tid >> 6, lane = tid & 63;
  const int wm   = (wid >> 1)*64, wn = (wid & 1)*64;
  const int sr   = tid >> 2;
  const int sk   = (tid & 3)*8;
  const int laneq = (lane >> 4)*8;
  const int lanem = lane & 15;

  f32x4 acc[4][4];
  #pragma unroll
  for (int i=0;i<4;i++)
    #pragma unroll
    for (int j=0;j<4;j++) acc[i][j] = (f32x4){0.f,0.f,0.f,0.f};

  for (int kt = 0; kt < K; kt += 32){
    uint4 a0 = *(const uint4*)(A + (size_t)(row0+sr   )*K + kt + sk);
    uint4 a1 = *(const uint4*)(A + (size_t)(row0+sr+64)*K + kt + sk);
    uint4 z; z.x=0u; z.y=0u; z.z=0u; z.w=0u;
    const int nb0 = n0+sr, nb1 = n0+sr+64;
    uint4 b0 = (nb0 < N) ? *(const uint4*)(Bt + (size_t)nb0*K + kt + sk) : z;
    uint4 b1 = (nb1 < N) ? *(const uint4*)(Bt + (size_t)nb1*K + kt + sk) : z;
    *(uint4*)(As + sr*32 + sk)      = a0;
    *(uint4*)(As + (sr+64)*32 + sk) = a1;
    *(uint4*)(Bs + sr*32 + sk)      = b0;
    *(uint4*)(Bs + (sr+64)*32 + sk) = b1;
    __syncthreads();

    bf16x8 af[4], bfr[4];
    #pragma unroll
    for (int mi=0;mi<4;mi++)
      af[mi] = *(const bf16x8*)(As + (wm + mi*16 + lanem)*32 + laneq);
    #pragma unroll
    for (int ni=0;ni<4;ni++)
      bfr[ni] = *(const bf16x8*)(Bs + (wn + ni*16 + lanem)*32 + laneq);
    #pragma unroll
    for (int mi=0;mi<4;mi++)
      #pragma unroll
      for (int ni=0;ni<4;ni++)
        acc[mi][ni] = __builtin_amdgcn_mfma_f32_16x16x32_bf16(af[mi], bfr[ni], acc[mi][ni], 0,0,0);
    __syncthreads();
  }

  const int rr = (lane >> 4)*4, cc = lane & 15;
  #pragma unroll
  for (int mi=0;mi<4;mi++){
    #pragma unroll
    for (int ni=0;ni<4;ni++){
      const int cg = n0 + wn + ni*16 + cc;
      if (cg < N){
        #pragma unroll
        for (int q=0;q<4;q++){
          const int rg = row0 + wm + mi*16 + rr + q;
          float v = acc[mi][ni][q];
          if (c_bf16) ((unsigned short*)Cp)[(size_t)rg*N + cg] = f2bf(v);
          else        ((float*)Cp)[(size_t)rg*N + cg] = v;
        }
      }
    }
  }
}

// ---------------------------------------------------------------------------
// bf16 GEMM with tanh hi/lo epilogue (for m5).  N guarded.
// ---------------------------------------------------------------------------
__launch_bounds__(256)
__global__ void gemm_tanh_bf16(const unsigned short* __restrict__ A,
                               const unsigned short* __restrict__ Bt,
                               unsigned short* __restrict__ Th,
                               unsigned short* __restrict__ Tl,
                               int M, int N, int K)
{
  __shared__ unsigned short As[128*32];
  __shared__ unsigned short Bs[128*32];
  const int tid  = threadIdx.x;
  const int row0 = blockIdx.x*128, n0 = blockIdx.y*128;
  const int wid  = tid >> 6, lane = tid & 63;
  const int wm   = (wid >> 1)*64, wn = (wid & 1)*64;
  const int sr   = tid >> 2;
  const int sk   = (tid & 3)*8;
  const int laneq = (lane >> 4)*8;
  const int lanem = lane & 15;

  f32x4 acc[4][4];
  #pragma unroll
  for (int i=0;i<4;i++)
    #pragma unroll
    for (int j=0;j<4;j++) acc[i][j] = (f32x4){0.f,0.f,0.f,0.f};

  for (int kt = 0; kt < K; kt += 32){
    uint4 a0 = *(const uint4*)(A + (size_t)(row0+sr   )*K + kt + sk);
    uint4 a1 = *(const uint4*)(A + (size_t)(row0+sr+64)*K + kt + sk);
    uint4 z; z.x=0u; z.y=0u; z.z=0u; z.w=0u;
    const int nb0 = n0+sr, nb1 = n0+sr+64;
    uint4 b0 = (nb0 < N) ? *(const uint4*)(Bt + (size_t)nb0*K + kt + sk) : z;
    uint4 b1 = (nb1 < N) ? *(const uint4*)(Bt + (size_t)nb1*K + kt + sk) : z;
    *(uint4*)(As + sr*32 + sk)      = a0;
    *(uint4*)(As + (sr+64)*32 + sk) = a1;
    *(uint4*)(Bs + sr*32 + sk)      = b0;
    *(uint4*)(Bs + (sr+64)*32 + sk) = b1;
    __syncthreads();

    bf16x8 af[4], bfr[4];
    #pragma unroll
    for (int mi=0;mi<4;mi++)
      af[mi] = *(const bf16x8*)(As + (wm + mi*16 + lanem)*32 + laneq);
    #pragma unroll
    for (int ni=0;ni<4;ni++)
      bfr[ni] = *(const bf16x8*)(Bs + (wn + ni*16 + lanem)*32 + laneq);
    #pragma unroll
    for (int mi=0;mi<4;mi++)
      #pragma unroll
      for (int ni=0;ni<4;ni++)
        acc[mi][ni] = __builtin_amdgcn_mfma_f32_16x16x32_bf16(af[mi], bfr[ni], acc[mi][ni], 0,0,0);
    __syncthreads();
  }

  const int rr = (lane >> 4)*4, cc = lane & 15;
  #pragma unroll
  for (int mi=0;mi<4;mi++){
    #pragma unroll
    for (int ni=0;ni<4;ni++){
      const int cg = n0 + wn + ni*16 + cc;
      if (cg < N){
        #pragma unroll
        for (int q=0;q<4;q++){
          const int rg = row0 + wm + mi*16 + rr + q;
          const float t = tanhf(acc[mi][ni][q]);
          const unsigned short h = f2bf(t);
          Th[(size_t)rg*N + cg] = h;
          Tl[(size_t)rg*N + cg] = f2bf(t - bf2f(h));
        }
      }
    }
  }
}

// ---------------------------------------------------------------------------
// gemm_mix: Z[d][tok] = w2t-tile @ m5^T (single K=32 step), then LDS-bounce
// transpose + COALESCED lerp epilogue (32 lanes cover one token's 128 d).
// A = w2t [5120][32] hi/lo (rows = d), Bt = m5 [8192][160] hi/lo.
// grid (40, 64).  LDS: Zs[128][136] f32 (69.6KB) aliases dead staging.
// ---------------------------------------------------------------------------
__launch_bounds__(256)
__global__ void gemm_mix(const unsigned short* __restrict__ w2th,
                         const unsigned short* __restrict__ w2tl,
                         const unsigned short* __restrict__ m5h,
                         const unsigned short* __restrict__ m5l,
                         const float* __restrict__ x,
                         const float* __restrict__ maa_x,
                         const float* __restrict__ maa_w,
                         const float* __restrict__ maa_k,
                         const float* __restrict__ maa_v,
                         const float* __restrict__ maa_r,
                         const float* __restrict__ maa_g,
                         unsigned short* __restrict__ xwh, unsigned short* __restrict__ xwl,
                         unsigned short* __restrict__ xkh, unsigned short* __restrict__ xkl,
                         unsigned short* __restrict__ xvh, unsigned short* __restrict__ xvl,
                         unsigned short* __restrict__ xrh, unsigned short* __restrict__ xrl,
                         unsigned short* __restrict__ xg)
{
  __shared__ __attribute__((aligned(16))) float Zs[128*136];   // 69632 B
  unsigned short* AhS = (unsigned short*)Zs;        // staging aliases Zs
  unsigned short* AlS = AhS + 4096;
  unsigned short* BhS = AhS + 8192;
  unsigned short* BlS = AhS + 12288;
  const int tid  = threadIdx.x;
  const int row0 = blockIdx.x*128;          // d dimension (0..5120)
  const int col0 = blockIdx.y*128;          // token dimension
  const int n    = row0 >> 10;              // uniform per block
  const int wid  = tid >> 6, lane = tid & 63;
  const int wm   = (wid >> 1)*64, wn = (wid & 1)*64;
  const int sr   = tid >> 2;
  const int sk   = (tid & 3)*8;
  const int laneq = (lane >> 4)*8;
  const int lanem = lane & 15;

  { // stage A (w2t rows) and B (m5 rows, K-window n*32)
    const size_t a0 = (size_t)(row0+sr)*32 + sk;
    const size_t a1 = (size_t)(row0+sr+64)*32 + sk;
    *(uint4*)(AhS + sr*32 + sk)      = *(const uint4*)(w2th + a0);
    *(uint4*)(AhS + (sr+64)*32 + sk) = *(const uint4*)(w2th + a1);
    *(uint4*)(AlS + sr*32 + sk)      = *(const uint4*)(w2tl + a0);
    *(uint4*)(AlS + (sr+64)*32 + sk) = *(const uint4*)(w2tl + a1);
    const size_t b0 = (size_t)(col0+sr)*160 + n*32 + sk;
    const size_t b1 = (size_t)(col0+sr+64)*160 + n*32 + sk;
    *(uint4*)(BhS + sr*32 + sk)      = *(const uint4*)(m5h + b0);
    *(uint4*)(BhS + (sr+64)*32 + sk) = *(const uint4*)(m5h + b1);
    *(uint4*)(BlS + sr*32 + sk)      = *(const uint4*)(m5l + b0);
    *(uint4*)(BlS + (sr+64)*32 + sk) = *(const uint4*)(m5l + b1);
  }
  __syncthreads();

  f32x4 acc[4][4];
  #pragma unroll
  for (int i=0;i<4;i++)
    #pragma unroll
    for (int j=0;j<4;j++) acc[i][j] = (f32x4){0.f,0.f,0.f,0.f};

  {
    bf16x8 ahf[4], alf[4], bhf[4], blf[4];
    #pragma unroll
    for (int mi=0;mi<4;mi++){
      ahf[mi] = *(const bf16x8*)(AhS + (wm + mi*16 + lanem)*32 + laneq);
      alf[mi] = *(const bf16x8*)(AlS + (wm + mi*16 + lanem)*32 + laneq);
    }
    #pragma unroll
    for (int ni=0;ni<4;ni++){
      bhf[ni] = *(const bf16x8*)(BhS + (wn + ni*16 + lanem)*32 + laneq);
      blf[ni] = *(const bf16x8*)(BlS + (wn + ni*16 + lanem)*32 + laneq);
    }
    #pragma unroll
    for (int mi=0;mi<4;mi++)
      #pragma unroll
      for (int ni=0;ni<4;ni++){
        acc[mi][ni] = __builtin_amdgcn_mfma_f32_16x16x32_bf16(ahf[mi], bhf[ni], acc[mi][ni], 0,0,0);
        acc[mi][ni] = __builtin_amdgcn_mfma_f32_16x16x32_bf16(ahf[mi], blf[ni], acc[mi][ni], 0,0,0);
        acc[mi][ni] = __builtin_amdgcn_mfma_f32_16x16x32_bf16(alf[mi], bhf[ni], acc[mi][ni], 0,0,0);
      }
  }
  __syncthreads();   // staging fully consumed -> reuse as Zs

  { // scatter acc into Zs[tokL][dL] (stride 136)
    const int rr = (lane >> 4)*4, cc = lane & 15;
    #pragma unroll
    for (int mi=0;mi<4;mi++){
      const int dL0 = wm + mi*16 + rr;
      #pragma unroll
      for (int ni=0;ni<4;ni++){
        const int tokL = wn + ni*16 + cc;
        #pragma unroll
        for (int q=0;q<4;q++)
          Zs[tokL*136 + dL0 + q] = acc[mi][ni][q];
      }
    }
  }
  __syncthreads();

  { // coalesced lerp epilogue
    const int dbase = row0 & 1023;
    const float* cnp = (n==0)?maa_w:(n==1)?maa_k:(n==2)?maa_v:(n==3)?maa_r:maa_g;
    unsigned short* hp = (n==0)?xwh:(n==1)?xkh:(n==2)?xvh:(n==3)?xrh:xg;
    unsigned short* lp = (n==0)?xwl:(n==1)?xkl:(n==2)?xvl:(n==3)?xrl:nullptr;
    #pragma unroll
    for (int i=0;i<16;i++){
      const int idx = tid + 256*i;        // 0..4095
      const int tokL = idx >> 5;          // 0..127
      const int d4 = (idx & 31)*4;        // 0..124
      const int tok = col0 + tokL;
      const int dd = dbase + d4;
      const size_t px = (size_t)tok*1024 + dd;
      float4 z4  = *(const float4*)&Zs[tokL*136 + d4];
      float4 mx4 = *(const float4*)(maa_x + dd);
      float4 cn4 = *(const float4*)(cnp + dd);
      float4 xc4 = *(const float4*)(x + px);
      float4 xp4;
      if ((tok & 4095) == 0) xp4 = make_float4(0.f,0.f,0.f,0.f);
      else                   xp4 = *(const float4*)(x + px - 1024);
      const float za[4]  = {z4.x,z4.y,z4.z,z4.w};
      const float xca[4] = {xc4.x,xc4.y,xc4.z,xc4.w};
      const float xpa[4] = {xp4.x,xp4.y,xp4.z,xp4.w};
      const float mxa[4] = {mx4.x,mx4.y,mx4.z,mx4.w};
      const float cna[4] = {cn4.x,cn4.y,cn4.z,cn4.w};
      ushort4 hv, lv;
      unsigned short* hq = (unsigned short*)&hv;
      unsigned short* lq = (unsigned short*)&lv;
      #pragma unroll
      for (int j=0;j<4;j++){
        const float xx = xpa[j] - xca[j];
        const float v  = xca[j] + xx*mxa[j] + xx*((cna[j]-mxa[j]) + za[j]);
        const unsigned short h = f2bf(v);
        hq[j] = h;
        lq[j] = f2bf(v - bf2f(h));
      }
      *(ushort4*)(hp + px) = hv;
      if (n != 4) *(ushort4*)(lp + px) = lv;
    }
  }
}

// ---------------------------------------------------------------------------
// split GEMM (pre-decomposed hi/lo): C = AhBh + AhBl + AlBh.  Register staging.
// EPI 0: f32 store.  EPI 2: wlog = -min(exp(bias[col]+acc), 5.2983174) f32.
// ---------------------------------------------------------------------------
template<int EPI>
__launch_bounds__(256)
__global__ void gemm_split2(const unsigned short* __restrict__ Ah,
                            const unsigned short* __restrict__ Al,
                            const unsigned short* __restrict__ Bh,
                            const unsigned short* __restrict__ Bl,
                            float* __restrict__ C, const float* __restrict__ bias,
                            int M, int N, int K)
{
  __shared__ unsigned short AhS[128*32], AlS[128*32];
  __shared__ unsigned short BhS[128*32], BlS[128*32];
  const int tid  = threadIdx.x;
  const int row0 = blockIdx.x*128, n0 = blockIdx.y*128;
  const int wid  = tid >> 6, lane = tid & 63;
  const int wm   = (wid >> 1)*64, wn = (wid & 1)*64;
  const int sr   = tid >> 2;
  const int sk   = (tid & 3)*8;
  const int laneq = (lane >> 4)*8;
  const int lanem = lane & 15;

  f32x4 acc[4][4];
  #pragma unroll
  for (int i=0;i<4;i++)
    #pragma unroll
    for (int j=0;j<4;j++) acc[i][j] = (f32x4){0.f,0.f,0.f,0.f};

  for (int kt = 0; kt < K; kt += 32){
    const size_t ra0 = (size_t)(row0+sr)*K + kt + sk;
    const size_t ra1 = (size_t)(row0+sr+64)*K + kt + sk;
    const size_t rb0 = (size_t)(n0 +sr)*K + kt + sk;
    const size_t rb1 = (size_t)(n0 +sr+64)*K + kt + sk;
    uint4 ah0 = *(const uint4*)(Ah + ra0);
    uint4 ah1 = *(const uint4*)(Ah + ra1);
    uint4 al0 = *(const uint4*)(Al + ra0);
    uint4 al1 = *(const uint4*)(Al + ra1);
    uint4 bh0 = *(const uint4*)(Bh + rb0);
    uint4 bh1 = *(const uint4*)(Bh + rb1);
    uint4 bl0 = *(const uint4*)(Bl + rb0);
    uint4 bl1 = *(const uint4*)(Bl + rb1);
    *(uint4*)(AhS + sr*32 + sk)      = ah0;
    *(uint4*)(AhS + (sr+64)*32 + sk) = ah1;
    *(uint4*)(AlS + sr*32 + sk)      = al0;
    *(uint4*)(AlS + (sr+64)*32 + sk) = al1;
    *(uint4*)(BhS + sr*32 + sk)      = bh0;
    *(uint4*)(BhS + (sr+64)*32 + sk) = bh1;
    *(uint4*)(BlS + sr*32 + sk)      = bl0;
    *(uint4*)(BlS + (sr+64)*32 + sk) = bl1;
    __syncthreads();

    bf16x8 ahf[4], alf[4], bhf[4], blf[4];
    #pragma unroll
    for (int mi=0;mi<4;mi++){
      ahf[mi] = *(const bf16x8*)(AhS + (wm + mi*16 + lanem)*32 + laneq);
      alf[mi] = *(const bf16x8*)(AlS + (wm + mi*16 + lanem)*32 + laneq);
    }
    #pragma unroll
    for (int ni=0;ni<4;ni++){
      bhf[ni] = *(const bf16x8*)(BhS + (wn + ni*16 + lanem)*32 + laneq);
      blf[ni] = *(const bf16x8*)(BlS + (wn + ni*16 + lanem)*32 + laneq);
    }
    #pragma unroll
    for (int mi=0;mi<4;mi++)
      #pragma unroll
      for (int ni=0;ni<4;ni++){
        acc[mi][ni] = __builtin_amdgcn_mfma_f32_16x16x32_bf16(ahf[mi], bhf[ni], acc[mi][ni], 0,0,0);
        acc[mi][ni] = __builtin_amdgcn_mfma_f32_16x16x32_bf16(ahf[mi], blf[ni], acc[mi][ni], 0,0,0);
        acc[mi][ni] = __builtin_amdgcn_mfma_f32_16x16x32_bf16(alf[mi], bhf[ni], acc[mi][ni], 0,0,0);
      }
    __syncthreads();
  }

  const int rr = (lane >> 4)*4, cc = lane & 15;
  #pragma unroll
  for (int mi=0;mi<4;mi++)
    #pragma unroll
    for (int ni=0;ni<4;ni++){
      const int cg = n0 + wn + ni*16 + cc;
      const float bv = (EPI==2) ? bias[cg] : 0.f;
      #pragma unroll
      for (int q=0;q<4;q++){
        float v = acc[mi][ni][q];
        if (EPI==2) v = -fminf(expf(bv + v), 5.2983174f);
        C[(size_t)(row0 + wm + mi*16 + rr + q)*N + cg] = v;
      }
    }
}

// ---------------------------------------------------------------------------
// split GEMM, N=64 guarded, tanh epilogue -> hi/lo bf16 outputs.
// ---------------------------------------------------------------------------
__launch_bounds__(256)
__global__ void gemm_tanh64(const unsigned short* __restrict__ Ah,
                            const unsigned short* __restrict__ Al,
                            const unsigned short* __restrict__ Bh,
                            const unsigned short* __restrict__ Bl,
                            unsigned short* __restrict__ Th,
                            unsigned short* __restrict__ Tl,
                            int M, int N, int K)
{
  __shared__ unsigned short AhS[128*32], AlS[128*32];
  __shared__ unsigned short BhS[128*32], BlS[128*32];
  const int tid  = threadIdx.x;
  const int row0 = blockIdx.x*128, n0 = 0;
  const int wid  = tid >> 6, lane = tid & 63;
  const int wm   = (wid >> 1)*64, wn = (wid & 1)*64;
  const int sr   = tid >> 2;
  const int sk   = (tid & 3)*8;
  const int laneq = (lane >> 4)*8;
  const int lanem = lane & 15;

  f32x4 acc[4][4];
  #pragma unroll
  for (int i=0;i<4;i++)
    #pragma unroll
    for (int j=0;j<4;j++) acc[i][j] = (f32x4){0.f,0.f,0.f,0.f};

  for (int kt = 0; kt < K; kt += 32){
    const size_t ra0 = (size_t)(row0+sr)*K + kt + sk;
    const size_t ra1 = (size_t)(row0+sr+64)*K + kt + sk;
    uint4 ah0 = *(const uint4*)(Ah + ra0);
    uint4 ah1 = *(const uint4*)(Ah + ra1);
    uint4 al0 = *(const uint4*)(Al + ra0);
    uint4 al1 = *(const uint4*)(Al + ra1);
    uint4 z; z.x=0u; z.y=0u; z.z=0u; z.w=0u;
    uint4 bh0 = (sr < N) ? *(const uint4*)(Bh + (size_t)sr*K + kt + sk) : z;
    uint4 bl0 = (sr < N) ? *(const uint4*)(Bl + (size_t)sr*K + kt + sk) : z;
    *(uint4*)(AhS + sr*32 + sk)      = ah0;
    *(uint4*)(AhS + (sr+64)*32 + sk) = ah1;
    *(uint4*)(AlS + sr*32 + sk)      = al0;
    *(uint4*)(AlS + (sr+64)*32 + sk) = al1;
    *(uint4*)(BhS + sr*32 + sk)      = bh0;
    *(uint4*)(BhS + (sr+64)*32 + sk) = z;
    *(uint4*)(BlS + sr*32 + sk)      = bl0;
    *(uint4*)(BlS + (sr+64)*32 + sk) = z;
    __syncthreads();

    bf16x8 ahf[4], alf[4], bhf[4], blf[4];
    #pragma unroll
    for (int mi=0;mi<4;mi++){
      ahf[mi] = *(const bf16x8*)(AhS + (wm + mi*16 + lanem)*32 + laneq);
      alf[mi] = *(const bf16x8*)(AlS + (wm + mi*16 + lanem)*32 + laneq);
    }
    #pragma unroll
    for (int ni=0;ni<4;ni++){
      bhf[ni] = *(const bf16x8*)(BhS + (wn + ni*16 + lanem)*32 + laneq);
      blf[ni] = *(const bf16x8*)(BlS + (wn + ni*16 + lanem)*32 + laneq);
    }
    #pragma unroll
    for (int mi=0;mi<4;mi++)
      #pragma unroll
      for (int ni=0;ni<4;ni++){
        acc[mi][ni] = __builtin_amdgcn_mfma_f32_16x16x32_bf16(ahf[mi], bhf[ni], acc[mi][ni], 0,0,0);
        acc[mi][ni] = __builtin_amdgcn_mfma_f32_16x16x32_bf16(ahf[mi], blf[ni], acc[mi][ni], 0,0,0);
        acc[mi][ni] = __builtin_amdgcn_mfma_f32_16x16x32_bf16(alf[mi], bhf[ni], acc[mi][ni], 0,0,0);
      }
    __syncthreads();
  }

  const int rr = (lane >> 4)*4, cc = lane & 15;
  #pragma unroll
  for (int mi=0;mi<4;mi++)
    #pragma unroll
    for (int ni=0;ni<4;ni++){
      const int cg = n0 + wn + ni*16 + cc;
      if (cg < N){
        #pragma unroll
        for (int q=0;q<4;q++){
          const int rg = row0 + wm + mi*16 + rr + q;
          const float t = tanhf(acc[mi][ni][q]);
          const unsigned short h = f2bf(t);
          Th[(size_t)rg*N + cg] = h;
          Tl[(size_t)rg*N + cg] = f2bf(t - bf2f(h));
        }
      }
    }
}

// ---------------------------------------------------------------------------
// prep: xxx = x + (shift(x)-x)*maa_x (bf16).  grid 8192 x 256.
// ---------------------------------------------------------------------------
__global__ void prep_k(const float* __restrict__ x, const float* __restrict__ maa_x,
                       unsigned short* __restrict__ xxxg)
{
  const size_t e = ((size_t)blockIdx.x*256 + threadIdx.x)*4;
  const int d = (int)(e & 1023);
  const int t = (int)((e >> 10) & 4095);
  float4 xv = *(const float4*)(x + e);
  float4 xp;
  if (t == 0) xp = make_float4(0.f,0.f,0.f,0.f);
  else        xp = *(const float4*)(x + e - 1024);
  float4 mx = *(const float4*)(maa_x + d);
  ushort4 o;
  o.x = f2bf(xv.x + (xp.x-xv.x)*mx.x);
  o.y = f2bf(xv.y + (xp.y-xv.y)*mx.y);
  o.z = f2bf(xv.z + (xp.z-xv.z)*mx.z);
  o.w = f2bf(xv.w + (xp.w-xv.w)*mx.w);
  *(ushort4*)(xxxg + e) = o;
}

// ---------------------------------------------------------------------------
// mix fallback (tier-2): bf16 outputs + in-kernel decay GEMV + wlog.
// ---------------------------------------------------------------------------
__launch_bounds__(256)
__global__ void mix_fb(const float* __restrict__ x, const float* __restrict__ mraw,
                       const float* __restrict__ maa_x, const float* __restrict__ maa_w,
                       const float* __restrict__ maa_k, const float* __restrict__ maa_v,
                       const float* __restrict__ maa_r, const float* __restrict__ maa_g,
                       const float* __restrict__ w2,   const float* __restrict__ dw1,
                       const float* __restrict__ dw2,  const float* __restrict__ tdec,
                       unsigned short* __restrict__ xr, unsigned short* __restrict__ xk,
                       unsigned short* __restrict__ xv, unsigned short* __restrict__ xg,
                       float* __restrict__ wlog)
{
  __shared__ float m5L[8*160];
  __shared__ float xwL[8*1024];
  __shared__ float t64L[8*64];
  const int tid = threadIdx.x;
  const size_t g0 = (size_t)blockIdx.x*8;

  for (int idx = tid; idx < 1280; idx += 256){
    const int tok = idx/160, f = idx%160;
    m5L[tok*160+f] = tanhf(mraw[(g0+tok)*160 + f]);
  }
  float xxv[8][4], xsv[8][4];
  #pragma unroll
  for (int i=0;i<4;i++){
    const int d = i*256 + tid;
    const float mx = maa_x[d];
    #pragma unroll
    for (int tok=0;tok<8;tok++){
      const size_t tglob = g0 + tok;
      const size_t p = tglob*1024 + d;
      const float xc = x[p];
      const float xprev = ((tglob & 4095) == 0) ? 0.f : x[p - 1024];
      const float xxq = xprev - xc;
      xxv[tok][i] = xxq;
      xsv[tok][i] = xc + xxq*mx;
    }
  }
  __syncthreads();

  for (int n=0;n<5;n++){
    float acc[8][4];
    #pragma unroll
    for (int tok=0;tok<8;tok++)
      #pragma unroll
      for (int i=0;i<4;i++) acc[tok][i] = 0.f;
    for (int jj=0;jj<32;jj++){
      const int f = n*32+jj;
      float mv[8];
      #pragma unroll
      for (int tok=0;tok<8;tok++) mv[tok] = m5L[tok*160+f];
      #pragma unroll
      for (int i=0;i<4;i++){
        const float wv = w2[(size_t)f*1024 + i*256 + tid];
        #pragma unroll
        for (int tok=0;tok<8;tok++) acc[tok][i] += mv[tok]*wv;
      }
    }
    const float* cnp = (n==0)?maa_w:(n==1)?maa_k:(n==2)?maa_v:(n==3)?maa_r:maa_g;
    unsigned short* outp = (n==1)?xk:(n==2)?xv:(n==3)?xr:xg;
    #pragma unroll
    for (int i=0;i<4;i++){
      const int d = i*256 + tid;
      const float cdelta = cnp[d] - maa_x[d];
      #pragma unroll
      for (int tok=0;tok<8;tok++){
        const float val = xsv[tok][i] + xxv[tok][i]*(cdelta + acc[tok][i]);
        const size_t op = (g0+tok)*1024 + d;
        if (n == 0) xwL[tok*1024 + d] = val;
        else        outp[op] = f2bf(val);
      }
    }
  }
  __syncthreads();

  {
    const int jj = tid & 63, grp = tid >> 6;
    float a0 = 0.f, a1 = 0.f;
    const float* xr0 = &xwL[grp*1024];
    const float* xr1 = &xwL[(grp+4)*1024];
    for (int k=0;k<1024;k+=8){
      #pragma unroll
      for (int q=0;q<8;q++){
        const float dv = dw1[(size_t)(k+q)*64 + jj];
        a0 += xr0[k+q]*dv;
        a1 += xr1[k+q]*dv;
      }
    }
    t64L[grp*64 + jj]     = tanhf(a0);
    t64L[(grp+4)*64 + jj] = tanhf(a1);
  }
  __syncthreads();

  {
    float acc[8][4];
    #pragma unroll
    for (int tok=0;tok<8;tok++)
      #pragma unroll
      for (int i=0;i<4;i++) acc[tok][i] = 0.f;
    for (int f=0;f<64;f++){
      float tv[8];
      #pragma unroll
      for (int tok=0;tok<8;tok++) tv[tok] = t64L[tok*64+f];
      #pragma unroll
      for (int i=0;i<4;i++){
        const float wv = dw2[(size_t)f*1024 + i*256 + tid];
        #pragma unroll
        for (int tok=0;tok<8;tok++) acc[tok][i] += tv[tok]*wv;
      }
    }
    #pragma unroll
    for (int i=0;i<4;i++){
      const int d = i*256 + tid;
      const float td = tdec[d];
      #pragma unroll
      for (int tok=0;tok<8;tok++){
        const float wl = -fminf(expf(td + acc[tok][i]), 5.2983174f);
        wlog[(g0+tok)*1024 + d] = wl;
      }
    }
  }
}

// ---------------------------------------------------------------------------
// wkv pass1.  Reads wlog, computes cumsum, WRITES CUM BACK IN PLACE (over
// wlog), computes per-chunk wkv + wse.  F32KV selects f32 vs bf16 k/v.
// ---------------------------------------------------------------------------
template<int F32KV>
__launch_bounds__(256, 3)
__global__ void wkv_pass1(float* __restrict__ wlog, const void* __restrict__ kg,
                          const void* __restrict__ vg,
                          float* __restrict__ wkv, float* __restrict__ wse)
{
  __shared__ float cumL[128*64];   // cum -> khat in place
  __shared__ float vL[64*64];
  __shared__ float wsL[64];
  __shared__ float segsum[4*64];
  const int tid = threadIdx.x;
  const int hc = blockIdx.x;
  const int n = hc & 31, h = (hc >> 5) & 15, b = hc >> 9;
  const size_t tokbase = (size_t)b*4096 + (size_t)n*128;
  const size_t colbase = (size_t)h*64;

  #pragma unroll
  for (int i=0;i<8;i++){
    const int q = tid + 256*i;          // 2048 float4
    const int t = q >> 4, k4 = (q & 15)*4;
    *(float4*)&cumL[t*64 + k4] =
      *(const float4*)&wlog[(tokbase + t)*1024 + colbase + k4];
  }
  __syncthreads();
  { // segmented cumsum along t
    const int k2 = tid & 63, seg = tid >> 6;
    const int base = seg*32*64 + k2;
    float run = 0.f;
    for (int i=0;i<32;i++){ run += cumL[base + i*64]; cumL[base + i*64] = run; }
    segsum[seg*64 + k2] = run;
    __syncthreads();
    float offv = 0.f;
    for (int s2=0;s2<seg;s2++) offv += segsum[s2*64 + k2];
    if (seg > 0)
      for (int i=0;i<32;i++) cumL[base + i*64] += offv;
    __syncthreads();
  }
  if (tid < 64){
    const float wsv = cumL[127*64 + tid];
    wsL[tid] = wsv;
    wse[(size_t)hc*64 + tid] = expf(wsv);
  }
  __syncthreads();
  for (int idx = tid; idx < 8192; idx += 256){
    const int t = idx >> 6, k2 = idx & 63;
    const float c = cumL[idx];
    const size_t p = (tokbase + t)*1024 + colbase + k2;
    wlog[p] = c;
    const float kv = F32KV ? ((const float*)kg)[p] : bf2f(((const unsigned short*)kg)[p]);
    cumL[idx] = kv * expf(wsL[k2] - c);
  }
  __syncthreads();

  const int kk0 = (tid >> 4)*4, vv0 = (tid & 15)*4;
  float a[4][4];
  #pragma unroll
  for (int i=0;i<4;i++){ a[i][0]=0.f; a[i][1]=0.f; a[i][2]=0.f; a[i][3]=0.f; }
  for (int half=0; half<2; half++){
    #pragma unroll
    for (int i=0;i<4;i++){
      const int q = tid + 256*i;        // 1024 float4
      const int tr = q >> 4, k4 = (q & 15)*4;
      const size_t p = (tokbase + half*64 + tr)*1024 + colbase + k4;
      float4 vv;
      if (F32KV) vv = *(const float4*)((const float*)vg + p);
      else {
        ushort4 vu = *(const ushort4*)((const unsigned short*)vg + p);
        vv = make_float4(bf2f(vu.x), bf2f(vu.y), bf2f(vu.z), bf2f(vu.w));
      }
      *(float4*)&vL[tr*64 + k4] = vv;
    }
    __syncthreads();
    for (int t64=0; t64<64; t64++){
      float4 kf = *(const float4*)&cumL[(half*64 + t64)*64 + kk0];
      float4 vf = *(const float4*)&vL[t64*64 + vv0];
      const float kr[4] = {kf.x, kf.y, kf.z, kf.w};
      const float vr[4] = {vf.x, vf.y, vf.z, vf.w};
      #pragma unroll
      for (int i=0;i<4;i++)
        #pragma unroll
        for (int j=0;j<4;j++) a[i][j] += kr[i]*vr[j];
    }
    __syncthreads();
  }
  const size_t obase = (size_t)hc*4096;
  #pragma unroll
  for (int i=0;i<4;i++)
    *(float4*)(wkv + obase + (size_t)(kk0+i)*64 + vv0) = make_float4(a[i][0],a[i][1],a[i][2],a[i][3]);
}

// ---------------------------------------------------------------------------
// wkv pass2: scan over 32 chunks.
// ---------------------------------------------------------------------------
__global__ void wkv_scan(const float* __restrict__ wkv, const float* __restrict__ wse,
                         float* __restrict__ states)
{
  const int idx = blockIdx.x*256 + threadIdx.x;
  const int vv = idx & 63, kq = (idx >> 6) & 63, bh = idx >> 12;
  float st = 0.f;
  for (int n=0;n<32;n++){
    const size_t hc = (size_t)bh*32 + n;
    states[hc*4096 + (size_t)kq*64 + vv] = st;
    st = st * wse[hc*64 + kq] + wkv[hc*4096 + (size_t)kq*64 + vv];
  }
}

// ---------------------------------------------------------------------------
// wkv pass3 v3: precomputed cum; shfl-broadcast rhat in phase D.
// F32 selects f32 r/k/v.  FUSED=1: groupnorm+silu(g) -> act bf16.
// ---------------------------------------------------------------------------
template<int F32, int FUSED>
__launch_bounds__(256, 4)
__global__ void wkv_pass3(const float* __restrict__ cum, const void* __restrict__ rg,
                          const void* __restrict__ kg, const void* __restrict__ vg,
                          const float* __restrict__ states, const float* __restrict__ faaaa,
                          const unsigned short* __restrict__ gg,
                          const float* __restrict__ lnw, const float* __restrict__ lnb,
                          unsigned short* __restrict__ outp)
{
  __shared__ float cumS[2][16*68];
  __shared__ float P[64*64];
  __shared__ __attribute__((aligned(16))) float rhat[16*68];
  __shared__ __attribute__((aligned(16))) float khat[16*68];
  __shared__ float vB[16*64];
  __shared__ float decL[64];
  __shared__ float aL[16*16];
  __shared__ float uL[64];
  __shared__ float lnwL[64], lnbL[64];
  const int tid = threadIdx.x;
  const int lane = tid & 63;
  const int hc = blockIdx.x;
  const int n = hc & 31, h = (hc >> 5) & 15, b = hc >> 9;
  const size_t tokbase = (size_t)b*4096 + (size_t)n*128;
  const size_t colbase = (size_t)h*64;

  if (tid < 64){
    uL[tid] = faaaa[colbase + tid];
    cumS[1][15*68 + tid] = 0.f;          // "prev" row-15 for c=0
    if (FUSED){
      lnwL[tid] = lnw[colbase + tid];
      lnbL[tid] = lnb[colbase + tid];
    }
  }
  for (int idx = tid; idx < 4096; idx += 256)
    P[idx] = states[(size_t)hc*4096 + idx];
  __syncthreads();

  for (int c=0;c<8;c++){
    const int t0 = c*16;
    float* cur = cumS[c & 1];
    float* prv = cumS[(c & 1) ^ 1];
    { // phase A: load cum rows t0..t0+15
      const int row = tid >> 4, k4 = (tid & 15)*4;
      *(float4*)&cur[row*68 + k4] =
        *(const float4*)&cum[(tokbase + t0 + row)*1024 + colbase + k4];
    }
    __syncthreads();

    float rh0, rh1, rh2, rh3;    // this thread's rhat[tl][k4..k4+3]
    { // phase B: staging — rhat/khat/vB/diag/decL
      const int tl = tid >> 4, k4 = (tid & 15)*4;
      const size_t p4 = (tokbase + t0 + tl)*1024 + colbase + k4;
      float rv[4], kv[4], vv[4];
      if (F32){
        float4 r4 = *(const float4*)((const float*)rg + p4);
        float4 kq4 = *(const float4*)((const float*)kg + p4);
        float4 v4 = *(const float4*)((const float*)vg + p4);
        rv[0]=r4.x; rv[1]=r4.y; rv[2]=r4.z; rv[3]=r4.w;
        kv[0]=kq4.x; kv[1]=kq4.y; kv[2]=kq4.z; kv[3]=kq4.w;
        vv[0]=v4.x; vv[1]=v4.y; vv[2]=v4.z; vv[3]=v4.w;
      } else {
        ushort4 r4 = *(const ushort4*)((const unsigned short*)rg + p4);
        ushort4 kq4 = *(const ushort4*)((const unsigned short*)kg + p4);
        ushort4 v4 = *(const ushort4*)((const unsigned short*)vg + p4);
        rv[0]=bf2f(r4.x); rv[1]=bf2f(r4.y); rv[2]=bf2f(r4.z); rv[3]=bf2f(r4.w);
        kv[0]=bf2f(kq4.x); kv[1]=bf2f(kq4.y); kv[2]=bf2f(kq4.z); kv[3]=bf2f(kq4.w);
        vv[0]=bf2f(v4.x); vv[1]=bf2f(v4.y); vv[2]=bf2f(v4.z); vv[3]=bf2f(v4.w);
      }
      float4 off4 = *(const float4*)&prv[15*68 + k4];
      float4 cs4  = *(const float4*)&cur[tl*68 + k4];
      float4 cp4  = (tl == 0) ? off4 : *(const float4*)&cur[(tl-1)*68 + k4];
      float4 u4   = *(const float4*)&uL[k4];
      const float offa[4] = {off4.x,off4.y,off4.z,off4.w};
      const float csa[4]  = {cs4.x,cs4.y,cs4.z,cs4.w};
      const float cpa[4]  = {cp4.x,cp4.y,cp4.z,cp4.w};
      const float ua[4]   = {u4.x,u4.y,u4.z,u4.w};
      float rh[4], kh[4];
      float diagp = 0.f;
      #pragma unroll
      for (int j=0;j<4;j++){
        rh[j] = rv[j]*expf(cpa[j] - offa[j]);
        kh[j] = kv[j]*expf(offa[j] - csa[j]);
        diagp += rv[j]*ua[j]*kv[j];
      }
      rh0 = rh[0]; rh1 = rh[1]; rh2 = rh[2]; rh3 = rh[3];
      *(float4*)&rhat[tl*68 + k4] = make_float4(rh[0],rh[1],rh[2],rh[3]);
      *(float4*)&khat[tl*68 + k4] = make_float4(kh[0],kh[1],kh[2],kh[3]);
      *(float4*)&vB[tl*64 + k4]   = make_float4(vv[0],vv[1],vv[2],vv[3]);
      diagp += __shfl_xor(diagp, 1);
      diagp += __shfl_xor(diagp, 2);
      diagp += __shfl_xor(diagp, 4);
      diagp += __shfl_xor(diagp, 8);
      if ((tid & 15) == 0) aL[tl*16 + tl] = diagp;
      if (tl == 15){
        decL[k4+0] = expf(csa[0] - offa[0]);
        decL[k4+1] = expf(csa[1] - offa[1]);
        decL[k4+2] = expf(csa[2] - offa[2]);
        decL[k4+3] = expf(csa[3] - offa[3]);
      }
    }
    __syncthreads();

    { // phase C: strict-lower a[t,s] = rhat[t].khat[s]
      const int tl = tid >> 4, sl = tid & 15;
      if (sl < tl){
        const float4* rp = (const float4*)&rhat[tl*68];
        const float4* kp = (const float4*)&khat[sl*68];
        float a0=0.f,a1=0.f,a2=0.f,a3=0.f;
        #pragma unroll
        for (int q=0;q<16;q++){
          float4 rv4 = rp[q], kv4 = kp[q];
          a0 += rv4.x*kv4.x; a1 += rv4.y*kv4.y;
          a2 += rv4.z*kv4.z; a3 += rv4.w*kv4.w;
        }
        aL[tl*16 + sl] = (a0+a1)+(a2+a3);
      }
    }
    __syncthreads();

    { // phase D: out = tril(a)@v + rhat@P  (rhat via shfl broadcast)
      const int tl = tid >> 4, vq = (tid & 15)*4;
      float o0=0.f,o1=0.f,o2=0.f,o3=0.f;
      for (int sl=0; sl<=tl; sl++){
        const float av = aL[tl*16 + sl];
        float4 vf = *(const float4*)&vB[sl*64 + vq];
        o0 += av*vf.x; o1 += av*vf.y; o2 += av*vf.z; o3 += av*vf.w;
      }
      const int gbase = lane & 48;
      #pragma unroll
      for (int k2q=0;k2q<16;k2q++){
        const int src = gbase | k2q;
        const float r0 = __shfl(rh0, src, 64);
        const float r1 = __shfl(rh1, src, 64);
        const float r2 = __shfl(rh2, src, 64);
        const float r3 = __shfl(rh3, src, 64);
        float4 p0 = *(const float4*)&P[(k2q*4+0)*64 + vq];
        float4 p1 = *(const float4*)&P[(k2q*4+1)*64 + vq];
        float4 p2 = *(const float4*)&P[(k2q*4+2)*64 + vq];
        float4 p3 = *(const float4*)&P[(k2q*4+3)*64 + vq];
        o0 += r0*p0.x + r1*p1.x + r2*p2.x + r3*p3.x;
        o1 += r0*p0.y + r1*p1.y + r2*p2.y + r3*p3.y;
        o2 += r0*p0.z + r1*p1.z + r2*p2.z + r3*p3.z;
        o3 += r0*p0.w + r1*p1.w + r2*p2.w + r3*p3.w;
      }
      const size_t yp = (tokbase + t0 + tl)*1024 + colbase + vq;
      if (FUSED){
        float s  = o0+o1+o2+o3;
        float s2 = o0*o0+o1*o1+o2*o2+o3*o3;
        #pragma unroll
        for (int m=1; m<16; m<<=1){
          s  += __shfl_xor(s,  m);
          s2 += __shfl_xor(s2, m);
        }
        const float mean = s*(1.f/64.f);
        const float var  = s2*(1.f/64.f) - mean*mean;
        const float rstd = rsqrtf(var + 6.4e-4f);
        ushort4 gv4 = *(const ushort4*)(gg + yp);
        const float gvs[4] = {bf2f(gv4.x), bf2f(gv4.y), bf2f(gv4.z), bf2f(gv4.w)};
        const float os[4] = {o0,o1,o2,o3};
        ushort4 ov;
        unsigned short* ovp = (unsigned short*)&ov;
        #pragma unroll
        for (int j=0;j<4;j++){
          const float yn = (os[j] - mean)*rstd*lnwL[vq+j] + lnbL[vq+j];
          const float gv = gvs[j];
          const float sg = gv/(1.f + expf(-gv));
          ovp[j] = f2bf(yn*sg);
        }
        *(ushort4*)(outp + yp) = ov;
      } else {
        ushort4 ov; ov.x = f2bf(o0); ov.y = f2bf(o1); ov.z = f2bf(o2); ov.w = f2bf(o3);
        *(ushort4*)(outp + yp) = ov;
      }
    }
    __syncthreads();

    { // phase E: P = P*dec + (khat*dec)^T @ v
      const int vq = (tid & 15)*4;
      const int kq0 = tid >> 4;
      float dec_ii[4];
      #pragma unroll
      for (int ii=0;ii<4;ii++) dec_ii[ii] = decL[kq0 + ii*16];
      float pv[4][4];
      #pragma unroll
      for (int ii=0;ii<4;ii++){
        const int kq = kq0 + ii*16;
        const float dec = dec_ii[ii];
        float4 pf = *(const float4*)&P[kq*64 + vq];
        pv[ii][0] = pf.x*dec; pv[ii][1] = pf.y*dec; pv[ii][2] = pf.z*dec; pv[ii][3] = pf.w*dec;
      }
      for (int tl=0;tl<16;tl++){
        float4 vf = *(const float4*)&vB[tl*64 + vq];
        const float vr[4] = {vf.x, vf.y, vf.z, vf.w};
        #pragma unroll
        for (int ii=0;ii<4;ii++){
          const float khv = khat[tl*68 + kq0 + ii*16]*dec_ii[ii];
          #pragma unroll
          for (int j=0;j<4;j++) pv[ii][j] += khv*vr[j];
        }
      }
      #pragma unroll
      for (int ii=0;ii<4;ii++)
        *(float4*)&P[(kq0+ii*16)*64 + vq] = make_float4(pv[ii][0],pv[ii][1],pv[ii][2],pv[ii][3]);
    }
    __syncthreads();
  }
}

// ---------------------------------------------------------------------------
// act (tier-2 only): groupnorm * silu(g) -> bf16.
// ---------------------------------------------------------------------------
__global__ void act_k(const unsigned short* __restrict__ y, const unsigned short* __restrict__ g,
                      const float* __restrict__ lnw, const float* __restrict__ lnb,
                      unsigned short* __restrict__ act)
{
  const size_t tau = blockIdx.x;
  const int lane = threadIdx.x & 63;
  const int wave = threadIdx.x >> 6;
  #pragma unroll
  for (int hh=0; hh<4; hh++){
    const int h = wave*4 + hh;
    const size_t p = tau*1024 + (size_t)h*64 + lane;
    const float val = bf2f(y[p]);
    float s = val, s2 = val*val;
    #pragma unroll
    for (int m=32; m>=1; m>>=1){
      s  += __shfl_xor(s, m);
      s2 += __shfl_xor(s2, m);
    }
    const float mean = s*(1.f/64.f);
    const float var  = s2*(1.f/64.f) - mean*mean;
    const int dd = h*64 + lane;
    float yn = (val - mean)*rsqrtf(var + 6.4e-4f);
    yn = yn*lnw[dd] + lnb[dd];
    const float gv = bf2f(g[p]);
    const float sg = gv/(1.f + expf(-gv));
    act[p] = f2bf(yn*sg);
  }
}

// ===========================================================================
extern "C" void kernel_launch(void* const* d_in, const int* in_sizes, int n_in,
                              void* d_out, int out_size, void* d_ws, size_t ws_size,
                              hipStream_t stream)
{
  (void)in_sizes; (void)n_in; (void)out_size;
  const float* x     = (const float*)d_in[0];
  const float* maa_x = (const float*)d_in[1];
  const float* maa_r = (const float*)d_in[2];
  const float* maa_w = (const float*)d_in[3];
  const float* maa_k = (const float*)d_in[4];
  const float* maa_v = (const float*)d_in[5];
  const float* maa_g = (const float*)d_in[6];
  const float* w1    = (const float*)d_in[7];
  const float* w2    = (const float*)d_in[8];
  const float* dw1   = (const float*)d_in[9];
  const float* dw2   = (const float*)d_in[10];
  const float* tdec  = (const float*)d_in[11];
  const float* faaaa = (const float*)d_in[12];
  const float* Wr    = (const float*)d_in[13];
  const float* Wk    = (const float*)d_in[14];
  const float* Wv    = (const float*)d_in[15];
  const float* Wg    = (const float*)d_in[16];
  const float* Wo    = (const float*)d_in[17];
  const float* lnw   = (const float*)d_in[18];
  const float* lnb   = (const float*)d_in[19];

  char* ws = (char*)d_ws;
  const dim3 tb32(32, 8);
  const size_t MB16 = (size_t)8192*1024*2;   // 16MB (one bf16 token-matrix)

  // ---------- tier-1 (~186MB) ----------
  {
    size_t o = 0;
    auto take = [&o](size_t nb){ size_t r = o; o += (nb + 255) & ~(size_t)255; return r; };
    unsigned short* WtG = (unsigned short*)(ws + take((size_t)1024*1024*2));
    unsigned short* WtO = (unsigned short*)(ws + take((size_t)1024*1024*2));
    unsigned short* W1t = (unsigned short*)(ws + take((size_t)160*1024*2));
    unsigned short* WrH = (unsigned short*)(ws + take((size_t)1024*1024*2));
    unsigned short* WrL = (unsigned short*)(ws + take((size_t)1024*1024*2));
    unsigned short* WkH = (unsigned short*)(ws + take((size_t)1024*1024*2));
    unsigned short* WkL = (unsigned short*)(ws + take((size_t)1024*1024*2));
    unsigned short* WvH = (unsigned short*)(ws + take((size_t)1024*1024*2));
    unsigned short* WvL = (unsigned short*)(ws + take((size_t)1024*1024*2));
    unsigned short* D1H = (unsigned short*)(ws + take((size_t)64*1024*2));
    unsigned short* D1L = (unsigned short*)(ws + take((size_t)64*1024*2));
    unsigned short* D2H = (unsigned short*)(ws + take((size_t)1024*64*2));
    unsigned short* D2L = (unsigned short*)(ws + take((size_t)1024*64*2));
    unsigned short* W2tH= (unsigned short*)(ws + take((size_t)5120*32*2));
    unsigned short* W2tL= (unsigned short*)(ws + take((size_t)5120*32*2));
    unsigned short* Th  = (unsigned short*)(ws + take((size_t)8192*64*2));
    unsigned short* Tl  = (unsigned short*)(ws + take((size_t)8192*64*2));
    unsigned short* M5h = (unsigned short*)(ws + take((size_t)8192*160*2));  // -> wse f32
    unsigned short* M5l = (unsigned short*)(ws + take((size_t)8192*160*2));
    char*  Sxxx  = ws + take(MB16);            // xxx bf16 -> g bf16
    char*  slotRA = ws + take(2*MB16);         // xrh+xrl -> k32 f32
    char*  slotKB = ws + take(2*MB16);         // xkh+xkl -> v32 f32
    char*  slotVC = ws + take(2*MB16);         // xvh+xvl -> wkv f32 + st f32
    char*  slotOA = ws + take(2*MB16);         // xwh+xwl -> r32 f32
    char*  Sxg   = ws + take(MB16);            // xg bf16 -> act bf16

    if (o <= ws_size){
      unsigned short* xxxb = (unsigned short*)Sxxx;
      unsigned short* gb   = (unsigned short*)Sxxx;
      float* wse = (float*)M5h;                 // m5 dead after gemm_mix
      unsigned short* xrh = (unsigned short*)slotRA;
      unsigned short* xrl = (unsigned short*)(slotRA + MB16);
      float* k32 = (float*)slotRA;
      unsigned short* xkh = (unsigned short*)slotKB;
      unsigned short* xkl = (unsigned short*)(slotKB + MB16);
      float* v32 = (float*)slotKB;
      unsigned short* xvh = (unsigned short*)slotVC;
      unsigned short* xvl = (unsigned short*)(slotVC + MB16);
      float* wkvb = (float*)slotVC;
      float* st   = (float*)(slotVC + MB16);
      unsigned short* xwh = (unsigned short*)slotOA;
      unsigned short* xwl = (unsigned short*)(slotOA + MB16);
      float* r32  = (float*)slotOA;
      unsigned short* xgb  = (unsigned short*)Sxg;
      unsigned short* actb = (unsigned short*)Sxg;
      float* wlogb = (float*)d_out;             // wlog -> cum (in place)

      transpose_k<1><<<dim3(32,32), tb32, 0, stream>>>(Wg, WtG, 1024, 1024);
      transpose_k<1><<<dim3(32,32), tb32, 0, stream>>>(Wo, WtO, 1024, 1024);
      transpose_k<1><<<dim3(5,32),  tb32, 0, stream>>>(w1, W1t, 1024, 160);
      transpose_split<<<dim3(32,32), tb32, 0, stream>>>(Wr, WrH, WrL, 1024, 1024);
      transpose_split<<<dim3(32,32), tb32, 0, stream>>>(Wk, WkH, WkL, 1024, 1024);
      transpose_split<<<dim3(32,32), tb32, 0, stream>>>(Wv, WvH, WvL, 1024, 1024);
      transpose_split<<<dim3(2,32),  tb32, 0, stream>>>(dw1, D1H, D1L, 1024, 64);
      transpose_split<<<dim3(32,2),  tb32, 0, stream>>>(dw2, D2H, D2L, 64, 1024);
      build_w2t<<<640, 256, 0, stream>>>(w2, W2tH, W2tL);

      prep_k<<<8192, 256, 0, stream>>>(x, maa_x, xxxb);
      gemm_tanh_bf16<<<dim3(64,2), 256, 0, stream>>>(xxxb, W1t, M5h, M5l, 8192, 160, 1024);
      gemm_mix<<<dim3(40,64), 256, 0, stream>>>(W2tH, W2tL, M5h, M5l, x, maa_x,
                                                maa_w, maa_k, maa_v, maa_r, maa_g,
                                                xwh, xwl, xkh, xkl, xvh, xvl,
                                                xrh, xrl, xgb);

      // decay path: t = tanh(xw@dw1) -> wlog = -min(exp(tdec + t@dw2), 5.298)
      gemm_tanh64<<<dim3(64,1), 256, 0, stream>>>(xwh, xwl, D1H, D1L, Th, Tl, 8192, 64, 1024);
      gemm_split2<2><<<dim3(64,8), 256, 0, stream>>>(Th, Tl, D2H, D2L, wlogb, tdec, 8192, 1024, 64);

      gemm_bf16<<<dim3(64,8), 256, 0, stream>>>(xgb, WtG, gb, 8192, 1024, 1024, 1);
      gemm_split2<0><<<dim3(64,8), 256, 0, stream>>>(xrh, xrl, WrH, WrL, r32, nullptr, 8192, 1024, 1024);
      gemm_split2<0><<<dim3(64,8), 256, 0, stream>>>(xkh, xkl, WkH, WkL, k32, nullptr, 8192, 1024, 1024);
      gemm_split2<0><<<dim3(64,8), 256, 0, stream>>>(xvh, xvl, WvH, WvL, v32, nullptr, 8192, 1024, 1024);

      wkv_pass1<1><<<1024, 256, 0, stream>>>(wlogb, k32, v32, wkvb, wse);
      wkv_scan    <<<512,  256, 0, stream>>>(wkvb, wse, st);
      wkv_pass3<1,1><<<1024, 256, 0, stream>>>(wlogb, r32, k32, v32, st, faaaa,
                                               gb, lnw, lnb, actb);

      gemm_bf16<<<dim3(64,8), 256, 0, stream>>>(actb, WtO, d_out, 8192, 1024, 1024, 0);
      return;
    }
  }

  // ---------- tier-2 fallback (~112MB, all-bf16) ----------
  {
    size_t o = 0;
    auto take = [&o](size_t nb){ size_t r = o; o += (nb + 255) & ~(size_t)255; return r; };
    unsigned short* WtR  = (unsigned short*)(ws + take((size_t)1024*1024*2));
    unsigned short* WtK  = (unsigned short*)(ws + take((size_t)1024*1024*2));
    unsigned short* WtV  = (unsigned short*)(ws + take((size_t)1024*1024*2));
    unsigned short* WtG  = (unsigned short*)(ws + take((size_t)1024*1024*2));
    unsigned short* WtO  = (unsigned short*)(ws + take((size_t)1024*1024*2));
    unsigned short* W1t  = (unsigned short*)(ws + take((size_t)160*1024*2));
    unsigned short* xxxb = (unsigned short*)(ws + take(MB16));
    float*          mraw = (float*)         (ws + take((size_t)8192*160*4));
    unsigned short* xrb  = (unsigned short*)(ws + take(MB16));
    unsigned short* xkb  = (unsigned short*)(ws + take(MB16));
    unsigned short* xvb  = (unsigned short*)(ws + take(MB16));
    unsigned short* xgb  = (unsigned short*)(ws + take(MB16));
    unsigned short* kb   = (unsigned short*)(ws + take(MB16));
    float*          wseb = (float*)         (ws + take((size_t)1024*64*4));
    if (o > ws_size) return;

    float*          wlogb = (float*)d_out;
    unsigned short* rb    = xxxb;
    unsigned short* vb    = xrb;
    unsigned short* gb    = xkb;
    float*          wkvb  = (float*)xvb;
    float*          stb   = (float*)xgb;
    unsigned short* yb    = xvb;
    unsigned short* actb  = kb;

    transpose_k<1><<<dim3(32,32), tb32, 0, stream>>>(Wr, WtR, 1024, 1024);
    transpose_k<1><<<dim3(32,32), tb32, 0, stream>>>(Wk, WtK, 1024, 1024);
    transpose_k<1><<<dim3(32,32), tb32, 0, stream>>>(Wv, WtV, 1024, 1024);
    transpose_k<1><<<dim3(32,32), tb32, 0, stream>>>(Wg, WtG, 1024, 1024);
    transpose_k<1><<<dim3(32,32), tb32, 0, stream>>>(Wo, WtO, 1024, 1024);
    transpose_k<1><<<dim3(5,32),  tb32, 0, stream>>>(w1, W1t, 1024, 160);

    prep_k<<<8192, 256, 0, stream>>>(x, maa_x, xxxb);
    gemm_bf16<<<dim3(64,2), 256, 0, stream>>>(xxxb, W1t, mraw, 8192, 160, 1024, 0);
    mix_fb<<<1024, 256, 0, stream>>>(x, mraw, maa_x, maa_w, maa_k, maa_v, maa_r, maa_g,
                                     w2, dw1, dw2, tdec,
                                     xrb, xkb, xvb, xgb, wlogb);

    gemm_bf16<<<dim3(64,8), 256, 0, stream>>>(xrb, WtR, rb, 8192, 1024, 1024, 1);
    gemm_bf16<<<dim3(64,8), 256, 0, stream>>>(xkb, WtK, kb, 8192, 1024, 1024, 1);
    gemm_bf16<<<dim3(64,8), 256, 0, stream>>>(xvb, WtV, vb, 8192, 1024, 1024, 1);
    gemm_bf16<<<dim3(64,8), 256, 0, stream>>>(xgb, WtG, gb, 8192, 1024, 1024, 1);

    wkv_pass1<0><<<1024, 256, 0, stream>>>(wlogb, kb, vb, wkvb, wseb);
    wkv_scan    <<<512,  256, 0, stream>>>(wkvb, wseb, stb);
    wkv_pass3<0,0><<<1024, 256, 0, stream>>>(wlogb, rb, kb, vb, stb, faaaa,
                                             nullptr, nullptr, nullptr, yb);

    act_k<<<8192, 256, 0, stream>>>(yb, gb, lnw, lnb, actb);
    gemm_bf16<<<dim3(64,8), 256, 0, stream>>>(actb, WtO, d_out, 8192, 1024, 1024, 0);
  }
}

// Round 11
// 532.923 us; speedup vs baseline: 1.3072x; 1.3026x over previous
//
#include <hip/hip_runtime.h>

// ============================================================================
// RWKV6 TimeMix forward, MI355X.  B=2 L=4096 D=1024 H=16 DH=64 T_CHUNK=128.
// Tier-1: mix einsum as swapped split MFMA GEMM w/ LDS-bounced epilogue;
//   r,k,v via SINGLE fp16 MFMA GEMMs (10-bit mantissa);
//   decay path via split-bf16 GEMMs (exponent-sensitive);
//   pass1 writes cumsum in-place (d_out); pass3 v2 (LDS rhat, 4 blocks/CU);
//   fused GN+SiLU.
// Tier-2 fallback (~112MB): all-bf16 pipeline.
// ============================================================================

typedef __attribute__((ext_vector_type(8))) short bf16x8;
typedef __attribute__((ext_vector_type(8))) _Float16 f16x8;
typedef __attribute__((ext_vector_type(4))) float f32x4;

static __device__ __forceinline__ unsigned short f2bf(float f){
  unsigned int u = __float_as_uint(f);
  u += 0x7FFFu + ((u >> 16) & 1u);
  return (unsigned short)(u >> 16);
}
static __device__ __forceinline__ float bf2f(unsigned short h){
  return __uint_as_float(((unsigned int)h) << 16);
}
static __device__ __forceinline__ unsigned short f2h(float f){
  _Float16 h = (_Float16)f;
  return *(unsigned short*)&h;
}

// ---------------------------------------------------------------------------
// transpose: src[R][C] f32 -> dst[C][R].  OUT: 0=f32, 1=bf16, 2=fp16.
// ---------------------------------------------------------------------------
template<int OUT>
__global__ void transpose_k(const float* __restrict__ src, void* __restrict__ dst,
                            int R, int C)
{
  __shared__ float tile[32][33];
  const int c0 = blockIdx.x*32, r0 = blockIdx.y*32;
  const int tx = threadIdx.x, ty = threadIdx.y;
  #pragma unroll
  for (int i=0;i<4;i++)
    tile[ty+i*8][tx] = src[(size_t)(r0+ty+i*8)*C + (c0+tx)];
  __syncthreads();
  #pragma unroll
  for (int i=0;i<4;i++){
    float v = tile[tx][ty+i*8];
    size_t o = (size_t)(c0+ty+i*8)*R + (r0+tx);
    if (OUT==1)      ((unsigned short*)dst)[o] = f2bf(v);
    else if (OUT==2) ((unsigned short*)dst)[o] = f2h(v);
    else             ((float*)dst)[o] = v;
  }
}

// transpose f32 -> bf16 hi + bf16 lo residual
__global__ void transpose_split(const float* __restrict__ src,
                                unsigned short* __restrict__ dh,
                                unsigned short* __restrict__ dl, int R, int C)
{
  __shared__ float tile[32][33];
  const int c0 = blockIdx.x*32, r0 = blockIdx.y*32;
  const int tx = threadIdx.x, ty = threadIdx.y;
  #pragma unroll
  for (int i=0;i<4;i++)
    tile[ty+i*8][tx] = src[(size_t)(r0+ty+i*8)*C + (c0+tx)];
  __syncthreads();
  #pragma unroll
  for (int i=0;i<4;i++){
    float v = tile[tx][ty+i*8];
    size_t o = (size_t)(c0+ty+i*8)*R + (r0+tx);
    unsigned short h = f2bf(v);
    dh[o] = h;
    dl[o] = f2bf(v - bf2f(h));
  }
}

// w2 [5][32][1024] -> w2t [5120][32] hi/lo  (w2t[n*1024+d][f] = w2[n][f][d])
__global__ void build_w2t(const float* __restrict__ w2,
                          unsigned short* __restrict__ th,
                          unsigned short* __restrict__ tl)
{
  const int idx = blockIdx.x*256 + threadIdx.x;   // 163840 total
  const int col = idx >> 5, f = idx & 31;
  const int n = col >> 10, d = col & 1023;
  const float v = w2[(size_t)n*32768 + (size_t)f*1024 + d];
  const unsigned short h = f2bf(v);
  th[idx] = h;
  tl[idx] = f2bf(v - bf2f(h));
}

// ---------------------------------------------------------------------------
// bf16 MFMA GEMM: C[M][N] = A[M][K]*B, A bf16 row-major, Bt = B^T bf16 [N][K].
// ---------------------------------------------------------------------------
__launch_bounds__(256)
__global__ void gemm_bf16(const unsigned short* __restrict__ A,
                          const unsigned short* __restrict__ Bt,
                          void* __restrict__ Cp,
                          int M, int N, int K, int c_bf16)
{
  __shared__ unsigned short As[128*32];
  __shared__ unsigned short Bs[128*32];
  const int tid  = threadIdx.x;
  const int row0 = blockIdx.x*128, n0 = blockIdx.y*128;
  const int wid  = tid >> 6, lane = tid & 63;
  const int wm   = (wid >> 1)*64, wn = (wid & 1)*64;
  const int sr   = tid >> 2;
  const int sk   = (tid & 3)*8;
  const int laneq = (lane >> 4)*8;
  const int lanem = lane & 15;

  f32x4 acc[4][4];
  #pragma unroll
  for (int i=0;i<4;i++)
    #pragma unroll
    for (int j=0;j<4;j++) acc[i][j] = (f32x4){0.f,0.f,0.f,0.f};

  for (int kt = 0; kt < K; kt += 32){
    uint4 a0 = *(const uint4*)(A + (size_t)(row0+sr   )*K + kt + sk);
    uint4 a1 = *(const uint4*)(A + (size_t)(row0+sr+64)*K + kt + sk);
    uint4 z; z.x=0u; z.y=0u; z.z=0u; z.w=0u;
    const int nb0 = n0+sr, nb1 = n0+sr+64;
    uint4 b0 = (nb0 < N) ? *(const uint4*)(Bt + (size_t)nb0*K + kt + sk) : z;
    uint4 b1 = (nb1 < N) ? *(const uint4*)(Bt + (size_t)nb1*K + kt + sk) : z;
    *(uint4*)(As + sr*32 + sk)      = a0;
    *(uint4*)(As + (sr+64)*32 + sk) = a1;
    *(uint4*)(Bs + sr*32 + sk)      = b0;
    *(uint4*)(Bs + (sr+64)*32 + sk) = b1;
    __syncthreads();

    bf16x8 af[4], bfr[4];
    #pragma unroll
    for (int mi=0;mi<4;mi++)
      af[mi] = *(const bf16x8*)(As + (wm + mi*16 + lanem)*32 + laneq);
    #pragma unroll
    for (int ni=0;ni<4;ni++)
      bfr[ni] = *(const bf16x8*)(Bs + (wn + ni*16 + lanem)*32 + laneq);
    #pragma unroll
    for (int mi=0;mi<4;mi++)
      #pragma unroll
      for (int ni=0;ni<4;ni++)
        acc[mi][ni] = __builtin_amdgcn_mfma_f32_16x16x32_bf16(af[mi], bfr[ni], acc[mi][ni], 0,0,0);
    __syncthreads();
  }

  const int rr = (lane >> 4)*4, cc = lane & 15;
  #pragma unroll
  for (int mi=0;mi<4;mi++){
    #pragma unroll
    for (int ni=0;ni<4;ni++){
      const int cg = n0 + wn + ni*16 + cc;
      if (cg < N){
        #pragma unroll
        for (int q=0;q<4;q++){
          const int rg = row0 + wm + mi*16 + rr + q;
          float v = acc[mi][ni][q];
          if (c_bf16) ((unsigned short*)Cp)[(size_t)rg*N + cg] = f2bf(v);
          else        ((float*)Cp)[(size_t)rg*N + cg] = v;
        }
      }
    }
  }
}

// ---------------------------------------------------------------------------
// fp16 MFMA GEMM: C[M][N] f32 = A[M][K] fp16 * B, Bt = B^T fp16 [N][K].
// M,N % 128 == 0.  Single MFMA per fragment (10-bit mantissa precision).
// ---------------------------------------------------------------------------
__launch_bounds__(256)
__global__ void gemm_fp16(const unsigned short* __restrict__ A,
                          const unsigned short* __restrict__ Bt,
                          float* __restrict__ C,
                          int M, int N, int K)
{
  __shared__ unsigned short As[128*32];
  __shared__ unsigned short Bs[128*32];
  const int tid  = threadIdx.x;
  const int row0 = blockIdx.x*128, n0 = blockIdx.y*128;
  const int wid  = tid >> 6, lane = tid & 63;
  const int wm   = (wid >> 1)*64, wn = (wid & 1)*64;
  const int sr   = tid >> 2;
  const int sk   = (tid & 3)*8;
  const int laneq = (lane >> 4)*8;
  const int lanem = lane & 15;

  f32x4 acc[4][4];
  #pragma unroll
  for (int i=0;i<4;i++)
    #pragma unroll
    for (int j=0;j<4;j++) acc[i][j] = (f32x4){0.f,0.f,0.f,0.f};

  for (int kt = 0; kt < K; kt += 32){
    uint4 a0 = *(const uint4*)(A + (size_t)(row0+sr   )*K + kt + sk);
    uint4 a1 = *(const uint4*)(A + (size_t)(row0+sr+64)*K + kt + sk);
    uint4 b0 = *(const uint4*)(Bt + (size_t)(n0+sr   )*K + kt + sk);
    uint4 b1 = *(const uint4*)(Bt + (size_t)(n0+sr+64)*K + kt + sk);
    *(uint4*)(As + sr*32 + sk)      = a0;
    *(uint4*)(As + (sr+64)*32 + sk) = a1;
    *(uint4*)(Bs + sr*32 + sk)      = b0;
    *(uint4*)(Bs + (sr+64)*32 + sk) = b1;
    __syncthreads();

    f16x8 af[4], bfr[4];
    #pragma unroll
    for (int mi=0;mi<4;mi++)
      af[mi] = *(const f16x8*)(As + (wm + mi*16 + lanem)*32 + laneq);
    #pragma unroll
    for (int ni=0;ni<4;ni++)
      bfr[ni] = *(const f16x8*)(Bs + (wn + ni*16 + lanem)*32 + laneq);
    #pragma unroll
    for (int mi=0;mi<4;mi++)
      #pragma unroll
      for (int ni=0;ni<4;ni++)
        acc[mi][ni] = __builtin_amdgcn_mfma_f32_16x16x32_f16(af[mi], bfr[ni], acc[mi][ni], 0,0,0);
    __syncthreads();
  }

  const int rr = (lane >> 4)*4, cc = lane & 15;
  #pragma unroll
  for (int mi=0;mi<4;mi++)
    #pragma unroll
    for (int ni=0;ni<4;ni++){
      const int cg = n0 + wn + ni*16 + cc;
      #pragma unroll
      for (int q=0;q<4;q++)
        C[(size_t)(row0 + wm + mi*16 + rr + q)*N + cg] = acc[mi][ni][q];
    }
}

// ---------------------------------------------------------------------------
// bf16 GEMM with tanh hi/lo epilogue (for m5).  N guarded.
// ---------------------------------------------------------------------------
__launch_bounds__(256)
__global__ void gemm_tanh_bf16(const unsigned short* __restrict__ A,
                               const unsigned short* __restrict__ Bt,
                               unsigned short* __restrict__ Th,
                               unsigned short* __restrict__ Tl,
                               int M, int N, int K)
{
  __shared__ unsigned short As[128*32];
  __shared__ unsigned short Bs[128*32];
  const int tid  = threadIdx.x;
  const int row0 = blockIdx.x*128, n0 = blockIdx.y*128;
  const int wid  = tid >> 6, lane = tid & 63;
  const int wm   = (wid >> 1)*64, wn = (wid & 1)*64;
  const int sr   = tid >> 2;
  const int sk   = (tid & 3)*8;
  const int laneq = (lane >> 4)*8;
  const int lanem = lane & 15;

  f32x4 acc[4][4];
  #pragma unroll
  for (int i=0;i<4;i++)
    #pragma unroll
    for (int j=0;j<4;j++) acc[i][j] = (f32x4){0.f,0.f,0.f,0.f};

  for (int kt = 0; kt < K; kt += 32){
    uint4 a0 = *(const uint4*)(A + (size_t)(row0+sr   )*K + kt + sk);
    uint4 a1 = *(const uint4*)(A + (size_t)(row0+sr+64)*K + kt + sk);
    uint4 z; z.x=0u; z.y=0u; z.z=0u; z.w=0u;
    const int nb0 = n0+sr, nb1 = n0+sr+64;
    uint4 b0 = (nb0 < N) ? *(const uint4*)(Bt + (size_t)nb0*K + kt + sk) : z;
    uint4 b1 = (nb1 < N) ? *(const uint4*)(Bt + (size_t)nb1*K + kt + sk) : z;
    *(uint4*)(As + sr*32 + sk)      = a0;
    *(uint4*)(As + (sr+64)*32 + sk) = a1;
    *(uint4*)(Bs + sr*32 + sk)      = b0;
    *(uint4*)(Bs + (sr+64)*32 + sk) = b1;
    __syncthreads();

    bf16x8 af[4], bfr[4];
    #pragma unroll
    for (int mi=0;mi<4;mi++)
      af[mi] = *(const bf16x8*)(As + (wm + mi*16 + lanem)*32 + laneq);
    #pragma unroll
    for (int ni=0;ni<4;ni++)
      bfr[ni] = *(const bf16x8*)(Bs + (wn + ni*16 + lanem)*32 + laneq);
    #pragma unroll
    for (int mi=0;mi<4;mi++)
      #pragma unroll
      for (int ni=0;ni<4;ni++)
        acc[mi][ni] = __builtin_amdgcn_mfma_f32_16x16x32_bf16(af[mi], bfr[ni], acc[mi][ni], 0,0,0);
    __syncthreads();
  }

  const int rr = (lane >> 4)*4, cc = lane & 15;
  #pragma unroll
  for (int mi=0;mi<4;mi++){
    #pragma unroll
    for (int ni=0;ni<4;ni++){
      const int cg = n0 + wn + ni*16 + cc;
      if (cg < N){
        #pragma unroll
        for (int q=0;q<4;q++){
          const int rg = row0 + wm + mi*16 + rr + q;
          const float t = tanhf(acc[mi][ni][q]);
          const unsigned short h = f2bf(t);
          Th[(size_t)rg*N + cg] = h;
          Tl[(size_t)rg*N + cg] = f2bf(t - bf2f(h));
        }
      }
    }
  }
}

// ---------------------------------------------------------------------------
// gemm_mix: Z[d][tok] = w2t-tile @ m5^T (single K=32 step), LDS-bounce,
// coalesced lerp epilogue.  Outputs: n=0 -> xw bf16 hi/lo; n=1,2,3 ->
// xk/xv/xr fp16; n=4 -> xg bf16.  grid (40, 64).
// ---------------------------------------------------------------------------
__launch_bounds__(256)
__global__ void gemm_mix(const unsigned short* __restrict__ w2th,
                         const unsigned short* __restrict__ w2tl,
                         const unsigned short* __restrict__ m5h,
                         const unsigned short* __restrict__ m5l,
                         const float* __restrict__ x,
                         const float* __restrict__ maa_x,
                         const float* __restrict__ maa_w,
                         const float* __restrict__ maa_k,
                         const float* __restrict__ maa_v,
                         const float* __restrict__ maa_r,
                         const float* __restrict__ maa_g,
                         unsigned short* __restrict__ xwh, unsigned short* __restrict__ xwl,
                         unsigned short* __restrict__ xk16, unsigned short* __restrict__ xv16,
                         unsigned short* __restrict__ xr16, unsigned short* __restrict__ xg)
{
  __shared__ __attribute__((aligned(16))) float Zs[128*136];   // 69632 B
  unsigned short* AhS = (unsigned short*)Zs;        // staging aliases Zs
  unsigned short* AlS = AhS + 4096;
  unsigned short* BhS = AhS + 8192;
  unsigned short* BlS = AhS + 12288;
  const int tid  = threadIdx.x;
  const int row0 = blockIdx.x*128;          // d dimension (0..5120)
  const int col0 = blockIdx.y*128;          // token dimension
  const int n    = row0 >> 10;              // uniform per block
  const int wid  = tid >> 6, lane = tid & 63;
  const int wm   = (wid >> 1)*64, wn = (wid & 1)*64;
  const int sr   = tid >> 2;
  const int sk   = (tid & 3)*8;
  const int laneq = (lane >> 4)*8;
  const int lanem = lane & 15;

  { // stage A (w2t rows) and B (m5 rows, K-window n*32)
    const size_t a0 = (size_t)(row0+sr)*32 + sk;
    const size_t a1 = (size_t)(row0+sr+64)*32 + sk;
    *(uint4*)(AhS + sr*32 + sk)      = *(const uint4*)(w2th + a0);
    *(uint4*)(AhS + (sr+64)*32 + sk) = *(const uint4*)(w2th + a1);
    *(uint4*)(AlS + sr*32 + sk)      = *(const uint4*)(w2tl + a0);
    *(uint4*)(AlS + (sr+64)*32 + sk) = *(const uint4*)(w2tl + a1);
    const size_t b0 = (size_t)(col0+sr)*160 + n*32 + sk;
    const size_t b1 = (size_t)(col0+sr+64)*160 + n*32 + sk;
    *(uint4*)(BhS + sr*32 + sk)      = *(const uint4*)(m5h + b0);
    *(uint4*)(BhS + (sr+64)*32 + sk) = *(const uint4*)(m5h + b1);
    *(uint4*)(BlS + sr*32 + sk)      = *(const uint4*)(m5l + b0);
    *(uint4*)(BlS + (sr+64)*32 + sk) = *(const uint4*)(m5l + b1);
  }
  __syncthreads();

  f32x4 acc[4][4];
  #pragma unroll
  for (int i=0;i<4;i++)
    #pragma unroll
    for (int j=0;j<4;j++) acc[i][j] = (f32x4){0.f,0.f,0.f,0.f};

  {
    bf16x8 ahf[4], alf[4], bhf[4], blf[4];
    #pragma unroll
    for (int mi=0;mi<4;mi++){
      ahf[mi] = *(const bf16x8*)(AhS + (wm + mi*16 + lanem)*32 + laneq);
      alf[mi] = *(const bf16x8*)(AlS + (wm + mi*16 + lanem)*32 + laneq);
    }
    #pragma unroll
    for (int ni=0;ni<4;ni++){
      bhf[ni] = *(const bf16x8*)(BhS + (wn + ni*16 + lanem)*32 + laneq);
      blf[ni] = *(const bf16x8*)(BlS + (wn + ni*16 + lanem)*32 + laneq);
    }
    #pragma unroll
    for (int mi=0;mi<4;mi++)
      #pragma unroll
      for (int ni=0;ni<4;ni++){
        acc[mi][ni] = __builtin_amdgcn_mfma_f32_16x16x32_bf16(ahf[mi], bhf[ni], acc[mi][ni], 0,0,0);
        acc[mi][ni] = __builtin_amdgcn_mfma_f32_16x16x32_bf16(ahf[mi], blf[ni], acc[mi][ni], 0,0,0);
        acc[mi][ni] = __builtin_amdgcn_mfma_f32_16x16x32_bf16(alf[mi], bhf[ni], acc[mi][ni], 0,0,0);
      }
  }
  __syncthreads();   // staging fully consumed -> reuse as Zs

  { // scatter acc into Zs[tokL][dL] (stride 136)
    const int rr = (lane >> 4)*4, cc = lane & 15;
    #pragma unroll
    for (int mi=0;mi<4;mi++){
      const int dL0 = wm + mi*16 + rr;
      #pragma unroll
      for (int ni=0;ni<4;ni++){
        const int tokL = wn + ni*16 + cc;
        #pragma unroll
        for (int q=0;q<4;q++)
          Zs[tokL*136 + dL0 + q] = acc[mi][ni][q];
      }
    }
  }
  __syncthreads();

  { // coalesced lerp epilogue
    const int dbase = row0 & 1023;
    const float* cnp = (n==0)?maa_w:(n==1)?maa_k:(n==2)?maa_v:(n==3)?maa_r:maa_g;
    unsigned short* hp = (n==0)?xwh:(n==1)?xk16:(n==2)?xv16:(n==3)?xr16:xg;
    const int mode = (n==0) ? 0 : (n==4) ? 2 : 1;   // 0=bf16 hi/lo, 1=fp16, 2=bf16
    #pragma unroll
    for (int i=0;i<16;i++){
      const int idx = tid + 256*i;        // 0..4095
      const int tokL = idx >> 5;          // 0..127
      const int d4 = (idx & 31)*4;        // 0..124
      const int tok = col0 + tokL;
      const int dd = dbase + d4;
      const size_t px = (size_t)tok*1024 + dd;
      float4 z4  = *(const float4*)&Zs[tokL*136 + d4];
      float4 mx4 = *(const float4*)(maa_x + dd);
      float4 cn4 = *(const float4*)(cnp + dd);
      float4 xc4 = *(const float4*)(x + px);
      float4 xp4;
      if ((tok & 4095) == 0) xp4 = make_float4(0.f,0.f,0.f,0.f);
      else                   xp4 = *(const float4*)(x + px - 1024);
      const float za[4]  = {z4.x,z4.y,z4.z,z4.w};
      const float xca[4] = {xc4.x,xc4.y,xc4.z,xc4.w};
      const float xpa[4] = {xp4.x,xp4.y,xp4.z,xp4.w};
      const float mxa[4] = {mx4.x,mx4.y,mx4.z,mx4.w};
      const float cna[4] = {cn4.x,cn4.y,cn4.z,cn4.w};
      ushort4 hv, lv;
      unsigned short* hq = (unsigned short*)&hv;
      unsigned short* lq = (unsigned short*)&lv;
      #pragma unroll
      for (int j=0;j<4;j++){
        const float xx = xpa[j] - xca[j];
        const float v  = xca[j] + xx*mxa[j] + xx*((cna[j]-mxa[j]) + za[j]);
        if (mode == 0){
          const unsigned short h = f2bf(v);
          hq[j] = h;
          lq[j] = f2bf(v - bf2f(h));
        } else if (mode == 1){
          hq[j] = f2h(v);
        } else {
          hq[j] = f2bf(v);
        }
      }
      *(ushort4*)(hp + px) = hv;
      if (mode == 0) *(ushort4*)(xwl + px) = lv;
    }
  }
}

// ---------------------------------------------------------------------------
// split GEMM (pre-decomposed hi/lo): C = AhBh + AhBl + AlBh.  Register staging.
// EPI 0: f32 store.  EPI 2: wlog = -min(exp(bias[col]+acc), 5.2983174) f32.
// ---------------------------------------------------------------------------
template<int EPI>
__launch_bounds__(256)
__global__ void gemm_split2(const unsigned short* __restrict__ Ah,
                            const unsigned short* __restrict__ Al,
                            const unsigned short* __restrict__ Bh,
                            const unsigned short* __restrict__ Bl,
                            float* __restrict__ C, const float* __restrict__ bias,
                            int M, int N, int K)
{
  __shared__ unsigned short AhS[128*32], AlS[128*32];
  __shared__ unsigned short BhS[128*32], BlS[128*32];
  const int tid  = threadIdx.x;
  const int row0 = blockIdx.x*128, n0 = blockIdx.y*128;
  const int wid  = tid >> 6, lane = tid & 63;
  const int wm   = (wid >> 1)*64, wn = (wid & 1)*64;
  const int sr   = tid >> 2;
  const int sk   = (tid & 3)*8;
  const int laneq = (lane >> 4)*8;
  const int lanem = lane & 15;

  f32x4 acc[4][4];
  #pragma unroll
  for (int i=0;i<4;i++)
    #pragma unroll
    for (int j=0;j<4;j++) acc[i][j] = (f32x4){0.f,0.f,0.f,0.f};

  for (int kt = 0; kt < K; kt += 32){
    const size_t ra0 = (size_t)(row0+sr)*K + kt + sk;
    const size_t ra1 = (size_t)(row0+sr+64)*K + kt + sk;
    const size_t rb0 = (size_t)(n0 +sr)*K + kt + sk;
    const size_t rb1 = (size_t)(n0 +sr+64)*K + kt + sk;
    uint4 ah0 = *(const uint4*)(Ah + ra0);
    uint4 ah1 = *(const uint4*)(Ah + ra1);
    uint4 al0 = *(const uint4*)(Al + ra0);
    uint4 al1 = *(const uint4*)(Al + ra1);
    uint4 bh0 = *(const uint4*)(Bh + rb0);
    uint4 bh1 = *(const uint4*)(Bh + rb1);
    uint4 bl0 = *(const uint4*)(Bl + rb0);
    uint4 bl1 = *(const uint4*)(Bl + rb1);
    *(uint4*)(AhS + sr*32 + sk)      = ah0;
    *(uint4*)(AhS + (sr+64)*32 + sk) = ah1;
    *(uint4*)(AlS + sr*32 + sk)      = al0;
    *(uint4*)(AlS + (sr+64)*32 + sk) = al1;
    *(uint4*)(BhS + sr*32 + sk)      = bh0;
    *(uint4*)(BhS + (sr+64)*32 + sk) = bh1;
    *(uint4*)(BlS + sr*32 + sk)      = bl0;
    *(uint4*)(BlS + (sr+64)*32 + sk) = bl1;
    __syncthreads();

    bf16x8 ahf[4], alf[4], bhf[4], blf[4];
    #pragma unroll
    for (int mi=0;mi<4;mi++){
      ahf[mi] = *(const bf16x8*)(AhS + (wm + mi*16 + lanem)*32 + laneq);
      alf[mi] = *(const bf16x8*)(AlS + (wm + mi*16 + lanem)*32 + laneq);
    }
    #pragma unroll
    for (int ni=0;ni<4;ni++){
      bhf[ni] = *(const bf16x8*)(BhS + (wn + ni*16 + lanem)*32 + laneq);
      blf[ni] = *(const bf16x8*)(BlS + (wn + ni*16 + lanem)*32 + laneq);
    }
    #pragma unroll
    for (int mi=0;mi<4;mi++)
      #pragma unroll
      for (int ni=0;ni<4;ni++){
        acc[mi][ni] = __builtin_amdgcn_mfma_f32_16x16x32_bf16(ahf[mi], bhf[ni], acc[mi][ni], 0,0,0);
        acc[mi][ni] = __builtin_amdgcn_mfma_f32_16x16x32_bf16(ahf[mi], blf[ni], acc[mi][ni], 0,0,0);
        acc[mi][ni] = __builtin_amdgcn_mfma_f32_16x16x32_bf16(alf[mi], bhf[ni], acc[mi][ni], 0,0,0);
      }
    __syncthreads();
  }

  const int rr = (lane >> 4)*4, cc = lane & 15;
  #pragma unroll
  for (int mi=0;mi<4;mi++)
    #pragma unroll
    for (int ni=0;ni<4;ni++){
      const int cg = n0 + wn + ni*16 + cc;
      const float bv = (EPI==2) ? bias[cg] : 0.f;
      #pragma unroll
      for (int q=0;q<4;q++){
        float v = acc[mi][ni][q];
        if (EPI==2) v = -fminf(expf(bv + v), 5.2983174f);
        C[(size_t)(row0 + wm + mi*16 + rr + q)*N + cg] = v;
      }
    }
}

// ---------------------------------------------------------------------------
// split GEMM, N=64, 64-row tiles (no wasted waves), tanh epilogue -> hi/lo.
// grid (M/64).  Each wave: 16 rows x 64 cols.
// ---------------------------------------------------------------------------
__launch_bounds__(256)
__global__ void gemm_tanh64(const unsigned short* __restrict__ Ah,
                            const unsigned short* __restrict__ Al,
                            const unsigned short* __restrict__ Bh,
                            const unsigned short* __restrict__ Bl,
                            unsigned short* __restrict__ Th,
                            unsigned short* __restrict__ Tl,
                            int M, int K)
{
  __shared__ unsigned short AhS[64*32], AlS[64*32];
  __shared__ unsigned short BhS[64*32], BlS[64*32];
  const int tid  = threadIdx.x;
  const int row0 = blockIdx.x*64;
  const int wid  = tid >> 6, lane = tid & 63;
  const int wm   = wid*16;
  const int sr   = tid >> 2;
  const int sk   = (tid & 3)*8;
  const int laneq = (lane >> 4)*8;
  const int lanem = lane & 15;

  f32x4 acc[4];
  #pragma unroll
  for (int i=0;i<4;i++) acc[i] = (f32x4){0.f,0.f,0.f,0.f};

  for (int kt = 0; kt < K; kt += 32){
    const size_t ra = (size_t)(row0+sr)*K + kt + sk;
    const size_t rb = (size_t)sr*K + kt + sk;
    uint4 a_h = *(const uint4*)(Ah + ra);
    uint4 a_l = *(const uint4*)(Al + ra);
    uint4 b_h = *(const uint4*)(Bh + rb);
    uint4 b_l = *(const uint4*)(Bl + rb);
    *(uint4*)(AhS + sr*32 + sk) = a_h;
    *(uint4*)(AlS + sr*32 + sk) = a_l;
    *(uint4*)(BhS + sr*32 + sk) = b_h;
    *(uint4*)(BlS + sr*32 + sk) = b_l;
    __syncthreads();

    bf16x8 ahf = *(const bf16x8*)(AhS + (wm + lanem)*32 + laneq);
    bf16x8 alf = *(const bf16x8*)(AlS + (wm + lanem)*32 + laneq);
    #pragma unroll
    for (int ni=0;ni<4;ni++){
      bf16x8 bhf = *(const bf16x8*)(BhS + (ni*16 + lanem)*32 + laneq);
      bf16x8 blf = *(const bf16x8*)(BlS + (ni*16 + lanem)*32 + laneq);
      acc[ni] = __builtin_amdgcn_mfma_f32_16x16x32_bf16(ahf, bhf, acc[ni], 0,0,0);
      acc[ni] = __builtin_amdgcn_mfma_f32_16x16x32_bf16(ahf, blf, acc[ni], 0,0,0);
      acc[ni] = __builtin_amdgcn_mfma_f32_16x16x32_bf16(alf, bhf, acc[ni], 0,0,0);
    }
    __syncthreads();
  }

  const int rr = (lane >> 4)*4, cc = lane & 15;
  #pragma unroll
  for (int ni=0;ni<4;ni++){
    const int cg = ni*16 + cc;
    #pragma unroll
    for (int q=0;q<4;q++){
      const int rg = row0 + wm + rr + q;
      const float t = tanhf(acc[ni][q]);
      const unsigned short h = f2bf(t);
      Th[(size_t)rg*64 + cg] = h;
      Tl[(size_t)rg*64 + cg] = f2bf(t - bf2f(h));
    }
  }
}

// ---------------------------------------------------------------------------
// prep: xxx = x + (shift(x)-x)*maa_x (bf16).  grid 8192 x 256.
// ---------------------------------------------------------------------------
__global__ void prep_k(const float* __restrict__ x, const float* __restrict__ maa_x,
                       unsigned short* __restrict__ xxxg)
{
  const size_t e = ((size_t)blockIdx.x*256 + threadIdx.x)*4;
  const int d = (int)(e & 1023);
  const int t = (int)((e >> 10) & 4095);
  float4 xv = *(const float4*)(x + e);
  float4 xp;
  if (t == 0) xp = make_float4(0.f,0.f,0.f,0.f);
  else        xp = *(const float4*)(x + e - 1024);
  float4 mx = *(const float4*)(maa_x + d);
  ushort4 o;
  o.x = f2bf(xv.x + (xp.x-xv.x)*mx.x);
  o.y = f2bf(xv.y + (xp.y-xv.y)*mx.y);
  o.z = f2bf(xv.z + (xp.z-xv.z)*mx.z);
  o.w = f2bf(xv.w + (xp.w-xv.w)*mx.w);
  *(ushort4*)(xxxg + e) = o;
}

// ---------------------------------------------------------------------------
// mix fallback (tier-2): bf16 outputs + in-kernel decay GEMV + wlog.
// ---------------------------------------------------------------------------
__launch_bounds__(256)
__global__ void mix_fb(const float* __restrict__ x, const float* __restrict__ mraw,
                       const float* __restrict__ maa_x, const float* __restrict__ maa_w,
                       const float* __restrict__ maa_k, const float* __restrict__ maa_v,
                       const float* __restrict__ maa_r, const float* __restrict__ maa_g,
                       const float* __restrict__ w2,   const float* __restrict__ dw1,
                       const float* __restrict__ dw2,  const float* __restrict__ tdec,
                       unsigned short* __restrict__ xr, unsigned short* __restrict__ xk,
                       unsigned short* __restrict__ xv, unsigned short* __restrict__ xg,
                       float* __restrict__ wlog)
{
  __shared__ float m5L[8*160];
  __shared__ float xwL[8*1024];
  __shared__ float t64L[8*64];
  const int tid = threadIdx.x;
  const size_t g0 = (size_t)blockIdx.x*8;

  for (int idx = tid; idx < 1280; idx += 256){
    const int tok = idx/160, f = idx%160;
    m5L[tok*160+f] = tanhf(mraw[(g0+tok)*160 + f]);
  }
  float xxv[8][4], xsv[8][4];
  #pragma unroll
  for (int i=0;i<4;i++){
    const int d = i*256 + tid;
    const float mx = maa_x[d];
    #pragma unroll
    for (int tok=0;tok<8;tok++){
      const size_t tglob = g0 + tok;
      const size_t p = tglob*1024 + d;
      const float xc = x[p];
      const float xprev = ((tglob & 4095) == 0) ? 0.f : x[p - 1024];
      const float xxq = xprev - xc;
      xxv[tok][i] = xxq;
      xsv[tok][i] = xc + xxq*mx;
    }
  }
  __syncthreads();

  for (int n=0;n<5;n++){
    float acc[8][4];
    #pragma unroll
    for (int tok=0;tok<8;tok++)
      #pragma unroll
      for (int i=0;i<4;i++) acc[tok][i] = 0.f;
    for (int jj=0;jj<32;jj++){
      const int f = n*32+jj;
      float mv[8];
      #pragma unroll
      for (int tok=0;tok<8;tok++) mv[tok] = m5L[tok*160+f];
      #pragma unroll
      for (int i=0;i<4;i++){
        const float wv = w2[(size_t)f*1024 + i*256 + tid];
        #pragma unroll
        for (int tok=0;tok<8;tok++) acc[tok][i] += mv[tok]*wv;
      }
    }
    const float* cnp = (n==0)?maa_w:(n==1)?maa_k:(n==2)?maa_v:(n==3)?maa_r:maa_g;
    unsigned short* outp = (n==1)?xk:(n==2)?xv:(n==3)?xr:xg;
    #pragma unroll
    for (int i=0;i<4;i++){
      const int d = i*256 + tid;
      const float cdelta = cnp[d] - maa_x[d];
      #pragma unroll
      for (int tok=0;tok<8;tok++){
        const float val = xsv[tok][i] + xxv[tok][i]*(cdelta + acc[tok][i]);
        const size_t op = (g0+tok)*1024 + d;
        if (n == 0) xwL[tok*1024 + d] = val;
        else        outp[op] = f2bf(val);
      }
    }
  }
  __syncthreads();

  {
    const int jj = tid & 63, grp = tid >> 6;
    float a0 = 0.f, a1 = 0.f;
    const float* xr0 = &xwL[grp*1024];
    const float* xr1 = &xwL[(grp+4)*1024];
    for (int k=0;k<1024;k+=8){
      #pragma unroll
      for (int q=0;q<8;q++){
        const float dv = dw1[(size_t)(k+q)*64 + jj];
        a0 += xr0[k+q]*dv;
        a1 += xr1[k+q]*dv;
      }
    }
    t64L[grp*64 + jj]     = tanhf(a0);
    t64L[(grp+4)*64 + jj] = tanhf(a1);
  }
  __syncthreads();

  {
    float acc[8][4];
    #pragma unroll
    for (int tok=0;tok<8;tok++)
      #pragma unroll
      for (int i=0;i<4;i++) acc[tok][i] = 0.f;
    for (int f=0;f<64;f++){
      float tv[8];
      #pragma unroll
      for (int tok=0;tok<8;tok++) tv[tok] = t64L[tok*64+f];
      #pragma unroll
      for (int i=0;i<4;i++){
        const float wv = dw2[(size_t)f*1024 + i*256 + tid];
        #pragma unroll
        for (int tok=0;tok<8;tok++) acc[tok][i] += tv[tok]*wv;
      }
    }
    #pragma unroll
    for (int i=0;i<4;i++){
      const int d = i*256 + tid;
      const float td = tdec[d];
      #pragma unroll
      for (int tok=0;tok<8;tok++){
        const float wl = -fminf(expf(td + acc[tok][i]), 5.2983174f);
        wlog[(g0+tok)*1024 + d] = wl;
      }
    }
  }
}

// ---------------------------------------------------------------------------
// wkv pass1.  Reads wlog, computes cumsum, WRITES CUM BACK IN PLACE (over
// wlog), computes per-chunk wkv + wse.  F32KV selects f32 vs bf16 k/v.
// ---------------------------------------------------------------------------
template<int F32KV>
__launch_bounds__(256, 3)
__global__ void wkv_pass1(float* __restrict__ wlog, const void* __restrict__ kg,
                          const void* __restrict__ vg,
                          float* __restrict__ wkv, float* __restrict__ wse)
{
  __shared__ float cumL[128*64];   // cum -> khat in place
  __shared__ float vL[64*64];
  __shared__ float wsL[64];
  __shared__ float segsum[4*64];
  const int tid = threadIdx.x;
  const int hc = blockIdx.x;
  const int n = hc & 31, h = (hc >> 5) & 15, b = hc >> 9;
  const size_t tokbase = (size_t)b*4096 + (size_t)n*128;
  const size_t colbase = (size_t)h*64;

  #pragma unroll
  for (int i=0;i<8;i++){
    const int q = tid + 256*i;          // 2048 float4
    const int t = q >> 4, k4 = (q & 15)*4;
    *(float4*)&cumL[t*64 + k4] =
      *(const float4*)&wlog[(tokbase + t)*1024 + colbase + k4];
  }
  __syncthreads();
  { // segmented cumsum along t
    const int k2 = tid & 63, seg = tid >> 6;
    const int base = seg*32*64 + k2;
    float run = 0.f;
    for (int i=0;i<32;i++){ run += cumL[base + i*64]; cumL[base + i*64] = run; }
    segsum[seg*64 + k2] = run;
    __syncthreads();
    float offv = 0.f;
    for (int s2=0;s2<seg;s2++) offv += segsum[s2*64 + k2];
    if (seg > 0)
      for (int i=0;i<32;i++) cumL[base + i*64] += offv;
    __syncthreads();
  }
  if (tid < 64){
    const float wsv = cumL[127*64 + tid];
    wsL[tid] = wsv;
    wse[(size_t)hc*64 + tid] = expf(wsv);
  }
  __syncthreads();
  for (int idx = tid; idx < 8192; idx += 256){
    const int t = idx >> 6, k2 = idx & 63;
    const float c = cumL[idx];
    const size_t p = (tokbase + t)*1024 + colbase + k2;
    wlog[p] = c;
    const float kv = F32KV ? ((const float*)kg)[p] : bf2f(((const unsigned short*)kg)[p]);
    cumL[idx] = kv * expf(wsL[k2] - c);
  }
  __syncthreads();

  const int kk0 = (tid >> 4)*4, vv0 = (tid & 15)*4;
  float a[4][4];
  #pragma unroll
  for (int i=0;i<4;i++){ a[i][0]=0.f; a[i][1]=0.f; a[i][2]=0.f; a[i][3]=0.f; }
  for (int half=0; half<2; half++){
    #pragma unroll
    for (int i=0;i<4;i++){
      const int q = tid + 256*i;        // 1024 float4
      const int tr = q >> 4, k4 = (q & 15)*4;
      const size_t p = (tokbase + half*64 + tr)*1024 + colbase + k4;
      float4 vv;
      if (F32KV) vv = *(const float4*)((const float*)vg + p);
      else {
        ushort4 vu = *(const ushort4*)((const unsigned short*)vg + p);
        vv = make_float4(bf2f(vu.x), bf2f(vu.y), bf2f(vu.z), bf2f(vu.w));
      }
      *(float4*)&vL[tr*64 + k4] = vv;
    }
    __syncthreads();
    for (int t64=0; t64<64; t64++){
      float4 kf = *(const float4*)&cumL[(half*64 + t64)*64 + kk0];
      float4 vf = *(const float4*)&vL[t64*64 + vv0];
      const float kr[4] = {kf.x, kf.y, kf.z, kf.w};
      const float vr[4] = {vf.x, vf.y, vf.z, vf.w};
      #pragma unroll
      for (int i=0;i<4;i++)
        #pragma unroll
        for (int j=0;j<4;j++) a[i][j] += kr[i]*vr[j];
    }
    __syncthreads();
  }
  const size_t obase = (size_t)hc*4096;
  #pragma unroll
  for (int i=0;i<4;i++)
    *(float4*)(wkv + obase + (size_t)(kk0+i)*64 + vv0) = make_float4(a[i][0],a[i][1],a[i][2],a[i][3]);
}

// ---------------------------------------------------------------------------
// wkv pass2: scan over 32 chunks.
// ---------------------------------------------------------------------------
__global__ void wkv_scan(const float* __restrict__ wkv, const float* __restrict__ wse,
                         float* __restrict__ states)
{
  const int idx = blockIdx.x*256 + threadIdx.x;
  const int vv = idx & 63, kq = (idx >> 6) & 63, bh = idx >> 12;
  float st = 0.f;
  for (int n=0;n<32;n++){
    const size_t hc = (size_t)bh*32 + n;
    states[hc*4096 + (size_t)kq*64 + vv] = st;
    st = st * wse[hc*64 + kq] + wkv[hc*4096 + (size_t)kq*64 + vv];
  }
}

// ---------------------------------------------------------------------------
// wkv pass3 v2: precomputed cum; LDS rhat reads (round-9 form).
// F32 selects f32 r/k/v.  FUSED=1: groupnorm+silu(g) -> act bf16.
// ---------------------------------------------------------------------------
template<int F32, int FUSED>
__launch_bounds__(256, 4)
__global__ void wkv_pass3(const float* __restrict__ cum, const void* __restrict__ rg,
                          const void* __restrict__ kg, const void* __restrict__ vg,
                          const float* __restrict__ states, const float* __restrict__ faaaa,
                          const unsigned short* __restrict__ gg,
                          const float* __restrict__ lnw, const float* __restrict__ lnb,
                          unsigned short* __restrict__ outp)
{
  __shared__ float cumS[2][16*68];
  __shared__ float P[64*64];
  __shared__ __attribute__((aligned(16))) float rhat[16*68];
  __shared__ __attribute__((aligned(16))) float khat[16*68];
  __shared__ float vB[16*64];
  __shared__ float decL[64];
  __shared__ float aL[16*16];
  __shared__ float uL[64];
  __shared__ float lnwL[64], lnbL[64];
  const int tid = threadIdx.x;
  const int hc = blockIdx.x;
  const int n = hc & 31, h = (hc >> 5) & 15, b = hc >> 9;
  const size_t tokbase = (size_t)b*4096 + (size_t)n*128;
  const size_t colbase = (size_t)h*64;

  if (tid < 64){
    uL[tid] = faaaa[colbase + tid];
    cumS[1][15*68 + tid] = 0.f;          // "prev" row-15 for c=0
    if (FUSED){
      lnwL[tid] = lnw[colbase + tid];
      lnbL[tid] = lnb[colbase + tid];
    }
  }
  for (int idx = tid; idx < 4096; idx += 256)
    P[idx] = states[(size_t)hc*4096 + idx];
  __syncthreads();

  for (int c=0;c<8;c++){
    const int t0 = c*16;
    float* cur = cumS[c & 1];
    float* prv = cumS[(c & 1) ^ 1];
    { // phase A: load cum rows t0..t0+15
      const int row = tid >> 4, k4 = (tid & 15)*4;
      *(float4*)&cur[row*68 + k4] =
        *(const float4*)&cum[(tokbase + t0 + row)*1024 + colbase + k4];
    }
    __syncthreads();

    { // phase B: staging — rhat/khat/vB/diag/decL
      const int tl = tid >> 4, k4 = (tid & 15)*4;
      const size_t p4 = (tokbase + t0 + tl)*1024 + colbase + k4;
      float rv[4], kv[4], vv[4];
      if (F32){
        float4 r4 = *(const float4*)((const float*)rg + p4);
        float4 kq4 = *(const float4*)((const float*)kg + p4);
        float4 v4 = *(const float4*)((const float*)vg + p4);
        rv[0]=r4.x; rv[1]=r4.y; rv[2]=r4.z; rv[3]=r4.w;
        kv[0]=kq4.x; kv[1]=kq4.y; kv[2]=kq4.z; kv[3]=kq4.w;
        vv[0]=v4.x; vv[1]=v4.y; vv[2]=v4.z; vv[3]=v4.w;
      } else {
        ushort4 r4 = *(const ushort4*)((const unsigned short*)rg + p4);
        ushort4 kq4 = *(const ushort4*)((const unsigned short*)kg + p4);
        ushort4 v4 = *(const ushort4*)((const unsigned short*)vg + p4);
        rv[0]=bf2f(r4.x); rv[1]=bf2f(r4.y); rv[2]=bf2f(r4.z); rv[3]=bf2f(r4.w);
        kv[0]=bf2f(kq4.x); kv[1]=bf2f(kq4.y); kv[2]=bf2f(kq4.z); kv[3]=bf2f(kq4.w);
        vv[0]=bf2f(v4.x); vv[1]=bf2f(v4.y); vv[2]=bf2f(v4.z); vv[3]=bf2f(v4.w);
      }
      float4 off4 = *(const float4*)&prv[15*68 + k4];
      float4 cs4  = *(const float4*)&cur[tl*68 + k4];
      float4 cp4  = (tl == 0) ? off4 : *(const float4*)&cur[(tl-1)*68 + k4];
      float4 u4   = *(const float4*)&uL[k4];
      const float offa[4] = {off4.x,off4.y,off4.z,off4.w};
      const float csa[4]  = {cs4.x,cs4.y,cs4.z,cs4.w};
      const float cpa[4]  = {cp4.x,cp4.y,cp4.z,cp4.w};
      const float ua[4]   = {u4.x,u4.y,u4.z,u4.w};
      float rh[4], kh[4];
      float diagp = 0.f;
      #pragma unroll
      for (int j=0;j<4;j++){
        rh[j] = rv[j]*expf(cpa[j] - offa[j]);
        kh[j] = kv[j]*expf(offa[j] - csa[j]);
        diagp += rv[j]*ua[j]*kv[j];
      }
      *(float4*)&rhat[tl*68 + k4] = make_float4(rh[0],rh[1],rh[2],rh[3]);
      *(float4*)&khat[tl*68 + k4] = make_float4(kh[0],kh[1],kh[2],kh[3]);
      *(float4*)&vB[tl*64 + k4]   = make_float4(vv[0],vv[1],vv[2],vv[3]);
      diagp += __shfl_xor(diagp, 1);
      diagp += __shfl_xor(diagp, 2);
      diagp += __shfl_xor(diagp, 4);
      diagp += __shfl_xor(diagp, 8);
      if ((tid & 15) == 0) aL[tl*16 + tl] = diagp;
      if (tl == 15){
        decL[k4+0] = expf(csa[0] - offa[0]);
        decL[k4+1] = expf(csa[1] - offa[1]);
        decL[k4+2] = expf(csa[2] - offa[2]);
        decL[k4+3] = expf(csa[3] - offa[3]);
      }
    }
    __syncthreads();

    { // phase C: strict-lower a[t,s] = rhat[t].khat[s]
      const int tl = tid >> 4, sl = tid & 15;
      if (sl < tl){
        const float4* rp = (const float4*)&rhat[tl*68];
        const float4* kp = (const float4*)&khat[sl*68];
        float a0=0.f,a1=0.f,a2=0.f,a3=0.f;
        #pragma unroll
        for (int q=0;q<16;q++){
          float4 rv4 = rp[q], kv4 = kp[q];
          a0 += rv4.x*kv4.x; a1 += rv4.y*kv4.y;
          a2 += rv4.z*kv4.z; a3 += rv4.w*kv4.w;
        }
        aL[tl*16 + sl] = (a0+a1)+(a2+a3);
      }
    }
    __syncthreads();

    { // phase D: out = tril(a)@v + rhat@P (+ fused GN/SiLU)
      const int tl = tid >> 4, vq = (tid & 15)*4;
      float o0=0.f,o1=0.f,o2=0.f,o3=0.f;
      for (int sl=0; sl<=tl; sl++){
        const float av = aL[tl*16 + sl];
        float4 vf = *(const float4*)&vB[sl*64 + vq];
        o0 += av*vf.x; o1 += av*vf.y; o2 += av*vf.z; o3 += av*vf.w;
      }
      for (int k2=0;k2<64;k2++){
        const float rv = rhat[tl*68 + k2];
        float4 pf = *(const float4*)&P[k2*64 + vq];
        o0 += rv*pf.x; o1 += rv*pf.y; o2 += rv*pf.z; o3 += rv*pf.w;
      }
      const size_t yp = (tokbase + t0 + tl)*1024 + colbase + vq;
      if (FUSED){
        float s  = o0+o1+o2+o3;
        float s2 = o0*o0+o1*o1+o2*o2+o3*o3;
        #pragma unroll
        for (int m=1; m<16; m<<=1){
          s  += __shfl_xor(s,  m);
          s2 += __shfl_xor(s2, m);
        }
        const float mean = s*(1.f/64.f);
        const float var  = s2*(1.f/64.f) - mean*mean;
        const float rstd = rsqrtf(var + 6.4e-4f);
        ushort4 gv4 = *(const ushort4*)(gg + yp);
        const float gvs[4] = {bf2f(gv4.x), bf2f(gv4.y), bf2f(gv4.z), bf2f(gv4.w)};
        const float os[4] = {o0,o1,o2,o3};
        ushort4 ov;
        unsigned short* ovp = (unsigned short*)&ov;
        #pragma unroll
        for (int j=0;j<4;j++){
          const float yn = (os[j] - mean)*rstd*lnwL[vq+j] + lnbL[vq+j];
          const float gv = gvs[j];
          const float sg = gv/(1.f + expf(-gv));
          ovp[j] = f2bf(yn*sg);
        }
        *(ushort4*)(outp + yp) = ov;
      } else {
        ushort4 ov; ov.x = f2bf(o0); ov.y = f2bf(o1); ov.z = f2bf(o2); ov.w = f2bf(o3);
        *(ushort4*)(outp + yp) = ov;
      }
    }
    __syncthreads();

    { // phase E: P = P*dec + (khat*dec)^T @ v
      const int vq = (tid & 15)*4;
      const int kq0 = tid >> 4;
      float dec_ii[4];
      #pragma unroll
      for (int ii=0;ii<4;ii++) dec_ii[ii] = decL[kq0 + ii*16];
      float pv[4][4];
      #pragma unroll
      for (int ii=0;ii<4;ii++){
        const int kq = kq0 + ii*16;
        const float dec = dec_ii[ii];
        float4 pf = *(const float4*)&P[kq*64 + vq];
        pv[ii][0] = pf.x*dec; pv[ii][1] = pf.y*dec; pv[ii][2] = pf.z*dec; pv[ii][3] = pf.w*dec;
      }
      for (int tl=0;tl<16;tl++){
        float4 vf = *(const float4*)&vB[tl*64 + vq];
        const float vr[4] = {vf.x, vf.y, vf.z, vf.w};
        #pragma unroll
        for (int ii=0;ii<4;ii++){
          const float khv = khat[tl*68 + kq0 + ii*16]*dec_ii[ii];
          #pragma unroll
          for (int j=0;j<4;j++) pv[ii][j] += khv*vr[j];
        }
      }
      #pragma unroll
      for (int ii=0;ii<4;ii++)
        *(float4*)&P[(kq0+ii*16)*64 + vq] = make_float4(pv[ii][0],pv[ii][1],pv[ii][2],pv[ii][3]);
    }
    __syncthreads();
  }
}

// ---------------------------------------------------------------------------
// act (tier-2 only): groupnorm * silu(g) -> bf16.
// ---------------------------------------------------------------------------
__global__ void act_k(const unsigned short* __restrict__ y, const unsigned short* __restrict__ g,
                      const float* __restrict__ lnw, const float* __restrict__ lnb,
                      unsigned short* __restrict__ act)
{
  const size_t tau = blockIdx.x;
  const int lane = threadIdx.x & 63;
  const int wave = threadIdx.x >> 6;
  #pragma unroll
  for (int hh=0; hh<4; hh++){
    const int h = wave*4 + hh;
    const size_t p = tau*1024 + (size_t)h*64 + lane;
    const float val = bf2f(y[p]);
    float s = val, s2 = val*val;
    #pragma unroll
    for (int m=32; m>=1; m>>=1){
      s  += __shfl_xor(s, m);
      s2 += __shfl_xor(s2, m);
    }
    const float mean = s*(1.f/64.f);
    const float var  = s2*(1.f/64.f) - mean*mean;
    const int dd = h*64 + lane;
    float yn = (val - mean)*rsqrtf(var + 6.4e-4f);
    yn = yn*lnw[dd] + lnb[dd];
    const float gv = bf2f(g[p]);
    const float sg = gv/(1.f + expf(-gv));
    act[p] = f2bf(yn*sg);
  }
}

// ===========================================================================
extern "C" void kernel_launch(void* const* d_in, const int* in_sizes, int n_in,
                              void* d_out, int out_size, void* d_ws, size_t ws_size,
                              hipStream_t stream)
{
  (void)in_sizes; (void)n_in; (void)out_size;
  const float* x     = (const float*)d_in[0];
  const float* maa_x = (const float*)d_in[1];
  const float* maa_r = (const float*)d_in[2];
  const float* maa_w = (const float*)d_in[3];
  const float* maa_k = (const float*)d_in[4];
  const float* maa_v = (const float*)d_in[5];
  const float* maa_g = (const float*)d_in[6];
  const float* w1    = (const float*)d_in[7];
  const float* w2    = (const float*)d_in[8];
  const float* dw1   = (const float*)d_in[9];
  const float* dw2   = (const float*)d_in[10];
  const float* tdec  = (const float*)d_in[11];
  const float* faaaa = (const float*)d_in[12];
  const float* Wr    = (const float*)d_in[13];
  const float* Wk    = (const float*)d_in[14];
  const float* Wv    = (const float*)d_in[15];
  const float* Wg    = (const float*)d_in[16];
  const float* Wo    = (const float*)d_in[17];
  const float* lnw   = (const float*)d_in[18];
  const float* lnb   = (const float*)d_in[19];

  char* ws = (char*)d_ws;
  const dim3 tb32(32, 8);
  const size_t MB16 = (size_t)8192*1024*2;   // 16MB (one bf16/fp16 token-matrix)

  // ---------- tier-1 (~180MB) ----------
  {
    size_t o = 0;
    auto take = [&o](size_t nb){ size_t r = o; o += (nb + 255) & ~(size_t)255; return r; };
    unsigned short* WtG = (unsigned short*)(ws + take((size_t)1024*1024*2));
    unsigned short* WtO = (unsigned short*)(ws + take((size_t)1024*1024*2));
    unsigned short* W1t = (unsigned short*)(ws + take((size_t)160*1024*2));
    unsigned short* Wr16= (unsigned short*)(ws + take((size_t)1024*1024*2));
    unsigned short* Wk16= (unsigned short*)(ws + take((size_t)1024*1024*2));
    unsigned short* Wv16= (unsigned short*)(ws + take((size_t)1024*1024*2));
    unsigned short* D1H = (unsigned short*)(ws + take((size_t)64*1024*2));
    unsigned short* D1L = (unsigned short*)(ws + take((size_t)64*1024*2));
    unsigned short* D2H = (unsigned short*)(ws + take((size_t)1024*64*2));
    unsigned short* D2L = (unsigned short*)(ws + take((size_t)1024*64*2));
    unsigned short* W2tH= (unsigned short*)(ws + take((size_t)5120*32*2));
    unsigned short* W2tL= (unsigned short*)(ws + take((size_t)5120*32*2));
    unsigned short* Th  = (unsigned short*)(ws + take((size_t)8192*64*2));
    unsigned short* Tl  = (unsigned short*)(ws + take((size_t)8192*64*2));
    unsigned short* M5h = (unsigned short*)(ws + take((size_t)8192*160*2));  // -> wse f32
    unsigned short* M5l = (unsigned short*)(ws + take((size_t)8192*160*2));
    char*  Sxxx  = ws + take(MB16);            // xxx bf16 -> g bf16
    char*  slotRA = ws + take(2*MB16);         // xr16 -> k32 f32
    char*  slotKB = ws + take(2*MB16);         // xk16 -> v32 f32
    char*  slotVC = ws + take(2*MB16);         // xv16 -> wkv f32 + st f32
    char*  slotOA = ws + take(2*MB16);         // xwh+xwl -> r32 f32
    char*  Sxg   = ws + take(MB16);            // xg bf16 -> act bf16

    if (o <= ws_size){
      unsigned short* xxxb = (unsigned short*)Sxxx;
      unsigned short* gb   = (unsigned short*)Sxxx;
      float* wse = (float*)M5h;                 // m5 dead after gemm_mix
      unsigned short* xr16 = (unsigned short*)slotRA;
      float* k32 = (float*)slotRA;
      unsigned short* xk16 = (unsigned short*)slotKB;
      float* v32 = (float*)slotKB;
      unsigned short* xv16 = (unsigned short*)slotVC;
      float* wkvb = (float*)slotVC;
      float* st   = (float*)(slotVC + MB16);
      unsigned short* xwh = (unsigned short*)slotOA;
      unsigned short* xwl = (unsigned short*)(slotOA + MB16);
      float* r32  = (float*)slotOA;
      unsigned short* xgb  = (unsigned short*)Sxg;
      unsigned short* actb = (unsigned short*)Sxg;
      float* wlogb = (float*)d_out;             // wlog -> cum (in place)

      transpose_k<1><<<dim3(32,32), tb32, 0, stream>>>(Wg, WtG, 1024, 1024);
      transpose_k<1><<<dim3(32,32), tb32, 0, stream>>>(Wo, WtO, 1024, 1024);
      transpose_k<1><<<dim3(5,32),  tb32, 0, stream>>>(w1, W1t, 1024, 160);
      transpose_k<2><<<dim3(32,32), tb32, 0, stream>>>(Wr, Wr16, 1024, 1024);
      transpose_k<2><<<dim3(32,32), tb32, 0, stream>>>(Wk, Wk16, 1024, 1024);
      transpose_k<2><<<dim3(32,32), tb32, 0, stream>>>(Wv, Wv16, 1024, 1024);
      transpose_split<<<dim3(2,32),  tb32, 0, stream>>>(dw1, D1H, D1L, 1024, 64);
      transpose_split<<<dim3(32,2),  tb32, 0, stream>>>(dw2, D2H, D2L, 64, 1024);
      build_w2t<<<640, 256, 0, stream>>>(w2, W2tH, W2tL);

      prep_k<<<8192, 256, 0, stream>>>(x, maa_x, xxxb);
      gemm_tanh_bf16<<<dim3(64,2), 256, 0, stream>>>(xxxb, W1t, M5h, M5l, 8192, 160, 1024);
      gemm_mix<<<dim3(40,64), 256, 0, stream>>>(W2tH, W2tL, M5h, M5l, x, maa_x,
                                                maa_w, maa_k, maa_v, maa_r, maa_g,
                                                xwh, xwl, xk16, xv16, xr16, xgb);

      // decay path: t = tanh(xw@dw1) -> wlog = -min(exp(tdec + t@dw2), 5.298)
      gemm_tanh64<<<128, 256, 0, stream>>>(xwh, xwl, D1H, D1L, Th, Tl, 8192, 1024);
      gemm_split2<2><<<dim3(64,8), 256, 0, stream>>>(Th, Tl, D2H, D2L, wlogb, tdec, 8192, 1024, 64);

      gemm_bf16<<<dim3(64,8), 256, 0, stream>>>(xgb, WtG, gb, 8192, 1024, 1024, 1);
      gemm_fp16<<<dim3(64,8), 256, 0, stream>>>(xr16, Wr16, r32, 8192, 1024, 1024);
      gemm_fp16<<<dim3(64,8), 256, 0, stream>>>(xk16, Wk16, k32, 8192, 1024, 1024);
      gemm_fp16<<<dim3(64,8), 256, 0, stream>>>(xv16, Wv16, v32, 8192, 1024, 1024);

      wkv_pass1<1><<<1024, 256, 0, stream>>>(wlogb, k32, v32, wkvb, wse);
      wkv_scan    <<<512,  256, 0, stream>>>(wkvb, wse, st);
      wkv_pass3<1,1><<<1024, 256, 0, stream>>>(wlogb, r32, k32, v32, st, faaaa,
                                               gb, lnw, lnb, actb);

      gemm_bf16<<<dim3(64,8), 256, 0, stream>>>(actb, WtO, d_out, 8192, 1024, 1024, 0);
      return;
    }
  }

  // ---------- tier-2 fallback (~112MB, all-bf16) ----------
  {
    size_t o = 0;
    auto take = [&o](size_t nb){ size_t r = o; o += (nb + 255) & ~(size_t)255; return r; };
    unsigned short* WtR  = (unsigned short*)(ws + take((size_t)1024*1024*2));
    unsigned short* WtK  = (unsigned short*)(ws + take((size_t)1024*1024*2));
    unsigned short* WtV  = (unsigned short*)(ws + take((size_t)1024*1024*2));
    unsigned short* WtG  = (unsigned short*)(ws + take((size_t)1024*1024*2));
    unsigned short* WtO  = (unsigned short*)(ws + take((size_t)1024*1024*2));
    unsigned short* W1t  = (unsigned short*)(ws + take((size_t)160*1024*2));
    unsigned short* xxxb = (unsigned short*)(ws + take(MB16));
    float*          mraw = (float*)         (ws + take((size_t)8192*160*4));
    unsigned short* xrb  = (unsigned short*)(ws + take(MB16));
    unsigned short* xkb  = (unsigned short*)(ws + take(MB16));
    unsigned short* xvb  = (unsigned short*)(ws + take(MB16));
    unsigned short* xgb  = (unsigned short*)(ws + take(MB16));
    unsigned short* kb   = (unsigned short*)(ws + take(MB16));
    float*          wseb = (float*)         (ws + take((size_t)1024*64*4));
    if (o > ws_size) return;

    float*          wlogb = (float*)d_out;
    unsigned short* rb    = xxxb;
    unsigned short* vb    = xrb;
    unsigned short* gb    = xkb;
    float*          wkvb  = (float*)xvb;
    float*          stb   = (float*)xgb;
    unsigned short* yb    = xvb;
    unsigned short* actb  = kb;

    transpose_k<1><<<dim3(32,32), tb32, 0, stream>>>(Wr, WtR, 1024, 1024);
    transpose_k<1><<<dim3(32,32), tb32, 0, stream>>>(Wk, WtK, 1024, 1024);
    transpose_k<1><<<dim3(32,32), tb32, 0, stream>>>(Wv, WtV, 1024, 1024);
    transpose_k<1><<<dim3(32,32), tb32, 0, stream>>>(Wg, WtG, 1024, 1024);
    transpose_k<1><<<dim3(32,32), tb32, 0, stream>>>(Wo, WtO, 1024, 1024);
    transpose_k<1><<<dim3(5,32),  tb32, 0, stream>>>(w1, W1t, 1024, 160);

    prep_k<<<8192, 256, 0, stream>>>(x, maa_x, xxxb);
    gemm_bf16<<<dim3(64,2), 256, 0, stream>>>(xxxb, W1t, mraw, 8192, 160, 1024, 0);
    mix_fb<<<1024, 256, 0, stream>>>(x, mraw, maa_x, maa_w, maa_k, maa_v, maa_r, maa_g,
                                     w2, dw1, dw2, tdec,
                                     xrb, xkb, xvb, xgb, wlogb);

    gemm_bf16<<<dim3(64,8), 256, 0, stream>>>(xrb, WtR, rb, 8192, 1024, 1024, 1);
    gemm_bf16<<<dim3(64,8), 256, 0, stream>>>(xkb, WtK, kb, 8192, 1024, 1024, 1);
    gemm_bf16<<<dim3(64,8), 256, 0, stream>>>(xvb, WtV, vb, 8192, 1024, 1024, 1);
    gemm_bf16<<<dim3(64,8), 256, 0, stream>>>(xgb, WtG, gb, 8192, 1024, 1024, 1);

    wkv_pass1<0><<<1024, 256, 0, stream>>>(wlogb, kb, vb, wkvb, wseb);
    wkv_scan    <<<512,  256, 0, stream>>>(wkvb, wseb, stb);
    wkv_pass3<0,0><<<1024, 256, 0, stream>>>(wlogb, rb, kb, vb, stb, faaaa,
                                             nullptr, nullptr, nullptr, yb);

    act_k<<<8192, 256, 0, stream>>>(yb, gb, lnw, lnb, actb);
    gemm_bf16<<<dim3(64,8), 256, 0, stream>>>(actb, WtO, d_out, 8192, 1024, 1024, 0);
  }
}

// Round 12
// 512.712 us; speedup vs baseline: 1.3587x; 1.0394x over previous
//
#include <hip/hip_runtime.h>

// ============================================================================
// RWKV6 TimeMix forward, MI355X.  B=2 L=4096 D=1024 H=16 DH=64 T_CHUNK=128.
// Tier-1: mix einsum as swapped split MFMA GEMM w/ LDS-bounced epilogue;
//   r,k,v via fp16 MFMA GEMMs w/ global_load_lds staging; decay path split-bf16;
//   pass1 writes cumsum in-place (d_out); pass3 v2 (LDS rhat, 4 blocks/CU);
//   fused GN+SiLU.
// Tier-2 fallback (~112MB): all-bf16 pipeline.
// ============================================================================

typedef __attribute__((ext_vector_type(8))) short bf16x8;
typedef __attribute__((ext_vector_type(8))) _Float16 f16x8;
typedef __attribute__((ext_vector_type(4))) float f32x4;

static __device__ __forceinline__ unsigned short f2bf(float f){
  unsigned int u = __float_as_uint(f);
  u += 0x7FFFu + ((u >> 16) & 1u);
  return (unsigned short)(u >> 16);
}
static __device__ __forceinline__ float bf2f(unsigned short h){
  return __uint_as_float(((unsigned int)h) << 16);
}
static __device__ __forceinline__ unsigned short f2h(float f){
  _Float16 h = (_Float16)f;
  return *(unsigned short*)&h;
}

// async global->LDS, 16B/lane; LDS dest must be wave-uniform base + lane*16.
// Our staging offset is exactly 16*tid bytes: legal.
static __device__ __forceinline__ void gl_lds16(const void* g, void* l){
  __builtin_amdgcn_global_load_lds(
      (const __attribute__((address_space(1))) void*)g,
      (__attribute__((address_space(3))) void*)l, 16, 0, 0);
}

// ---------------------------------------------------------------------------
// transpose: src[R][C] f32 -> dst[C][R].  OUT: 0=f32, 1=bf16, 2=fp16.
// ---------------------------------------------------------------------------
template<int OUT>
__global__ void transpose_k(const float* __restrict__ src, void* __restrict__ dst,
                            int R, int C)
{
  __shared__ float tile[32][33];
  const int c0 = blockIdx.x*32, r0 = blockIdx.y*32;
  const int tx = threadIdx.x, ty = threadIdx.y;
  #pragma unroll
  for (int i=0;i<4;i++)
    tile[ty+i*8][tx] = src[(size_t)(r0+ty+i*8)*C + (c0+tx)];
  __syncthreads();
  #pragma unroll
  for (int i=0;i<4;i++){
    float v = tile[tx][ty+i*8];
    size_t o = (size_t)(c0+ty+i*8)*R + (r0+tx);
    if (OUT==1)      ((unsigned short*)dst)[o] = f2bf(v);
    else if (OUT==2) ((unsigned short*)dst)[o] = f2h(v);
    else             ((float*)dst)[o] = v;
  }
}

// transpose f32 -> bf16 hi + bf16 lo residual
__global__ void transpose_split(const float* __restrict__ src,
                                unsigned short* __restrict__ dh,
                                unsigned short* __restrict__ dl, int R, int C)
{
  __shared__ float tile[32][33];
  const int c0 = blockIdx.x*32, r0 = blockIdx.y*32;
  const int tx = threadIdx.x, ty = threadIdx.y;
  #pragma unroll
  for (int i=0;i<4;i++)
    tile[ty+i*8][tx] = src[(size_t)(r0+ty+i*8)*C + (c0+tx)];
  __syncthreads();
  #pragma unroll
  for (int i=0;i<4;i++){
    float v = tile[tx][ty+i*8];
    size_t o = (size_t)(c0+ty+i*8)*R + (r0+tx);
    unsigned short h = f2bf(v);
    dh[o] = h;
    dl[o] = f2bf(v - bf2f(h));
  }
}

// w2 [5][32][1024] -> w2t [5120][32] hi/lo  (w2t[n*1024+d][f] = w2[n][f][d])
__global__ void build_w2t(const float* __restrict__ w2,
                          unsigned short* __restrict__ th,
                          unsigned short* __restrict__ tl)
{
  const int idx = blockIdx.x*256 + threadIdx.x;   // 163840 total
  const int col = idx >> 5, f = idx & 31;
  const int n = col >> 10, d = col & 1023;
  const float v = w2[(size_t)n*32768 + (size_t)f*1024 + d];
  const unsigned short h = f2bf(v);
  th[idx] = h;
  tl[idx] = f2bf(v - bf2f(h));
}

// ---------------------------------------------------------------------------
// bf16 MFMA GEMM: C[M][N] = A[M][K]*B, A bf16 row-major, Bt = B^T bf16 [N][K].
// GLDS=1: N%128==0, global_load_lds staging.  GLDS=0: N-guarded reg staging.
// ---------------------------------------------------------------------------
template<int GLDS>
__launch_bounds__(256)
__global__ void gemm_bf16(const unsigned short* __restrict__ A,
                          const unsigned short* __restrict__ Bt,
                          void* __restrict__ Cp,
                          int M, int N, int K, int c_bf16)
{
  __shared__ unsigned short As[128*32];
  __shared__ unsigned short Bs[128*32];
  const int tid  = threadIdx.x;
  const int row0 = blockIdx.x*128, n0 = blockIdx.y*128;
  const int wid  = tid >> 6, lane = tid & 63;
  const int wm   = (wid >> 1)*64, wn = (wid & 1)*64;
  const int sr   = tid >> 2;
  const int sk   = (tid & 3)*8;
  const int laneq = (lane >> 4)*8;
  const int lanem = lane & 15;

  f32x4 acc[4][4];
  #pragma unroll
  for (int i=0;i<4;i++)
    #pragma unroll
    for (int j=0;j<4;j++) acc[i][j] = (f32x4){0.f,0.f,0.f,0.f};

  for (int kt = 0; kt < K; kt += 32){
    if (GLDS){
      gl_lds16(A  + (size_t)(row0+sr   )*K + kt + sk, As + sr*32 + sk);
      gl_lds16(A  + (size_t)(row0+sr+64)*K + kt + sk, As + (sr+64)*32 + sk);
      gl_lds16(Bt + (size_t)(n0 +sr   )*K + kt + sk, Bs + sr*32 + sk);
      gl_lds16(Bt + (size_t)(n0 +sr+64)*K + kt + sk, Bs + (sr+64)*32 + sk);
    } else {
      uint4 a0 = *(const uint4*)(A + (size_t)(row0+sr   )*K + kt + sk);
      uint4 a1 = *(const uint4*)(A + (size_t)(row0+sr+64)*K + kt + sk);
      uint4 z; z.x=0u; z.y=0u; z.z=0u; z.w=0u;
      const int nb0 = n0+sr, nb1 = n0+sr+64;
      uint4 b0 = (nb0 < N) ? *(const uint4*)(Bt + (size_t)nb0*K + kt + sk) : z;
      uint4 b1 = (nb1 < N) ? *(const uint4*)(Bt + (size_t)nb1*K + kt + sk) : z;
      *(uint4*)(As + sr*32 + sk)      = a0;
      *(uint4*)(As + (sr+64)*32 + sk) = a1;
      *(uint4*)(Bs + sr*32 + sk)      = b0;
      *(uint4*)(Bs + (sr+64)*32 + sk) = b1;
    }
    __syncthreads();

    bf16x8 af[4], bfr[4];
    #pragma unroll
    for (int mi=0;mi<4;mi++)
      af[mi] = *(const bf16x8*)(As + (wm + mi*16 + lanem)*32 + laneq);
    #pragma unroll
    for (int ni=0;ni<4;ni++)
      bfr[ni] = *(const bf16x8*)(Bs + (wn + ni*16 + lanem)*32 + laneq);
    #pragma unroll
    for (int mi=0;mi<4;mi++)
      #pragma unroll
      for (int ni=0;ni<4;ni++)
        acc[mi][ni] = __builtin_amdgcn_mfma_f32_16x16x32_bf16(af[mi], bfr[ni], acc[mi][ni], 0,0,0);
    __syncthreads();
  }

  const int rr = (lane >> 4)*4, cc = lane & 15;
  #pragma unroll
  for (int mi=0;mi<4;mi++){
    #pragma unroll
    for (int ni=0;ni<4;ni++){
      const int cg = n0 + wn + ni*16 + cc;
      if (GLDS || cg < N){
        #pragma unroll
        for (int q=0;q<4;q++){
          const int rg = row0 + wm + mi*16 + rr + q;
          float v = acc[mi][ni][q];
          if (c_bf16) ((unsigned short*)Cp)[(size_t)rg*N + cg] = f2bf(v);
          else        ((float*)Cp)[(size_t)rg*N + cg] = v;
        }
      }
    }
  }
}

// ---------------------------------------------------------------------------
// fp16 MFMA GEMM: C[M][N] f32 = A[M][K] fp16 * B, Bt = B^T fp16 [N][K].
// M,N % 128 == 0.  global_load_lds staging (m97 pattern).
// ---------------------------------------------------------------------------
__launch_bounds__(256)
__global__ void gemm_fp16(const unsigned short* __restrict__ A,
                          const unsigned short* __restrict__ Bt,
                          float* __restrict__ C,
                          int M, int N, int K)
{
  __shared__ unsigned short As[128*32];
  __shared__ unsigned short Bs[128*32];
  const int tid  = threadIdx.x;
  const int row0 = blockIdx.x*128, n0 = blockIdx.y*128;
  const int wid  = tid >> 6, lane = tid & 63;
  const int wm   = (wid >> 1)*64, wn = (wid & 1)*64;
  const int sr   = tid >> 2;
  const int sk   = (tid & 3)*8;
  const int laneq = (lane >> 4)*8;
  const int lanem = lane & 15;

  f32x4 acc[4][4];
  #pragma unroll
  for (int i=0;i<4;i++)
    #pragma unroll
    for (int j=0;j<4;j++) acc[i][j] = (f32x4){0.f,0.f,0.f,0.f};

  for (int kt = 0; kt < K; kt += 32){
    gl_lds16(A  + (size_t)(row0+sr   )*K + kt + sk, As + sr*32 + sk);
    gl_lds16(A  + (size_t)(row0+sr+64)*K + kt + sk, As + (sr+64)*32 + sk);
    gl_lds16(Bt + (size_t)(n0 +sr   )*K + kt + sk, Bs + sr*32 + sk);
    gl_lds16(Bt + (size_t)(n0 +sr+64)*K + kt + sk, Bs + (sr+64)*32 + sk);
    __syncthreads();

    f16x8 af[4], bfr[4];
    #pragma unroll
    for (int mi=0;mi<4;mi++)
      af[mi] = *(const f16x8*)(As + (wm + mi*16 + lanem)*32 + laneq);
    #pragma unroll
    for (int ni=0;ni<4;ni++)
      bfr[ni] = *(const f16x8*)(Bs + (wn + ni*16 + lanem)*32 + laneq);
    #pragma unroll
    for (int mi=0;mi<4;mi++)
      #pragma unroll
      for (int ni=0;ni<4;ni++)
        acc[mi][ni] = __builtin_amdgcn_mfma_f32_16x16x32_f16(af[mi], bfr[ni], acc[mi][ni], 0,0,0);
    __syncthreads();
  }

  const int rr = (lane >> 4)*4, cc = lane & 15;
  #pragma unroll
  for (int mi=0;mi<4;mi++)
    #pragma unroll
    for (int ni=0;ni<4;ni++){
      const int cg = n0 + wn + ni*16 + cc;
      #pragma unroll
      for (int q=0;q<4;q++)
        C[(size_t)(row0 + wm + mi*16 + rr + q)*N + cg] = acc[mi][ni][q];
    }
}

// ---------------------------------------------------------------------------
// bf16 GEMM with tanh hi/lo epilogue (for m5).  N guarded, register staging.
// ---------------------------------------------------------------------------
__launch_bounds__(256)
__global__ void gemm_tanh_bf16(const unsigned short* __restrict__ A,
                               const unsigned short* __restrict__ Bt,
                               unsigned short* __restrict__ Th,
                               unsigned short* __restrict__ Tl,
                               int M, int N, int K)
{
  __shared__ unsigned short As[128*32];
  __shared__ unsigned short Bs[128*32];
  const int tid  = threadIdx.x;
  const int row0 = blockIdx.x*128, n0 = blockIdx.y*128;
  const int wid  = tid >> 6, lane = tid & 63;
  const int wm   = (wid >> 1)*64, wn = (wid & 1)*64;
  const int sr   = tid >> 2;
  const int sk   = (tid & 3)*8;
  const int laneq = (lane >> 4)*8;
  const int lanem = lane & 15;

  f32x4 acc[4][4];
  #pragma unroll
  for (int i=0;i<4;i++)
    #pragma unroll
    for (int j=0;j<4;j++) acc[i][j] = (f32x4){0.f,0.f,0.f,0.f};

  for (int kt = 0; kt < K; kt += 32){
    uint4 a0 = *(const uint4*)(A + (size_t)(row0+sr   )*K + kt + sk);
    uint4 a1 = *(const uint4*)(A + (size_t)(row0+sr+64)*K + kt + sk);
    uint4 z; z.x=0u; z.y=0u; z.z=0u; z.w=0u;
    const int nb0 = n0+sr, nb1 = n0+sr+64;
    uint4 b0 = (nb0 < N) ? *(const uint4*)(Bt + (size_t)nb0*K + kt + sk) : z;
    uint4 b1 = (nb1 < N) ? *(const uint4*)(Bt + (size_t)nb1*K + kt + sk) : z;
    *(uint4*)(As + sr*32 + sk)      = a0;
    *(uint4*)(As + (sr+64)*32 + sk) = a1;
    *(uint4*)(Bs + sr*32 + sk)      = b0;
    *(uint4*)(Bs + (sr+64)*32 + sk) = b1;
    __syncthreads();

    bf16x8 af[4], bfr[4];
    #pragma unroll
    for (int mi=0;mi<4;mi++)
      af[mi] = *(const bf16x8*)(As + (wm + mi*16 + lanem)*32 + laneq);
    #pragma unroll
    for (int ni=0;ni<4;ni++)
      bfr[ni] = *(const bf16x8*)(Bs + (wn + ni*16 + lanem)*32 + laneq);
    #pragma unroll
    for (int mi=0;mi<4;mi++)
      #pragma unroll
      for (int ni=0;ni<4;ni++)
        acc[mi][ni] = __builtin_amdgcn_mfma_f32_16x16x32_bf16(af[mi], bfr[ni], acc[mi][ni], 0,0,0);
    __syncthreads();
  }

  const int rr = (lane >> 4)*4, cc = lane & 15;
  #pragma unroll
  for (int mi=0;mi<4;mi++){
    #pragma unroll
    for (int ni=0;ni<4;ni++){
      const int cg = n0 + wn + ni*16 + cc;
      if (cg < N){
        #pragma unroll
        for (int q=0;q<4;q++){
          const int rg = row0 + wm + mi*16 + rr + q;
          const float t = tanhf(acc[mi][ni][q]);
          const unsigned short h = f2bf(t);
          Th[(size_t)rg*N + cg] = h;
          Tl[(size_t)rg*N + cg] = f2bf(t - bf2f(h));
        }
      }
    }
  }
}

// ---------------------------------------------------------------------------
// gemm_mix: Z[d][tok] = w2t-tile @ m5^T (single K=32 step), LDS-bounce,
// coalesced lerp epilogue.  Outputs: n=0 -> xw bf16 hi/lo; n=1,2,3 ->
// xk/xv/xr fp16; n=4 -> xg bf16.  grid (40, 64).
// ---------------------------------------------------------------------------
__launch_bounds__(256)
__global__ void gemm_mix(const unsigned short* __restrict__ w2th,
                         const unsigned short* __restrict__ w2tl,
                         const unsigned short* __restrict__ m5h,
                         const unsigned short* __restrict__ m5l,
                         const float* __restrict__ x,
                         const float* __restrict__ maa_x,
                         const float* __restrict__ maa_w,
                         const float* __restrict__ maa_k,
                         const float* __restrict__ maa_v,
                         const float* __restrict__ maa_r,
                         const float* __restrict__ maa_g,
                         unsigned short* __restrict__ xwh, unsigned short* __restrict__ xwl,
                         unsigned short* __restrict__ xk16, unsigned short* __restrict__ xv16,
                         unsigned short* __restrict__ xr16, unsigned short* __restrict__ xg)
{
  __shared__ __attribute__((aligned(16))) float Zs[128*136];   // 69632 B
  unsigned short* AhS = (unsigned short*)Zs;        // staging aliases Zs
  unsigned short* AlS = AhS + 4096;
  unsigned short* BhS = AhS + 8192;
  unsigned short* BlS = AhS + 12288;
  const int tid  = threadIdx.x;
  const int row0 = blockIdx.x*128;          // d dimension (0..5120)
  const int col0 = blockIdx.y*128;          // token dimension
  const int n    = row0 >> 10;              // uniform per block
  const int wid  = tid >> 6, lane = tid & 63;
  const int wm   = (wid >> 1)*64, wn = (wid & 1)*64;
  const int sr   = tid >> 2;
  const int sk   = (tid & 3)*8;
  const int laneq = (lane >> 4)*8;
  const int lanem = lane & 15;

  { // stage A (w2t rows) and B (m5 rows, K-window n*32)
    const size_t a0 = (size_t)(row0+sr)*32 + sk;
    const size_t a1 = (size_t)(row0+sr+64)*32 + sk;
    *(uint4*)(AhS + sr*32 + sk)      = *(const uint4*)(w2th + a0);
    *(uint4*)(AhS + (sr+64)*32 + sk) = *(const uint4*)(w2th + a1);
    *(uint4*)(AlS + sr*32 + sk)      = *(const uint4*)(w2tl + a0);
    *(uint4*)(AlS + (sr+64)*32 + sk) = *(const uint4*)(w2tl + a1);
    const size_t b0 = (size_t)(col0+sr)*160 + n*32 + sk;
    const size_t b1 = (size_t)(col0+sr+64)*160 + n*32 + sk;
    *(uint4*)(BhS + sr*32 + sk)      = *(const uint4*)(m5h + b0);
    *(uint4*)(BhS + (sr+64)*32 + sk) = *(const uint4*)(m5h + b1);
    *(uint4*)(BlS + sr*32 + sk)      = *(const uint4*)(m5l + b0);
    *(uint4*)(BlS + (sr+64)*32 + sk) = *(const uint4*)(m5l + b1);
  }
  __syncthreads();

  f32x4 acc[4][4];
  #pragma unroll
  for (int i=0;i<4;i++)
    #pragma unroll
    for (int j=0;j<4;j++) acc[i][j] = (f32x4){0.f,0.f,0.f,0.f};

  {
    bf16x8 ahf[4], alf[4], bhf[4], blf[4];
    #pragma unroll
    for (int mi=0;mi<4;mi++){
      ahf[mi] = *(const bf16x8*)(AhS + (wm + mi*16 + lanem)*32 + laneq);
      alf[mi] = *(const bf16x8*)(AlS + (wm + mi*16 + lanem)*32 + laneq);
    }
    #pragma unroll
    for (int ni=0;ni<4;ni++){
      bhf[ni] = *(const bf16x8*)(BhS + (wn + ni*16 + lanem)*32 + laneq);
      blf[ni] = *(const bf16x8*)(BlS + (wn + ni*16 + lanem)*32 + laneq);
    }
    #pragma unroll
    for (int mi=0;mi<4;mi++)
      #pragma unroll
      for (int ni=0;ni<4;ni++){
        acc[mi][ni] = __builtin_amdgcn_mfma_f32_16x16x32_bf16(ahf[mi], bhf[ni], acc[mi][ni], 0,0,0);
        acc[mi][ni] = __builtin_amdgcn_mfma_f32_16x16x32_bf16(ahf[mi], blf[ni], acc[mi][ni], 0,0,0);
        acc[mi][ni] = __builtin_amdgcn_mfma_f32_16x16x32_bf16(alf[mi], bhf[ni], acc[mi][ni], 0,0,0);
      }
  }
  __syncthreads();   // staging fully consumed -> reuse as Zs

  { // scatter acc into Zs[tokL][dL] (stride 136)
    const int rr = (lane >> 4)*4, cc = lane & 15;
    #pragma unroll
    for (int mi=0;mi<4;mi++){
      const int dL0 = wm + mi*16 + rr;
      #pragma unroll
      for (int ni=0;ni<4;ni++){
        const int tokL = wn + ni*16 + cc;
        #pragma unroll
        for (int q=0;q<4;q++)
          Zs[tokL*136 + dL0 + q] = acc[mi][ni][q];
      }
    }
  }
  __syncthreads();

  { // coalesced lerp epilogue
    const int dbase = row0 & 1023;
    const float* cnp = (n==0)?maa_w:(n==1)?maa_k:(n==2)?maa_v:(n==3)?maa_r:maa_g;
    unsigned short* hp = (n==0)?xwh:(n==1)?xk16:(n==2)?xv16:(n==3)?xr16:xg;
    const int mode = (n==0) ? 0 : (n==4) ? 2 : 1;   // 0=bf16 hi/lo, 1=fp16, 2=bf16
    #pragma unroll
    for (int i=0;i<16;i++){
      const int idx = tid + 256*i;        // 0..4095
      const int tokL = idx >> 5;          // 0..127
      const int d4 = (idx & 31)*4;        // 0..124
      const int tok = col0 + tokL;
      const int dd = dbase + d4;
      const size_t px = (size_t)tok*1024 + dd;
      float4 z4  = *(const float4*)&Zs[tokL*136 + d4];
      float4 mx4 = *(const float4*)(maa_x + dd);
      float4 cn4 = *(const float4*)(cnp + dd);
      float4 xc4 = *(const float4*)(x + px);
      float4 xp4;
      if ((tok & 4095) == 0) xp4 = make_float4(0.f,0.f,0.f,0.f);
      else                   xp4 = *(const float4*)(x + px - 1024);
      const float za[4]  = {z4.x,z4.y,z4.z,z4.w};
      const float xca[4] = {xc4.x,xc4.y,xc4.z,xc4.w};
      const float xpa[4] = {xp4.x,xp4.y,xp4.z,xp4.w};
      const float mxa[4] = {mx4.x,mx4.y,mx4.z,mx4.w};
      const float cna[4] = {cn4.x,cn4.y,cn4.z,cn4.w};
      ushort4 hv, lv;
      unsigned short* hq = (unsigned short*)&hv;
      unsigned short* lq = (unsigned short*)&lv;
      #pragma unroll
      for (int j=0;j<4;j++){
        const float xx = xpa[j] - xca[j];
        const float v  = xca[j] + xx*mxa[j] + xx*((cna[j]-mxa[j]) + za[j]);
        if (mode == 0){
          const unsigned short h = f2bf(v);
          hq[j] = h;
          lq[j] = f2bf(v - bf2f(h));
        } else if (mode == 1){
          hq[j] = f2h(v);
        } else {
          hq[j] = f2bf(v);
        }
      }
      *(ushort4*)(hp + px) = hv;
      if (mode == 0) *(ushort4*)(xwl + px) = lv;
    }
  }
}

// ---------------------------------------------------------------------------
// split GEMM (pre-decomposed hi/lo): C = AhBh + AhBl + AlBh.  Register staging.
// EPI 0: f32 store.  EPI 2: wlog = -min(exp(bias[col]+acc), 5.2983174) f32.
// ---------------------------------------------------------------------------
template<int EPI>
__launch_bounds__(256)
__global__ void gemm_split2(const unsigned short* __restrict__ Ah,
                            const unsigned short* __restrict__ Al,
                            const unsigned short* __restrict__ Bh,
                            const unsigned short* __restrict__ Bl,
                            float* __restrict__ C, const float* __restrict__ bias,
                            int M, int N, int K)
{
  __shared__ unsigned short AhS[128*32], AlS[128*32];
  __shared__ unsigned short BhS[128*32], BlS[128*32];
  const int tid  = threadIdx.x;
  const int row0 = blockIdx.x*128, n0 = blockIdx.y*128;
  const int wid  = tid >> 6, lane = tid & 63;
  const int wm   = (wid >> 1)*64, wn = (wid & 1)*64;
  const int sr   = tid >> 2;
  const int sk   = (tid & 3)*8;
  const int laneq = (lane >> 4)*8;
  const int lanem = lane & 15;

  f32x4 acc[4][4];
  #pragma unroll
  for (int i=0;i<4;i++)
    #pragma unroll
    for (int j=0;j<4;j++) acc[i][j] = (f32x4){0.f,0.f,0.f,0.f};

  for (int kt = 0; kt < K; kt += 32){
    const size_t ra0 = (size_t)(row0+sr)*K + kt + sk;
    const size_t ra1 = (size_t)(row0+sr+64)*K + kt + sk;
    const size_t rb0 = (size_t)(n0 +sr)*K + kt + sk;
    const size_t rb1 = (size_t)(n0 +sr+64)*K + kt + sk;
    uint4 ah0 = *(const uint4*)(Ah + ra0);
    uint4 ah1 = *(const uint4*)(Ah + ra1);
    uint4 al0 = *(const uint4*)(Al + ra0);
    uint4 al1 = *(const uint4*)(Al + ra1);
    uint4 bh0 = *(const uint4*)(Bh + rb0);
    uint4 bh1 = *(const uint4*)(Bh + rb1);
    uint4 bl0 = *(const uint4*)(Bl + rb0);
    uint4 bl1 = *(const uint4*)(Bl + rb1);
    *(uint4*)(AhS + sr*32 + sk)      = ah0;
    *(uint4*)(AhS + (sr+64)*32 + sk) = ah1;
    *(uint4*)(AlS + sr*32 + sk)      = al0;
    *(uint4*)(AlS + (sr+64)*32 + sk) = al1;
    *(uint4*)(BhS + sr*32 + sk)      = bh0;
    *(uint4*)(BhS + (sr+64)*32 + sk) = bh1;
    *(uint4*)(BlS + sr*32 + sk)      = bl0;
    *(uint4*)(BlS + (sr+64)*32 + sk) = bl1;
    __syncthreads();

    bf16x8 ahf[4], alf[4], bhf[4], blf[4];
    #pragma unroll
    for (int mi=0;mi<4;mi++){
      ahf[mi] = *(const bf16x8*)(AhS + (wm + mi*16 + lanem)*32 + laneq);
      alf[mi] = *(const bf16x8*)(AlS + (wm + mi*16 + lanem)*32 + laneq);
    }
    #pragma unroll
    for (int ni=0;ni<4;ni++){
      bhf[ni] = *(const bf16x8*)(BhS + (wn + ni*16 + lanem)*32 + laneq);
      blf[ni] = *(const bf16x8*)(BlS + (wn + ni*16 + lanem)*32 + laneq);
    }
    #pragma unroll
    for (int mi=0;mi<4;mi++)
      #pragma unroll
      for (int ni=0;ni<4;ni++){
        acc[mi][ni] = __builtin_amdgcn_mfma_f32_16x16x32_bf16(ahf[mi], bhf[ni], acc[mi][ni], 0,0,0);
        acc[mi][ni] = __builtin_amdgcn_mfma_f32_16x16x32_bf16(ahf[mi], blf[ni], acc[mi][ni], 0,0,0);
        acc[mi][ni] = __builtin_amdgcn_mfma_f32_16x16x32_bf16(alf[mi], bhf[ni], acc[mi][ni], 0,0,0);
      }
    __syncthreads();
  }

  const int rr = (lane >> 4)*4, cc = lane & 15;
  #pragma unroll
  for (int mi=0;mi<4;mi++)
    #pragma unroll
    for (int ni=0;ni<4;ni++){
      const int cg = n0 + wn + ni*16 + cc;
      const float bv = (EPI==2) ? bias[cg] : 0.f;
      #pragma unroll
      for (int q=0;q<4;q++){
        float v = acc[mi][ni][q];
        if (EPI==2) v = -fminf(expf(bv + v), 5.2983174f);
        C[(size_t)(row0 + wm + mi*16 + rr + q)*N + cg] = v;
      }
    }
}

// ---------------------------------------------------------------------------
// split GEMM, N=64, 64-row tiles (no wasted waves), tanh epilogue -> hi/lo.
// grid (M/64).  Each wave: 16 rows x 64 cols.
// ---------------------------------------------------------------------------
__launch_bounds__(256)
__global__ void gemm_tanh64(const unsigned short* __restrict__ Ah,
                            const unsigned short* __restrict__ Al,
                            const unsigned short* __restrict__ Bh,
                            const unsigned short* __restrict__ Bl,
                            unsigned short* __restrict__ Th,
                            unsigned short* __restrict__ Tl,
                            int M, int K)
{
  __shared__ unsigned short AhS[64*32], AlS[64*32];
  __shared__ unsigned short BhS[64*32], BlS[64*32];
  const int tid  = threadIdx.x;
  const int row0 = blockIdx.x*64;
  const int wid  = tid >> 6, lane = tid & 63;
  const int wm   = wid*16;
  const int sr   = tid >> 2;
  const int sk   = (tid & 3)*8;
  const int laneq = (lane >> 4)*8;
  const int lanem = lane & 15;

  f32x4 acc[4];
  #pragma unroll
  for (int i=0;i<4;i++) acc[i] = (f32x4){0.f,0.f,0.f,0.f};

  for (int kt = 0; kt < K; kt += 32){
    const size_t ra = (size_t)(row0+sr)*K + kt + sk;
    const size_t rb = (size_t)sr*K + kt + sk;
    uint4 a_h = *(const uint4*)(Ah + ra);
    uint4 a_l = *(const uint4*)(Al + ra);
    uint4 b_h = *(const uint4*)(Bh + rb);
    uint4 b_l = *(const uint4*)(Bl + rb);
    *(uint4*)(AhS + sr*32 + sk) = a_h;
    *(uint4*)(AlS + sr*32 + sk) = a_l;
    *(uint4*)(BhS + sr*32 + sk) = b_h;
    *(uint4*)(BlS + sr*32 + sk) = b_l;
    __syncthreads();

    bf16x8 ahf = *(const bf16x8*)(AhS + (wm + lanem)*32 + laneq);
    bf16x8 alf = *(const bf16x8*)(AlS + (wm + lanem)*32 + laneq);
    #pragma unroll
    for (int ni=0;ni<4;ni++){
      bf16x8 bhf = *(const bf16x8*)(BhS + (ni*16 + lanem)*32 + laneq);
      bf16x8 blf = *(const bf16x8*)(BlS + (ni*16 + lanem)*32 + laneq);
      acc[ni] = __builtin_amdgcn_mfma_f32_16x16x32_bf16(ahf, bhf, acc[ni], 0,0,0);
      acc[ni] = __builtin_amdgcn_mfma_f32_16x16x32_bf16(ahf, blf, acc[ni], 0,0,0);
      acc[ni] = __builtin_amdgcn_mfma_f32_16x16x32_bf16(alf, bhf, acc[ni], 0,0,0);
    }
    __syncthreads();
  }

  const int rr = (lane >> 4)*4, cc = lane & 15;
  #pragma unroll
  for (int ni=0;ni<4;ni++){
    const int cg = ni*16 + cc;
    #pragma unroll
    for (int q=0;q<4;q++){
      const int rg = row0 + wm + rr + q;
      const float t = tanhf(acc[ni][q]);
      const unsigned short h = f2bf(t);
      Th[(size_t)rg*64 + cg] = h;
      Tl[(size_t)rg*64 + cg] = f2bf(t - bf2f(h));
    }
  }
}

// ---------------------------------------------------------------------------
// prep: xxx = x + (shift(x)-x)*maa_x (bf16).  grid 8192 x 256.
// ---------------------------------------------------------------------------
__global__ void prep_k(const float* __restrict__ x, const float* __restrict__ maa_x,
                       unsigned short* __restrict__ xxxg)
{
  const size_t e = ((size_t)blockIdx.x*256 + threadIdx.x)*4;
  const int d = (int)(e & 1023);
  const int t = (int)((e >> 10) & 4095);
  float4 xv = *(const float4*)(x + e);
  float4 xp;
  if (t == 0) xp = make_float4(0.f,0.f,0.f,0.f);
  else        xp = *(const float4*)(x + e - 1024);
  float4 mx = *(const float4*)(maa_x + d);
  ushort4 o;
  o.x = f2bf(xv.x + (xp.x-xv.x)*mx.x);
  o.y = f2bf(xv.y + (xp.y-xv.y)*mx.y);
  o.z = f2bf(xv.z + (xp.z-xv.z)*mx.z);
  o.w = f2bf(xv.w + (xp.w-xv.w)*mx.w);
  *(ushort4*)(xxxg + e) = o;
}

// ---------------------------------------------------------------------------
// mix fallback (tier-2): bf16 outputs + in-kernel decay GEMV + wlog.
// ---------------------------------------------------------------------------
__launch_bounds__(256)
__global__ void mix_fb(const float* __restrict__ x, const float* __restrict__ mraw,
                       const float* __restrict__ maa_x, const float* __restrict__ maa_w,
                       const float* __restrict__ maa_k, const float* __restrict__ maa_v,
                       const float* __restrict__ maa_r, const float* __restrict__ maa_g,
                       const float* __restrict__ w2,   const float* __restrict__ dw1,
                       const float* __restrict__ dw2,  const float* __restrict__ tdec,
                       unsigned short* __restrict__ xr, unsigned short* __restrict__ xk,
                       unsigned short* __restrict__ xv, unsigned short* __restrict__ xg,
                       float* __restrict__ wlog)
{
  __shared__ float m5L[8*160];
  __shared__ float xwL[8*1024];
  __shared__ float t64L[8*64];
  const int tid = threadIdx.x;
  const size_t g0 = (size_t)blockIdx.x*8;

  for (int idx = tid; idx < 1280; idx += 256){
    const int tok = idx/160, f = idx%160;
    m5L[tok*160+f] = tanhf(mraw[(g0+tok)*160 + f]);
  }
  float xxv[8][4], xsv[8][4];
  #pragma unroll
  for (int i=0;i<4;i++){
    const int d = i*256 + tid;
    const float mx = maa_x[d];
    #pragma unroll
    for (int tok=0;tok<8;tok++){
      const size_t tglob = g0 + tok;
      const size_t p = tglob*1024 + d;
      const float xc = x[p];
      const float xprev = ((tglob & 4095) == 0) ? 0.f : x[p - 1024];
      const float xxq = xprev - xc;
      xxv[tok][i] = xxq;
      xsv[tok][i] = xc + xxq*mx;
    }
  }
  __syncthreads();

  for (int n=0;n<5;n++){
    float acc[8][4];
    #pragma unroll
    for (int tok=0;tok<8;tok++)
      #pragma unroll
      for (int i=0;i<4;i++) acc[tok][i] = 0.f;
    for (int jj=0;jj<32;jj++){
      const int f = n*32+jj;
      float mv[8];
      #pragma unroll
      for (int tok=0;tok<8;tok++) mv[tok] = m5L[tok*160+f];
      #pragma unroll
      for (int i=0;i<4;i++){
        const float wv = w2[(size_t)f*1024 + i*256 + tid];
        #pragma unroll
        for (int tok=0;tok<8;tok++) acc[tok][i] += mv[tok]*wv;
      }
    }
    const float* cnp = (n==0)?maa_w:(n==1)?maa_k:(n==2)?maa_v:(n==3)?maa_r:maa_g;
    unsigned short* outp = (n==1)?xk:(n==2)?xv:(n==3)?xr:xg;
    #pragma unroll
    for (int i=0;i<4;i++){
      const int d = i*256 + tid;
      const float cdelta = cnp[d] - maa_x[d];
      #pragma unroll
      for (int tok=0;tok<8;tok++){
        const float val = xsv[tok][i] + xxv[tok][i]*(cdelta + acc[tok][i]);
        const size_t op = (g0+tok)*1024 + d;
        if (n == 0) xwL[tok*1024 + d] = val;
        else        outp[op] = f2bf(val);
      }
    }
  }
  __syncthreads();

  {
    const int jj = tid & 63, grp = tid >> 6;
    float a0 = 0.f, a1 = 0.f;
    const float* xr0 = &xwL[grp*1024];
    const float* xr1 = &xwL[(grp+4)*1024];
    for (int k=0;k<1024;k+=8){
      #pragma unroll
      for (int q=0;q<8;q++){
        const float dv = dw1[(size_t)(k+q)*64 + jj];
        a0 += xr0[k+q]*dv;
        a1 += xr1[k+q]*dv;
      }
    }
    t64L[grp*64 + jj]     = tanhf(a0);
    t64L[(grp+4)*64 + jj] = tanhf(a1);
  }
  __syncthreads();

  {
    float acc[8][4];
    #pragma unroll
    for (int tok=0;tok<8;tok++)
      #pragma unroll
      for (int i=0;i<4;i++) acc[tok][i] = 0.f;
    for (int f=0;f<64;f++){
      float tv[8];
      #pragma unroll
      for (int tok=0;tok<8;tok++) tv[tok] = t64L[tok*64+f];
      #pragma unroll
      for (int i=0;i<4;i++){
        const float wv = dw2[(size_t)f*1024 + i*256 + tid];
        #pragma unroll
        for (int tok=0;tok<8;tok++) acc[tok][i] += tv[tok]*wv;
      }
    }
    #pragma unroll
    for (int i=0;i<4;i++){
      const int d = i*256 + tid;
      const float td = tdec[d];
      #pragma unroll
      for (int tok=0;tok<8;tok++){
        const float wl = -fminf(expf(td + acc[tok][i]), 5.2983174f);
        wlog[(g0+tok)*1024 + d] = wl;
      }
    }
  }
}

// ---------------------------------------------------------------------------
// wkv pass1.  Reads wlog, computes cumsum, WRITES CUM BACK IN PLACE (over
// wlog), computes per-chunk wkv + wse.  F32KV selects f32 vs bf16 k/v.
// ---------------------------------------------------------------------------
template<int F32KV>
__launch_bounds__(256, 3)
__global__ void wkv_pass1(float* __restrict__ wlog, const void* __restrict__ kg,
                          const void* __restrict__ vg,
                          float* __restrict__ wkv, float* __restrict__ wse)
{
  __shared__ float cumL[128*64];   // cum -> khat in place
  __shared__ float vL[64*64];
  __shared__ float wsL[64];
  __shared__ float segsum[4*64];
  const int tid = threadIdx.x;
  const int hc = blockIdx.x;
  const int n = hc & 31, h = (hc >> 5) & 15, b = hc >> 9;
  const size_t tokbase = (size_t)b*4096 + (size_t)n*128;
  const size_t colbase = (size_t)h*64;

  #pragma unroll
  for (int i=0;i<8;i++){
    const int q = tid + 256*i;          // 2048 float4
    const int t = q >> 4, k4 = (q & 15)*4;
    *(float4*)&cumL[t*64 + k4] =
      *(const float4*)&wlog[(tokbase + t)*1024 + colbase + k4];
  }
  __syncthreads();
  { // segmented cumsum along t
    const int k2 = tid & 63, seg = tid >> 6;
    const int base = seg*32*64 + k2;
    float run = 0.f;
    for (int i=0;i<32;i++){ run += cumL[base + i*64]; cumL[base + i*64] = run; }
    segsum[seg*64 + k2] = run;
    __syncthreads();
    float offv = 0.f;
    for (int s2=0;s2<seg;s2++) offv += segsum[s2*64 + k2];
    if (seg > 0)
      for (int i=0;i<32;i++) cumL[base + i*64] += offv;
    __syncthreads();
  }
  if (tid < 64){
    const float wsv = cumL[127*64 + tid];
    wsL[tid] = wsv;
    wse[(size_t)hc*64 + tid] = expf(wsv);
  }
  __syncthreads();
  for (int idx = tid; idx < 8192; idx += 256){
    const int t = idx >> 6, k2 = idx & 63;
    const float c = cumL[idx];
    const size_t p = (tokbase + t)*1024 + colbase + k2;
    wlog[p] = c;
    const float kv = F32KV ? ((const float*)kg)[p] : bf2f(((const unsigned short*)kg)[p]);
    cumL[idx] = kv * expf(wsL[k2] - c);
  }
  __syncthreads();

  const int kk0 = (tid >> 4)*4, vv0 = (tid & 15)*4;
  float a[4][4];
  #pragma unroll
  for (int i=0;i<4;i++){ a[i][0]=0.f; a[i][1]=0.f; a[i][2]=0.f; a[i][3]=0.f; }
  for (int half=0; half<2; half++){
    #pragma unroll
    for (int i=0;i<4;i++){
      const int q = tid + 256*i;        // 1024 float4
      const int tr = q >> 4, k4 = (q & 15)*4;
      const size_t p = (tokbase + half*64 + tr)*1024 + colbase + k4;
      float4 vv;
      if (F32KV) vv = *(const float4*)((const float*)vg + p);
      else {
        ushort4 vu = *(const ushort4*)((const unsigned short*)vg + p);
        vv = make_float4(bf2f(vu.x), bf2f(vu.y), bf2f(vu.z), bf2f(vu.w));
      }
      *(float4*)&vL[tr*64 + k4] = vv;
    }
    __syncthreads();
    for (int t64=0; t64<64; t64++){
      float4 kf = *(const float4*)&cumL[(half*64 + t64)*64 + kk0];
      float4 vf = *(const float4*)&vL[t64*64 + vv0];
      const float kr[4] = {kf.x, kf.y, kf.z, kf.w};
      const float vr[4] = {vf.x, vf.y, vf.z, vf.w};
      #pragma unroll
      for (int i=0;i<4;i++)
        #pragma unroll
        for (int j=0;j<4;j++) a[i][j] += kr[i]*vr[j];
    }
    __syncthreads();
  }
  const size_t obase = (size_t)hc*4096;
  #pragma unroll
  for (int i=0;i<4;i++)
    *(float4*)(wkv + obase + (size_t)(kk0+i)*64 + vv0) = make_float4(a[i][0],a[i][1],a[i][2],a[i][3]);
}

// ---------------------------------------------------------------------------
// wkv pass2: scan over 32 chunks.
// ---------------------------------------------------------------------------
__global__ void wkv_scan(const float* __restrict__ wkv, const float* __restrict__ wse,
                         float* __restrict__ states)
{
  const int idx = blockIdx.x*256 + threadIdx.x;
  const int vv = idx & 63, kq = (idx >> 6) & 63, bh = idx >> 12;
  float st = 0.f;
  for (int n=0;n<32;n++){
    const size_t hc = (size_t)bh*32 + n;
    states[hc*4096 + (size_t)kq*64 + vv] = st;
    st = st * wse[hc*64 + kq] + wkv[hc*4096 + (size_t)kq*64 + vv];
  }
}

// ---------------------------------------------------------------------------
// wkv pass3 v2: precomputed cum; LDS rhat reads.
// F32 selects f32 r/k/v.  FUSED=1: groupnorm+silu(g) -> act bf16.
// ---------------------------------------------------------------------------
template<int F32, int FUSED>
__launch_bounds__(256, 4)
__global__ void wkv_pass3(const float* __restrict__ cum, const void* __restrict__ rg,
                          const void* __restrict__ kg, const void* __restrict__ vg,
                          const float* __restrict__ states, const float* __restrict__ faaaa,
                          const unsigned short* __restrict__ gg,
                          const float* __restrict__ lnw, const float* __restrict__ lnb,
                          unsigned short* __restrict__ outp)
{
  __shared__ float cumS[2][16*68];
  __shared__ float P[64*64];
  __shared__ __attribute__((aligned(16))) float rhat[16*68];
  __shared__ __attribute__((aligned(16))) float khat[16*68];
  __shared__ float vB[16*64];
  __shared__ float decL[64];
  __shared__ float aL[16*16];
  __shared__ float uL[64];
  __shared__ float lnwL[64], lnbL[64];
  const int tid = threadIdx.x;
  const int hc = blockIdx.x;
  const int n = hc & 31, h = (hc >> 5) & 15, b = hc >> 9;
  const size_t tokbase = (size_t)b*4096 + (size_t)n*128;
  const size_t colbase = (size_t)h*64;

  if (tid < 64){
    uL[tid] = faaaa[colbase + tid];
    cumS[1][15*68 + tid] = 0.f;          // "prev" row-15 for c=0
    if (FUSED){
      lnwL[tid] = lnw[colbase + tid];
      lnbL[tid] = lnb[colbase + tid];
    }
  }
  for (int idx = tid; idx < 4096; idx += 256)
    P[idx] = states[(size_t)hc*4096 + idx];
  __syncthreads();

  for (int c=0;c<8;c++){
    const int t0 = c*16;
    float* cur = cumS[c & 1];
    float* prv = cumS[(c & 1) ^ 1];
    { // phase A: load cum rows t0..t0+15
      const int row = tid >> 4, k4 = (tid & 15)*4;
      *(float4*)&cur[row*68 + k4] =
        *(const float4*)&cum[(tokbase + t0 + row)*1024 + colbase + k4];
    }
    __syncthreads();

    { // phase B: staging — rhat/khat/vB/diag/decL
      const int tl = tid >> 4, k4 = (tid & 15)*4;
      const size_t p4 = (tokbase + t0 + tl)*1024 + colbase + k4;
      float rv[4], kv[4], vv[4];
      if (F32){
        float4 r4 = *(const float4*)((const float*)rg + p4);
        float4 kq4 = *(const float4*)((const float*)kg + p4);
        float4 v4 = *(const float4*)((const float*)vg + p4);
        rv[0]=r4.x; rv[1]=r4.y; rv[2]=r4.z; rv[3]=r4.w;
        kv[0]=kq4.x; kv[1]=kq4.y; kv[2]=kq4.z; kv[3]=kq4.w;
        vv[0]=v4.x; vv[1]=v4.y; vv[2]=v4.z; vv[3]=v4.w;
      } else {
        ushort4 r4 = *(const ushort4*)((const unsigned short*)rg + p4);
        ushort4 kq4 = *(const ushort4*)((const unsigned short*)kg + p4);
        ushort4 v4 = *(const ushort4*)((const unsigned short*)vg + p4);
        rv[0]=bf2f(r4.x); rv[1]=bf2f(r4.y); rv[2]=bf2f(r4.z); rv[3]=bf2f(r4.w);
        kv[0]=bf2f(kq4.x); kv[1]=bf2f(kq4.y); kv[2]=bf2f(kq4.z); kv[3]=bf2f(kq4.w);
        vv[0]=bf2f(v4.x); vv[1]=bf2f(v4.y); vv[2]=bf2f(v4.z); vv[3]=bf2f(v4.w);
      }
      float4 off4 = *(const float4*)&prv[15*68 + k4];
      float4 cs4  = *(const float4*)&cur[tl*68 + k4];
      float4 cp4  = (tl == 0) ? off4 : *(const float4*)&cur[(tl-1)*68 + k4];
      float4 u4   = *(const float4*)&uL[k4];
      const float offa[4] = {off4.x,off4.y,off4.z,off4.w};
      const float csa[4]  = {cs4.x,cs4.y,cs4.z,cs4.w};
      const float cpa[4]  = {cp4.x,cp4.y,cp4.z,cp4.w};
      const float ua[4]   = {u4.x,u4.y,u4.z,u4.w};
      float rh[4], kh[4];
      float diagp = 0.f;
      #pragma unroll
      for (int j=0;j<4;j++){
        rh[j] = rv[j]*expf(cpa[j] - offa[j]);
        kh[j] = kv[j]*expf(offa[j] - csa[j]);
        diagp += rv[j]*ua[j]*kv[j];
      }
      *(float4*)&rhat[tl*68 + k4] = make_float4(rh[0],rh[1],rh[2],rh[3]);
      *(float4*)&khat[tl*68 + k4] = make_float4(kh[0],kh[1],kh[2],kh[3]);
      *(float4*)&vB[tl*64 + k4]   = make_float4(vv[0],vv[1],vv[2],vv[3]);
      diagp += __shfl_xor(diagp, 1);
      diagp += __shfl_xor(diagp, 2);
      diagp += __shfl_xor(diagp, 4);
      diagp += __shfl_xor(diagp, 8);
      if ((tid & 15) == 0) aL[tl*16 + tl] = diagp;
      if (tl == 15){
        decL[k4+0] = expf(csa[0] - offa[0]);
        decL[k4+1] = expf(csa[1] - offa[1]);
        decL[k4+2] = expf(csa[2] - offa[2]);
        decL[k4+3] = expf(csa[3] - offa[3]);
      }
    }
    __syncthreads();

    { // phase C: strict-lower a[t,s] = rhat[t].khat[s]
      const int tl = tid >> 4, sl = tid & 15;
      if (sl < tl){
        const float4* rp = (const float4*)&rhat[tl*68];
        const float4* kp = (const float4*)&khat[sl*68];
        float a0=0.f,a1=0.f,a2=0.f,a3=0.f;
        #pragma unroll
        for (int q=0;q<16;q++){
          float4 rv4 = rp[q], kv4 = kp[q];
          a0 += rv4.x*kv4.x; a1 += rv4.y*kv4.y;
          a2 += rv4.z*kv4.z; a3 += rv4.w*kv4.w;
        }
        aL[tl*16 + sl] = (a0+a1)+(a2+a3);
      }
    }
    __syncthreads();

    { // phase D: out = tril(a)@v + rhat@P (+ fused GN/SiLU)
      const int tl = tid >> 4, vq = (tid & 15)*4;
      float o0=0.f,o1=0.f,o2=0.f,o3=0.f;
      for (int sl=0; sl<=tl; sl++){
        const float av = aL[tl*16 + sl];
        float4 vf = *(const float4*)&vB[sl*64 + vq];
        o0 += av*vf.x; o1 += av*vf.y; o2 += av*vf.z; o3 += av*vf.w;
      }
      for (int k2=0;k2<64;k2++){
        const float rv = rhat[tl*68 + k2];
        float4 pf = *(const float4*)&P[k2*64 + vq];
        o0 += rv*pf.x; o1 += rv*pf.y; o2 += rv*pf.z; o3 += rv*pf.w;
      }
      const size_t yp = (tokbase + t0 + tl)*1024 + colbase + vq;
      if (FUSED){
        float s  = o0+o1+o2+o3;
        float s2 = o0*o0+o1*o1+o2*o2+o3*o3;
        #pragma unroll
        for (int m=1; m<16; m<<=1){
          s  += __shfl_xor(s,  m);
          s2 += __shfl_xor(s2, m);
        }
        const float mean = s*(1.f/64.f);
        const float var  = s2*(1.f/64.f) - mean*mean;
        const float rstd = rsqrtf(var + 6.4e-4f);
        ushort4 gv4 = *(const ushort4*)(gg + yp);
        const float gvs[4] = {bf2f(gv4.x), bf2f(gv4.y), bf2f(gv4.z), bf2f(gv4.w)};
        const float os[4] = {o0,o1,o2,o3};
        ushort4 ov;
        unsigned short* ovp = (unsigned short*)&ov;
        #pragma unroll
        for (int j=0;j<4;j++){
          const float yn = (os[j] - mean)*rstd*lnwL[vq+j] + lnbL[vq+j];
          const float gv = gvs[j];
          const float sg = gv/(1.f + expf(-gv));
          ovp[j] = f2bf(yn*sg);
        }
        *(ushort4*)(outp + yp) = ov;
      } else {
        ushort4 ov; ov.x = f2bf(o0); ov.y = f2bf(o1); ov.z = f2bf(o2); ov.w = f2bf(o3);
        *(ushort4*)(outp + yp) = ov;
      }
    }
    __syncthreads();

    { // phase E: P = P*dec + (khat*dec)^T @ v
      const int vq = (tid & 15)*4;
      const int kq0 = tid >> 4;
      float dec_ii[4];
      #pragma unroll
      for (int ii=0;ii<4;ii++) dec_ii[ii] = decL[kq0 + ii*16];
      float pv[4][4];
      #pragma unroll
      for (int ii=0;ii<4;ii++){
        const int kq = kq0 + ii*16;
        const float dec = dec_ii[ii];
        float4 pf = *(const float4*)&P[kq*64 + vq];
        pv[ii][0] = pf.x*dec; pv[ii][1] = pf.y*dec; pv[ii][2] = pf.z*dec; pv[ii][3] = pf.w*dec;
      }
      for (int tl=0;tl<16;tl++){
        float4 vf = *(const float4*)&vB[tl*64 + vq];
        const float vr[4] = {vf.x, vf.y, vf.z, vf.w};
        #pragma unroll
        for (int ii=0;ii<4;ii++){
          const float khv = khat[tl*68 + kq0 + ii*16]*dec_ii[ii];
          #pragma unroll
          for (int j=0;j<4;j++) pv[ii][j] += khv*vr[j];
        }
      }
      #pragma unroll
      for (int ii=0;ii<4;ii++)
        *(float4*)&P[(kq0+ii*16)*64 + vq] = make_float4(pv[ii][0],pv[ii][1],pv[ii][2],pv[ii][3]);
    }
    __syncthreads();
  }
}

// ---------------------------------------------------------------------------
// act (tier-2 only): groupnorm * silu(g) -> bf16.
// ---------------------------------------------------------------------------
__global__ void act_k(const unsigned short* __restrict__ y, const unsigned short* __restrict__ g,
                      const float* __restrict__ lnw, const float* __restrict__ lnb,
                      unsigned short* __restrict__ act)
{
  const size_t tau = blockIdx.x;
  const int lane = threadIdx.x & 63;
  const int wave = threadIdx.x >> 6;
  #pragma unroll
  for (int hh=0; hh<4; hh++){
    const int h = wave*4 + hh;
    const size_t p = tau*1024 + (size_t)h*64 + lane;
    const float val = bf2f(y[p]);
    float s = val, s2 = val*val;
    #pragma unroll
    for (int m=32; m>=1; m>>=1){
      s  += __shfl_xor(s, m);
      s2 += __shfl_xor(s2, m);
    }
    const float mean = s*(1.f/64.f);
    const float var  = s2*(1.f/64.f) - mean*mean;
    const int dd = h*64 + lane;
    float yn = (val - mean)*rsqrtf(var + 6.4e-4f);
    yn = yn*lnw[dd] + lnb[dd];
    const float gv = bf2f(g[p]);
    const float sg = gv/(1.f + expf(-gv));
    act[p] = f2bf(yn*sg);
  }
}

// ===========================================================================
extern "C" void kernel_launch(void* const* d_in, const int* in_sizes, int n_in,
                              void* d_out, int out_size, void* d_ws, size_t ws_size,
                              hipStream_t stream)
{
  (void)in_sizes; (void)n_in; (void)out_size;
  const float* x     = (const float*)d_in[0];
  const float* maa_x = (const float*)d_in[1];
  const float* maa_r = (const float*)d_in[2];
  const float* maa_w = (const float*)d_in[3];
  const float* maa_k = (const float*)d_in[4];
  const float* maa_v = (const float*)d_in[5];
  const float* maa_g = (const float*)d_in[6];
  const float* w1    = (const float*)d_in[7];
  const float* w2    = (const float*)d_in[8];
  const float* dw1   = (const float*)d_in[9];
  const float* dw2   = (const float*)d_in[10];
  const float* tdec  = (const float*)d_in[11];
  const float* faaaa = (const float*)d_in[12];
  const float* Wr    = (const float*)d_in[13];
  const float* Wk    = (const float*)d_in[14];
  const float* Wv    = (const float*)d_in[15];
  const float* Wg    = (const float*)d_in[16];
  const float* Wo    = (const float*)d_in[17];
  const float* lnw   = (const float*)d_in[18];
  const float* lnb   = (const float*)d_in[19];

  char* ws = (char*)d_ws;
  const dim3 tb32(32, 8);
  const size_t MB16 = (size_t)8192*1024*2;   // 16MB (one bf16/fp16 token-matrix)

  // ---------- tier-1 (~180MB) ----------
  {
    size_t o = 0;
    auto take = [&o](size_t nb){ size_t r = o; o += (nb + 255) & ~(size_t)255; return r; };
    unsigned short* WtG = (unsigned short*)(ws + take((size_t)1024*1024*2));
    unsigned short* WtO = (unsigned short*)(ws + take((size_t)1024*1024*2));
    unsigned short* W1t = (unsigned short*)(ws + take((size_t)160*1024*2));
    unsigned short* Wr16= (unsigned short*)(ws + take((size_t)1024*1024*2));
    unsigned short* Wk16= (unsigned short*)(ws + take((size_t)1024*1024*2));
    unsigned short* Wv16= (unsigned short*)(ws + take((size_t)1024*1024*2));
    unsigned short* D1H = (unsigned short*)(ws + take((size_t)64*1024*2));
    unsigned short* D1L = (unsigned short*)(ws + take((size_t)64*1024*2));
    unsigned short* D2H = (unsigned short*)(ws + take((size_t)1024*64*2));
    unsigned short* D2L = (unsigned short*)(ws + take((size_t)1024*64*2));
    unsigned short* W2tH= (unsigned short*)(ws + take((size_t)5120*32*2));
    unsigned short* W2tL= (unsigned short*)(ws + take((size_t)5120*32*2));
    unsigned short* Th  = (unsigned short*)(ws + take((size_t)8192*64*2));
    unsigned short* Tl  = (unsigned short*)(ws + take((size_t)8192*64*2));
    unsigned short* M5h = (unsigned short*)(ws + take((size_t)8192*160*2));  // -> wse f32
    unsigned short* M5l = (unsigned short*)(ws + take((size_t)8192*160*2));
    char*  Sxxx  = ws + take(MB16);            // xxx bf16 -> g bf16
    char*  slotRA = ws + take(2*MB16);         // xr16 -> k32 f32
    char*  slotKB = ws + take(2*MB16);         // xk16 -> v32 f32
    char*  slotVC = ws + take(2*MB16);         // xv16 -> wkv f32 + st f32
    char*  slotOA = ws + take(2*MB16);         // xwh+xwl -> r32 f32
    char*  Sxg   = ws + take(MB16);            // xg bf16 -> act bf16

    if (o <= ws_size){
      unsigned short* xxxb = (unsigned short*)Sxxx;
      unsigned short* gb   = (unsigned short*)Sxxx;
      float* wse = (float*)M5h;                 // m5 dead after gemm_mix
      unsigned short* xr16 = (unsigned short*)slotRA;
      float* k32 = (float*)slotRA;
      unsigned short* xk16 = (unsigned short*)slotKB;
      float* v32 = (float*)slotKB;
      unsigned short* xv16 = (unsigned short*)slotVC;
      float* wkvb = (float*)slotVC;
      float* st   = (float*)(slotVC + MB16);
      unsigned short* xwh = (unsigned short*)slotOA;
      unsigned short* xwl = (unsigned short*)(slotOA + MB16);
      float* r32  = (float*)slotOA;
      unsigned short* xgb  = (unsigned short*)Sxg;
      unsigned short* actb = (unsigned short*)Sxg;
      float* wlogb = (float*)d_out;             // wlog -> cum (in place)

      transpose_k<1><<<dim3(32,32), tb32, 0, stream>>>(Wg, WtG, 1024, 1024);
      transpose_k<1><<<dim3(32,32), tb32, 0, stream>>>(Wo, WtO, 1024, 1024);
      transpose_k<1><<<dim3(5,32),  tb32, 0, stream>>>(w1, W1t, 1024, 160);
      transpose_k<2><<<dim3(32,32), tb32, 0, stream>>>(Wr, Wr16, 1024, 1024);
      transpose_k<2><<<dim3(32,32), tb32, 0, stream>>>(Wk, Wk16, 1024, 1024);
      transpose_k<2><<<dim3(32,32), tb32, 0, stream>>>(Wv, Wv16, 1024, 1024);
      transpose_split<<<dim3(2,32),  tb32, 0, stream>>>(dw1, D1H, D1L, 1024, 64);
      transpose_split<<<dim3(32,2),  tb32, 0, stream>>>(dw2, D2H, D2L, 64, 1024);
      build_w2t<<<640, 256, 0, stream>>>(w2, W2tH, W2tL);

      prep_k<<<8192, 256, 0, stream>>>(x, maa_x, xxxb);
      gemm_tanh_bf16<<<dim3(64,2), 256, 0, stream>>>(xxxb, W1t, M5h, M5l, 8192, 160, 1024);
      gemm_mix<<<dim3(40,64), 256, 0, stream>>>(W2tH, W2tL, M5h, M5l, x, maa_x,
                                                maa_w, maa_k, maa_v, maa_r, maa_g,
                                                xwh, xwl, xk16, xv16, xr16, xgb);

      // decay path: t = tanh(xw@dw1) -> wlog = -min(exp(tdec + t@dw2), 5.298)
      gemm_tanh64<<<128, 256, 0, stream>>>(xwh, xwl, D1H, D1L, Th, Tl, 8192, 1024);
      gemm_split2<2><<<dim3(64,8), 256, 0, stream>>>(Th, Tl, D2H, D2L, wlogb, tdec, 8192, 1024, 64);

      gemm_bf16<1><<<dim3(64,8), 256, 0, stream>>>(xgb, WtG, gb, 8192, 1024, 1024, 1);
      gemm_fp16<<<dim3(64,8), 256, 0, stream>>>(xr16, Wr16, r32, 8192, 1024, 1024);
      gemm_fp16<<<dim3(64,8), 256, 0, stream>>>(xk16, Wk16, k32, 8192, 1024, 1024);
      gemm_fp16<<<dim3(64,8), 256, 0, stream>>>(xv16, Wv16, v32, 8192, 1024, 1024);

      wkv_pass1<1><<<1024, 256, 0, stream>>>(wlogb, k32, v32, wkvb, wse);
      wkv_scan    <<<512,  256, 0, stream>>>(wkvb, wse, st);
      wkv_pass3<1,1><<<1024, 256, 0, stream>>>(wlogb, r32, k32, v32, st, faaaa,
                                               gb, lnw, lnb, actb);

      gemm_bf16<1><<<dim3(64,8), 256, 0, stream>>>(actb, WtO, d_out, 8192, 1024, 1024, 0);
      return;
    }
  }

  // ---------- tier-2 fallback (~112MB, all-bf16) ----------
  {
    size_t o = 0;
    auto take = [&o](size_t nb){ size_t r = o; o += (nb + 255) & ~(size_t)255; return r; };
    unsigned short* WtR  = (unsigned short*)(ws + take((size_t)1024*1024*2));
    unsigned short* WtK  = (unsigned short*)(ws + take((size_t)1024*1024*2));
    unsigned short* WtV  = (unsigned short*)(ws + take((size_t)1024*1024*2));
    unsigned short* WtG  = (unsigned short*)(ws + take((size_t)1024*1024*2));
    unsigned short* WtO  = (unsigned short*)(ws + take((size_t)1024*1024*2));
    unsigned short* W1t  = (unsigned short*)(ws + take((size_t)160*1024*2));
    unsigned short* xxxb = (unsigned short*)(ws + take(MB16));
    float*          mraw = (float*)         (ws + take((size_t)8192*160*4));
    unsigned short* xrb  = (unsigned short*)(ws + take(MB16));
    unsigned short* xkb  = (unsigned short*)(ws + take(MB16));
    unsigned short* xvb  = (unsigned short*)(ws + take(MB16));
    unsigned short* xgb  = (unsigned short*)(ws + take(MB16));
    unsigned short* kb   = (unsigned short*)(ws + take(MB16));
    float*          wseb = (float*)         (ws + take((size_t)1024*64*4));
    if (o > ws_size) return;

    float*          wlogb = (float*)d_out;
    unsigned short* rb    = xxxb;
    unsigned short* vb    = xrb;
    unsigned short* gb    = xkb;
    float*          wkvb  = (float*)xvb;
    float*          stb   = (float*)xgb;
    unsigned short* yb    = xvb;
    unsigned short* actb  = kb;

    transpose_k<1><<<dim3(32,32), tb32, 0, stream>>>(Wr, WtR, 1024, 1024);
    transpose_k<1><<<dim3(32,32), tb32, 0, stream>>>(Wk, WtK, 1024, 1024);
    transpose_k<1><<<dim3(32,32), tb32, 0, stream>>>(Wv, WtV, 1024, 1024);
    transpose_k<1><<<dim3(32,32), tb32, 0, stream>>>(Wg, WtG, 1024, 1024);
    transpose_k<1><<<dim3(32,32), tb32, 0, stream>>>(Wo, WtO, 1024, 1024);
    transpose_k<1><<<dim3(5,32),  tb32, 0, stream>>>(w1, W1t, 1024, 160);

    prep_k<<<8192, 256, 0, stream>>>(x, maa_x, xxxb);
    gemm_bf16<0><<<dim3(64,2), 256, 0, stream>>>(xxxb, W1t, mraw, 8192, 160, 1024, 0);
    mix_fb<<<1024, 256, 0, stream>>>(x, mraw, maa_x, maa_w, maa_k, maa_v, maa_r, maa_g,
                                     w2, dw1, dw2, tdec,
                                     xrb, xkb, xvb, xgb, wlogb);

    gemm_bf16<0><<<dim3(64,8), 256, 0, stream>>>(xrb, WtR, rb, 8192, 1024, 1024, 1);
    gemm_bf16<0><<<dim3(64,8), 256, 0, stream>>>(xkb, WtK, kb, 8192, 1024, 1024, 1);
    gemm_bf16<0><<<dim3(64,8), 256, 0, stream>>>(xvb, WtV, vb, 8192, 1024, 1024, 1);
    gemm_bf16<0><<<dim3(64,8), 256, 0, stream>>>(xgb, WtG, gb, 8192, 1024, 1024, 1);

    wkv_pass1<0><<<1024, 256, 0, stream>>>(wlogb, kb, vb, wkvb, wseb);
    wkv_scan    <<<512,  256, 0, stream>>>(wkvb, wseb, stb);
    wkv_pass3<0,0><<<1024, 256, 0, stream>>>(wlogb, rb, kb, vb, stb, faaaa,
                                             nullptr, nullptr, nullptr, yb);

    act_k<<<8192, 256, 0, stream>>>(yb, gb, lnw, lnb, actb);
    gemm_bf16<0><<<dim3(64,8), 256, 0, stream>>>(actb, WtO, d_out, 8192, 1024, 1024, 0);
  }
}